// Round 3
// baseline (639.469 us; speedup 1.0000x reference)
//
#include <hip/hip_runtime.h>
#include <hip/hip_bf16.h>
#include <math.h>

#define N_NODES 50000
#define N_EDGES 800000
#define F_IN    128
#define HID     64
#define HEADS   4
#define NCLS    16
#define NEG_SLOPE 0.2f

typedef __attribute__((ext_vector_type(8))) short short8v;
typedef __attribute__((ext_vector_type(4))) float f32x4;

static __device__ __forceinline__ float lrelu(float x) {
    return x >= 0.f ? x : NEG_SLOPE * x;
}
static __device__ __forceinline__ float b2f(unsigned short u) {
    return __uint_as_float(((unsigned)u) << 16);
}
static __device__ __forceinline__ unsigned short f2b(float f) {
    __hip_bfloat16 b = __float2bfloat16(f);
    return *(unsigned short*)&b;
}
// monotonic float<->uint mapping for atomicMax on floats
static __device__ __forceinline__ unsigned encf(float f) {
    unsigned u = __float_as_uint(f);
    return (u & 0x80000000u) ? ~u : (u | 0x80000000u);
}
static __device__ __forceinline__ float decf(unsigned u) {
    unsigned b = (u & 0x80000000u) ? (u & 0x7FFFFFFFu) : ~u;
    return __uint_as_float(b);
}

// ---------------- converts ----------------
__global__ void k_f2b4(const float* __restrict__ in, unsigned short* __restrict__ out, int n4) {
    int i = blockIdx.x * blockDim.x + threadIdx.x;
    if (i < n4) {
        float4 v = *(const float4*)(in + i * 4);
        ushort4 o = { f2b(v.x), f2b(v.y), f2b(v.z), f2b(v.w) };
        *(ushort4*)(out + i * 4) = o;
    }
}

// Wt[c][k] = W[k][c], bf16
__global__ void k_wt(const float* __restrict__ W, unsigned short* __restrict__ Wt, int K, int N) {
    int i = blockIdx.x * blockDim.x + threadIdx.x;
    if (i < K * N) {
        int k = i / N, c = i % N;
        Wt[c * K + k] = f2b(W[i]);
    }
}

// ---------------- CSR build ----------------
__global__ void k_hist(const int* __restrict__ dst, int* __restrict__ counts, int e) {
    int i = blockIdx.x * blockDim.x + threadIdx.x;
    if (i < e) atomicAdd(&counts[dst[i]], 1);
}

__global__ __launch_bounds__(256) void k_scan1(const int* __restrict__ counts, int* __restrict__ incl,
                                               int* __restrict__ bsums, int n) {
    __shared__ int wsum[4];
    int blk = blockIdx.x, tid = threadIdx.x;
    int lane = tid & 63, w = tid >> 6;
    int i0 = blk * 1024 + tid * 4;
    int v[4];
    #pragma unroll
    for (int j = 0; j < 4; j++) v[j] = (i0 + j < n) ? counts[i0 + j] : 0;
    int t = v[0] + v[1] + v[2] + v[3];
    int x = t;
    #pragma unroll
    for (int d = 1; d < 64; d <<= 1) { int y = __shfl_up(x, d); if (lane >= d) x += y; }
    if (lane == 63) wsum[w] = x;
    __syncthreads();
    int woff = 0;
    #pragma unroll
    for (int ww = 0; ww < 4; ww++) woff += (ww < w) ? wsum[ww] : 0;
    int p = woff + x - t;
    #pragma unroll
    for (int j = 0; j < 4; j++) { p += v[j]; if (i0 + j < n) incl[i0 + j] = p; }
    if (tid == 255) bsums[blk] = woff + x;
}

__global__ void k_scan2(const int* __restrict__ bsums, int* __restrict__ boffs, int nb, int* rowptr_end) {
    int lane = threadIdx.x;
    int v = (lane < nb) ? bsums[lane] : 0;
    int x = v;
    #pragma unroll
    for (int d = 1; d < 64; d <<= 1) { int y = __shfl_up(x, d); if (lane >= d) x += y; }
    if (lane < nb) boffs[lane] = x - v;
    if (lane == 63) *rowptr_end = x;
}

__global__ void k_scan3(const int* __restrict__ incl, const int* __restrict__ counts,
                        const int* __restrict__ boffs, int* __restrict__ rowptr, int n) {
    int i = blockIdx.x * blockDim.x + threadIdx.x;
    if (i < n) rowptr[i] = boffs[i >> 10] + incl[i] - counts[i];
}

__global__ void k_scatter(const int* __restrict__ src, const int* __restrict__ dst,
                          const int* __restrict__ rowptr, int* __restrict__ cursor,
                          int* __restrict__ col, int e) {
    int i = blockIdx.x * blockDim.x + threadIdx.x;
    if (i < e) {
        int d = dst[i];
        int pos = rowptr[d] + atomicAdd(&cursor[d], 1);
        col[pos] = src[i];
    }
}

// ---------------- MFMA GEMM: C[M,256] = A[M,K] @ Bt[256,K]^T (bf16 in/out) ----------
static __device__ __forceinline__ int swz(int r, int lc) {
    return r * 4 + (lc ^ (r & 3) ^ ((r >> 2) & 1));
}

__global__ __launch_bounds__(256) void k_gemm_mfma(const unsigned short* __restrict__ A,
                                                   const unsigned short* __restrict__ Bt,
                                                   unsigned short* __restrict__ C,
                                                   int M, int K) {
    const int N = 256;
    __shared__ unsigned short Asm[128 * 32];
    __shared__ unsigned short Bsm[128 * 32];
    int tid = threadIdx.x;
    int lane = tid & 63, wid = tid >> 6;
    int bx = blockIdx.x & 1, by = blockIdx.x >> 1;
    int row0 = by * 128, col0 = bx * 128;
    int wr = wid >> 1, wc = wid & 1;
    f32x4 acc[4][4] = {};

    for (int k0 = 0; k0 < K; k0 += 32) {
        __syncthreads();
        #pragma unroll
        for (int s = 0; s < 2; s++) {
            int c = tid + s * 256;
            int row = c >> 2, lc = c & 3;
            int gr = row0 + row; if (gr >= M) gr = 0;
            uint4 va = *(const uint4*)(A + (size_t)gr * K + k0 + lc * 8);
            *(uint4*)(&Asm[swz(row, lc) * 8]) = va;
            uint4 vb = *(const uint4*)(Bt + (size_t)(col0 + row) * K + k0 + lc * 8);
            *(uint4*)(&Bsm[swz(row, lc) * 8]) = vb;
        }
        __syncthreads();
        short8v af[4], bf[4];
        int lq = lane >> 4;
        #pragma unroll
        for (int m = 0; m < 4; m++) {
            int r = wr * 64 + m * 16 + (lane & 15);
            af[m] = *(const short8v*)(&Asm[swz(r, lq) * 8]);
        }
        #pragma unroll
        for (int n = 0; n < 4; n++) {
            int r = wc * 64 + n * 16 + (lane & 15);
            bf[n] = *(const short8v*)(&Bsm[swz(r, lq) * 8]);
        }
        #pragma unroll
        for (int m = 0; m < 4; m++)
            #pragma unroll
            for (int n = 0; n < 4; n++)
                acc[m][n] = __builtin_amdgcn_mfma_f32_16x16x32_bf16(af[m], bf[n], acc[m][n], 0, 0, 0);
    }

    #pragma unroll
    for (int m = 0; m < 4; m++) {
        #pragma unroll
        for (int r = 0; r < 4; r++) {
            int row = row0 + wr * 64 + m * 16 + (lane >> 4) * 4 + r;
            if (row < M) {
                #pragma unroll
                for (int n = 0; n < 4; n++) {
                    C[(size_t)row * N + col0 + wc * 64 + n * 16 + (lane & 15)] = f2b(acc[m][n][r]);
                }
            }
        }
    }
}

// ---------------- attention scores, layers 1&2 (H=4, D=64), bf16 h ----------------
__global__ void k_scores(const unsigned short* __restrict__ h, const float* __restrict__ a_src,
                         const float* __restrict__ a_dst, float* __restrict__ s_src,
                         float* __restrict__ s_dst, int n) {
    int wave = (blockIdx.x * blockDim.x + threadIdx.x) >> 6;
    int lane = threadIdx.x & 63;
    if (wave >= n) return;
    ushort4 hv  = *(const ushort4*)(h + (size_t)wave * 256 + lane * 4);
    float4 av1 = *(const float4*)(a_src + lane * 4);
    float4 av2 = *(const float4*)(a_dst + lane * 4);
    float h0 = b2f(hv.x), h1 = b2f(hv.y), h2 = b2f(hv.z), h3 = b2f(hv.w);
    float ps = h0 * av1.x + h1 * av1.y + h2 * av1.z + h3 * av1.w;
    float pd = h0 * av2.x + h1 * av2.y + h2 * av2.z + h3 * av2.w;
    #pragma unroll
    for (int off = 1; off < 16; off <<= 1) {
        ps += __shfl_xor(ps, off);
        pd += __shfl_xor(pd, off);
    }
    if ((lane & 15) == 0) {
        int head = lane >> 4;
        s_src[wave * 4 + head] = ps;
        s_dst[wave * 4 + head] = pd;
    }
}

// ---------------- seed max with self-loop score (layers 1&2: H=4) ----------------
__global__ void k_init_max(const float* __restrict__ s_src, const float* __restrict__ s_dst,
                           unsigned* __restrict__ mEnc, int n4) {
    int i = blockIdx.x * blockDim.x + threadIdx.x;
    if (i < n4) mEnc[i] = encf(lrelu(s_src[i] + s_dst[i]));
}

// ---------------- edge-parallel max (layers 1&2: H=4) ----------------
__global__ void k_edge_max(const int* __restrict__ src, const int* __restrict__ dst,
                           const float* __restrict__ s_src, const float* __restrict__ s_dst,
                           unsigned* __restrict__ mEnc, int e) {
    int i = blockIdx.x * blockDim.x + threadIdx.x;
    if (i >= e) return;
    int s = src[i], d = dst[i];
    float4 ss = *(const float4*)(s_src + (size_t)s * 4);
    float4 ds = *(const float4*)(s_dst + (size_t)d * 4);
    atomicMax(&mEnc[d * 4 + 0], encf(lrelu(ss.x + ds.x)));
    atomicMax(&mEnc[d * 4 + 1], encf(lrelu(ss.y + ds.y)));
    atomicMax(&mEnc[d * 4 + 2], encf(lrelu(ss.z + ds.z)));
    atomicMax(&mEnc[d * 4 + 3], encf(lrelu(ss.w + ds.w)));
}

// ---------------- single-pass segment-softmax + aggregation, layers 1&2 ----------------
__global__ void k_aggregate(const unsigned short* __restrict__ h, const int* __restrict__ rowptr,
                            const int* __restrict__ col, const float* __restrict__ s_src,
                            const float* __restrict__ s_dst, const unsigned* __restrict__ mEnc,
                            const float* __restrict__ bias,
                            unsigned short* __restrict__ out, int n) {
    int wave = (blockIdx.x * blockDim.x + threadIdx.x) >> 6;
    int lane = threadIdx.x & 63;
    if (wave >= n) return;
    int head = lane >> 4;
    int f0 = lane * 4;
    float sd = s_dst[wave * 4 + head];
    float m  = decf(mEnc[wave * 4 + head]);
    float sc_self = lrelu(s_src[wave * 4 + head] + sd);
    int rs = rowptr[wave], re = rowptr[wave + 1];
    float z = 0.f;
    float a0 = 0.f, a1 = 0.f, a2 = 0.f, a3 = 0.f;
    {
        float p = __expf(sc_self - m);
        z += p;
        ushort4 hv = *(const ushort4*)(h + (size_t)wave * 256 + f0);
        a0 += p * b2f(hv.x); a1 += p * b2f(hv.y); a2 += p * b2f(hv.z); a3 += p * b2f(hv.w);
    }
    int i = rs;
    for (; i + 4 <= re; i += 4) {
        int s0 = col[i], s1 = col[i + 1], s2 = col[i + 2], s3 = col[i + 3];
        float e0 = lrelu(s_src[s0 * 4 + head] + sd);
        float e1 = lrelu(s_src[s1 * 4 + head] + sd);
        float e2 = lrelu(s_src[s2 * 4 + head] + sd);
        float e3 = lrelu(s_src[s3 * 4 + head] + sd);
        ushort4 h0 = *(const ushort4*)(h + (size_t)s0 * 256 + f0);
        ushort4 h1 = *(const ushort4*)(h + (size_t)s1 * 256 + f0);
        ushort4 h2 = *(const ushort4*)(h + (size_t)s2 * 256 + f0);
        ushort4 h3 = *(const ushort4*)(h + (size_t)s3 * 256 + f0);
        float p0 = __expf(e0 - m), p1 = __expf(e1 - m), p2 = __expf(e2 - m), p3 = __expf(e3 - m);
        z += (p0 + p1) + (p2 + p3);
        a0 += p0 * b2f(h0.x) + p1 * b2f(h1.x) + p2 * b2f(h2.x) + p3 * b2f(h3.x);
        a1 += p0 * b2f(h0.y) + p1 * b2f(h1.y) + p2 * b2f(h2.y) + p3 * b2f(h3.y);
        a2 += p0 * b2f(h0.z) + p1 * b2f(h1.z) + p2 * b2f(h2.z) + p3 * b2f(h3.z);
        a3 += p0 * b2f(h0.w) + p1 * b2f(h1.w) + p2 * b2f(h2.w) + p3 * b2f(h3.w);
    }
    for (; i < re; i++) {
        int s = col[i];
        float p = __expf(lrelu(s_src[s * 4 + head] + sd) - m);
        z += p;
        ushort4 hv = *(const ushort4*)(h + (size_t)s * 256 + f0);
        a0 += p * b2f(hv.x); a1 += p * b2f(hv.y); a2 += p * b2f(hv.z); a3 += p * b2f(hv.w);
    }
    float inv = 1.f / z;
    float4 bv = *(const float4*)(bias + f0);
    float o0 = a0 * inv + bv.x;
    float o1 = a1 * inv + bv.y;
    float o2 = a2 * inv + bv.z;
    float o3 = a3 * inv + bv.w;
    o0 = o0 > 0.f ? o0 : expm1f(o0);
    o1 = o1 > 0.f ? o1 : expm1f(o1);
    o2 = o2 > 0.f ? o2 : expm1f(o2);
    o3 = o3 > 0.f ? o3 : expm1f(o3);
    ushort4 ov = { f2b(o0), f2b(o1), f2b(o2), f2b(o3) };
    *(ushort4*)(out + (size_t)wave * 256 + f0) = ov;
}

// ---------------- layer 3: GEMM [M,256](bf16) @ [256,16](f32) -> f32 ----------------
__global__ __launch_bounds__(256) void k_gemm3(const unsigned short* __restrict__ A,
                                               const float* __restrict__ B,
                                               float* __restrict__ C, int M, int K) {
    __shared__ float Bs[256 * 16];
    for (int i = threadIdx.x; i < K * 16; i += 256) Bs[i] = B[i];
    __syncthreads();
    int tx = threadIdx.x & 15;
    int ty = threadIdx.x >> 4;
    int row = blockIdx.x * 16 + ty;
    if (row >= M) return;
    const unsigned short* Ar = A + (size_t)row * K;
    float acc = 0.f;
    for (int kk = 0; kk < K; kk += 8) {
        uint4 va = *(const uint4*)(Ar + kk);
        const unsigned* u = (const unsigned*)&va;
        #pragma unroll
        for (int j = 0; j < 4; j++) {
            float lo = __uint_as_float(u[j] << 16);
            float hi = __uint_as_float(u[j] & 0xffff0000u);
            acc += lo * Bs[(kk + 2 * j) * 16 + tx] + hi * Bs[(kk + 2 * j + 1) * 16 + tx];
        }
    }
    C[(size_t)row * 16 + tx] = acc;
}

// ---------------- layer 3 scores (H=1, D=16) ----------------
__global__ void k_scores3(const float* __restrict__ h3, const float* __restrict__ a_src,
                          const float* __restrict__ a_dst, float* __restrict__ s_src,
                          float* __restrict__ s_dst, int n) {
    int i = blockIdx.x * blockDim.x + threadIdx.x;
    if (i >= n) return;
    float ps = 0.f, pd = 0.f;
    #pragma unroll
    for (int c = 0; c < 16; c++) {
        float v = h3[(size_t)i * 16 + c];
        ps += v * a_src[c];
        pd += v * a_dst[c];
    }
    s_src[i] = ps;
    s_dst[i] = pd;
}

__global__ void k_init_max3(const float* __restrict__ s_src, const float* __restrict__ s_dst,
                            unsigned* __restrict__ mEnc, int n) {
    int i = blockIdx.x * blockDim.x + threadIdx.x;
    if (i < n) mEnc[i] = encf(lrelu(s_src[i] + s_dst[i]));
}

__global__ void k_edge_max3(const int* __restrict__ src, const int* __restrict__ dst,
                            const float* __restrict__ s_src, const float* __restrict__ s_dst,
                            unsigned* __restrict__ mEnc, int e) {
    int i = blockIdx.x * blockDim.x + threadIdx.x;
    if (i >= e) return;
    int s = src[i], d = dst[i];
    atomicMax(&mEnc[d], encf(lrelu(s_src[s] + s_dst[d])));
}

// ---------------- layer 3 single-pass aggregation + bias + log_softmax ----------------
// 4-way edge parallelism across 16-lane groups; cross-group shuffle reduce.
__global__ void k_agg3(const float* __restrict__ h3, const int* __restrict__ rowptr,
                       const int* __restrict__ col, const float* __restrict__ s_src,
                       const float* __restrict__ s_dst, const unsigned* __restrict__ mEnc,
                       const float* __restrict__ b3,
                       float* __restrict__ outp, int n) {
    int wave = (blockIdx.x * blockDim.x + threadIdx.x) >> 6;
    int lane = threadIdx.x & 63;
    if (wave >= n) return;
    int g = lane >> 4, c = lane & 15;
    float sd = s_dst[wave];
    float m  = decf(mEnc[wave]);
    int rs = rowptr[wave], re = rowptr[wave + 1];
    float z = 0.f, acc = 0.f;
    if (g == 0) {
        float p = __expf(lrelu(s_src[wave] + sd) - m);
        z += p;
        acc += p * h3[(size_t)wave * 16 + c];
    }
    for (int i = rs + g; i < re; i += 4) {
        int s = col[i];
        float p = __expf(lrelu(s_src[s] + sd) - m);
        z += p;
        acc += p * h3[(size_t)s * 16 + c];
    }
    z += __shfl_xor(z, 16);  z += __shfl_xor(z, 32);
    acc += __shfl_xor(acc, 16); acc += __shfl_xor(acc, 32);
    if (lane < 16) {
        float v = acc / z + b3[c];
        float mm = v;
        #pragma unroll
        for (int off = 1; off < 16; off <<= 1) mm = fmaxf(mm, __shfl_xor(mm, off));
        float se = __expf(v - mm);
        #pragma unroll
        for (int off = 1; off < 16; off <<= 1) se += __shfl_xor(se, off);
        outp[(size_t)wave * 16 + c] = v - mm - logf(se);
    }
}

extern "C" void kernel_launch(void* const* d_in, const int* in_sizes, int n_in,
                              void* d_out, int out_size, void* d_ws, size_t ws_size,
                              hipStream_t stream) {
    const float* x      = (const float*)d_in[0];
    const int*   ei     = (const int*)d_in[1];
    const float* W1     = (const float*)d_in[2];
    const float* a1_src = (const float*)d_in[3];
    const float* a1_dst = (const float*)d_in[4];
    const float* b1     = (const float*)d_in[5];
    const float* W2     = (const float*)d_in[6];
    const float* a2_src = (const float*)d_in[7];
    const float* a2_dst = (const float*)d_in[8];
    const float* b2     = (const float*)d_in[9];
    const float* W3     = (const float*)d_in[10];
    const float* a3_src = (const float*)d_in[11];
    const float* a3_dst = (const float*)d_in[12];
    const float* b3     = (const float*)d_in[13];
    float* outp = (float*)d_out;

    const int N = N_NODES, E = N_EDGES;
    const int* src = ei;
    const int* dst = ei + E;

    char* ws = (char*)d_ws;
    size_t off = 0;
    auto alloc = [&](size_t bytes) {
        void* p = ws + off;
        off = (off + bytes + 255) & ~(size_t)255;
        return p;
    };
    int*   rowptr = (int*)alloc((N + 1) * sizeof(int));
    int*   counts = (int*)alloc(N * sizeof(int));      // reused as cursor
    int*   col    = (int*)alloc(E * sizeof(int));
    int*   incl   = (int*)alloc(N * sizeof(int));
    int*   bsums  = (int*)alloc(64 * sizeof(int));
    int*   boffs  = (int*)alloc(64 * sizeof(int));
    float* s_src  = (float*)alloc((size_t)N * HEADS * sizeof(float));
    float* s_dst  = (float*)alloc((size_t)N * HEADS * sizeof(float));
    unsigned* mEnc = (unsigned*)alloc((size_t)N * HEADS * sizeof(unsigned));
    unsigned short* xb  = (unsigned short*)alloc((size_t)N * F_IN * sizeof(short));
    unsigned short* W1t = (unsigned short*)alloc((size_t)256 * F_IN * sizeof(short));
    unsigned short* W2t = (unsigned short*)alloc((size_t)256 * 256 * sizeof(short));
    unsigned short* hA  = (unsigned short*)alloc((size_t)N * 256 * sizeof(short));
    unsigned short* hB  = (unsigned short*)alloc((size_t)N * 256 * sizeof(short));
    float* h3     = (float*)alloc((size_t)N * 16 * sizeof(float));
    (void)ws_size;

    // ---- converts ----
    k_f2b4<<<(N * F_IN / 4 + 255) / 256, 256, 0, stream>>>(x, xb, N * F_IN / 4);
    k_wt<<<(F_IN * 256 + 255) / 256, 256, 0, stream>>>(W1, W1t, F_IN, 256);
    k_wt<<<(256 * 256 + 255) / 256, 256, 0, stream>>>(W2, W2t, 256, 256);

    // ---- CSR build (by dst) ----
    hipMemsetAsync(counts, 0, N * sizeof(int), stream);
    k_hist<<<(E + 255) / 256, 256, 0, stream>>>(dst, counts, E);
    const int nb = (N + 1023) / 1024;
    k_scan1<<<nb, 256, 0, stream>>>(counts, incl, bsums, N);
    k_scan2<<<1, 64, 0, stream>>>(bsums, boffs, nb, rowptr + N);
    k_scan3<<<(N + 255) / 256, 256, 0, stream>>>(incl, counts, boffs, rowptr, N);
    hipMemsetAsync(counts, 0, N * sizeof(int), stream);
    k_scatter<<<(E + 255) / 256, 256, 0, stream>>>(src, dst, rowptr, counts, col, E);

    const int aggBlocks = (N + 3) / 4;
    const int gemmBlocks = ((N + 127) / 128) * 2;
    const int edgeBlocks = (E + 255) / 256;

    // ---- layer 1 ----
    k_gemm_mfma<<<gemmBlocks, 256, 0, stream>>>(xb, W1t, hA, N, F_IN);
    k_scores<<<aggBlocks, 256, 0, stream>>>(hA, a1_src, a1_dst, s_src, s_dst, N);
    k_init_max<<<(N * 4 + 255) / 256, 256, 0, stream>>>(s_src, s_dst, mEnc, N * 4);
    k_edge_max<<<edgeBlocks, 256, 0, stream>>>(src, dst, s_src, s_dst, mEnc, E);
    k_aggregate<<<aggBlocks, 256, 0, stream>>>(hA, rowptr, col, s_src, s_dst, mEnc, b1, hB, N);
    // ---- layer 2 ----
    k_gemm_mfma<<<gemmBlocks, 256, 0, stream>>>(hB, W2t, hA, N, 256);
    k_scores<<<aggBlocks, 256, 0, stream>>>(hA, a2_src, a2_dst, s_src, s_dst, N);
    k_init_max<<<(N * 4 + 255) / 256, 256, 0, stream>>>(s_src, s_dst, mEnc, N * 4);
    k_edge_max<<<edgeBlocks, 256, 0, stream>>>(src, dst, s_src, s_dst, mEnc, E);
    k_aggregate<<<aggBlocks, 256, 0, stream>>>(hA, rowptr, col, s_src, s_dst, mEnc, b2, hB, N);
    // ---- layer 3 ----
    k_gemm3<<<(N + 15) / 16, 256, 0, stream>>>(hB, W3, h3, N, 256);
    k_scores3<<<(N + 255) / 256, 256, 0, stream>>>(h3, a3_src, a3_dst, s_src, s_dst, N);
    k_init_max3<<<(N + 255) / 256, 256, 0, stream>>>(s_src, s_dst, mEnc, N);
    k_edge_max3<<<edgeBlocks, 256, 0, stream>>>(src, dst, s_src, s_dst, mEnc, E);
    k_agg3<<<aggBlocks, 256, 0, stream>>>(h3, rowptr, col, s_src, s_dst, mEnc, b3, outp, N);
}

// Round 4
// 381.585 us; speedup vs baseline: 1.6758x; 1.6758x over previous
//
#include <hip/hip_runtime.h>
#include <hip/hip_bf16.h>
#include <math.h>

#define N_NODES 50000
#define N_EDGES 800000
#define F_IN    128
#define HID     64
#define HEADS   4
#define NCLS    16
#define NEG_SLOPE 0.2f

typedef __attribute__((ext_vector_type(8))) short short8v;
typedef __attribute__((ext_vector_type(4))) float f32x4;

static __device__ __forceinline__ float lrelu(float x) {
    return x >= 0.f ? x : NEG_SLOPE * x;
}
static __device__ __forceinline__ float b2f(unsigned short u) {
    return __uint_as_float(((unsigned)u) << 16);
}
static __device__ __forceinline__ unsigned short f2b(float f) {
    __hip_bfloat16 b = __float2bfloat16(f);
    return *(unsigned short*)&b;
}

// ---------------- converts ----------------
__global__ void k_f2b4(const float* __restrict__ in, unsigned short* __restrict__ out, int n4) {
    int i = blockIdx.x * blockDim.x + threadIdx.x;
    if (i < n4) {
        float4 v = *(const float4*)(in + i * 4);
        ushort4 o = { f2b(v.x), f2b(v.y), f2b(v.z), f2b(v.w) };
        *(ushort4*)(out + i * 4) = o;
    }
}

// Wt[c][k] = W[k][c], bf16
__global__ void k_wt(const float* __restrict__ W, unsigned short* __restrict__ Wt, int K, int N) {
    int i = blockIdx.x * blockDim.x + threadIdx.x;
    if (i < K * N) {
        int k = i / N, c = i % N;
        Wt[c * K + k] = f2b(W[i]);
    }
}

// ---------------- CSR build ----------------
__global__ void k_hist(const int* __restrict__ dst, int* __restrict__ counts, int e) {
    int i = blockIdx.x * blockDim.x + threadIdx.x;
    if (i < e) atomicAdd(&counts[dst[i]], 1);
}

__global__ __launch_bounds__(256) void k_scan1(const int* __restrict__ counts, int* __restrict__ incl,
                                               int* __restrict__ bsums, int n) {
    __shared__ int wsum[4];
    int blk = blockIdx.x, tid = threadIdx.x;
    int lane = tid & 63, w = tid >> 6;
    int i0 = blk * 1024 + tid * 4;
    int v[4];
    #pragma unroll
    for (int j = 0; j < 4; j++) v[j] = (i0 + j < n) ? counts[i0 + j] : 0;
    int t = v[0] + v[1] + v[2] + v[3];
    int x = t;
    #pragma unroll
    for (int d = 1; d < 64; d <<= 1) { int y = __shfl_up(x, d); if (lane >= d) x += y; }
    if (lane == 63) wsum[w] = x;
    __syncthreads();
    int woff = 0;
    #pragma unroll
    for (int ww = 0; ww < 4; ww++) woff += (ww < w) ? wsum[ww] : 0;
    int p = woff + x - t;
    #pragma unroll
    for (int j = 0; j < 4; j++) { p += v[j]; if (i0 + j < n) incl[i0 + j] = p; }
    if (tid == 255) bsums[blk] = woff + x;
}

__global__ void k_scan2(const int* __restrict__ bsums, int* __restrict__ boffs, int nb, int* rowptr_end) {
    int lane = threadIdx.x;
    int v = (lane < nb) ? bsums[lane] : 0;
    int x = v;
    #pragma unroll
    for (int d = 1; d < 64; d <<= 1) { int y = __shfl_up(x, d); if (lane >= d) x += y; }
    if (lane < nb) boffs[lane] = x - v;
    if (lane == 63) *rowptr_end = x;
}

__global__ void k_scan3(const int* __restrict__ incl, const int* __restrict__ counts,
                        const int* __restrict__ boffs, int* __restrict__ rowptr, int n) {
    int i = blockIdx.x * blockDim.x + threadIdx.x;
    if (i < n) rowptr[i] = boffs[i >> 10] + incl[i] - counts[i];
}

__global__ void k_scatter(const int* __restrict__ src, const int* __restrict__ dst,
                          const int* __restrict__ rowptr, int* __restrict__ cursor,
                          int* __restrict__ col, int* __restrict__ dstv, int e) {
    int i = blockIdx.x * blockDim.x + threadIdx.x;
    if (i < e) {
        int d = dst[i];
        int pos = rowptr[d] + atomicAdd(&cursor[d], 1);
        col[pos] = src[i];
        dstv[pos] = d;
    }
}

// ---------------- per-edge scores in CSR order, head-transposed (layers 1&2) ----------
__global__ void k_escore(const int* __restrict__ col, const int* __restrict__ dstv,
                         const float* __restrict__ s_src, const float* __restrict__ s_dst,
                         float* __restrict__ escT, int e) {
    int i = blockIdx.x * blockDim.x + threadIdx.x;
    if (i >= e) return;
    int s = col[i], d = dstv[i];
    float4 ss = *(const float4*)(s_src + (size_t)s * 4);
    float4 ds = *(const float4*)(s_dst + (size_t)d * 4);
    escT[i]         = lrelu(ss.x + ds.x);
    escT[e + i]     = lrelu(ss.y + ds.y);
    escT[2 * e + i] = lrelu(ss.z + ds.z);
    escT[3 * e + i] = lrelu(ss.w + ds.w);
}

// layer-3 scores (H=1)
__global__ void k_escore3(const int* __restrict__ col, const int* __restrict__ dstv,
                          const float* __restrict__ s_src, const float* __restrict__ s_dst,
                          float* __restrict__ esc, int e) {
    int i = blockIdx.x * blockDim.x + threadIdx.x;
    if (i >= e) return;
    esc[i] = lrelu(s_src[col[i]] + s_dst[dstv[i]]);
}

// ---------------- MFMA GEMM: C[M,256] = A[M,K] @ Bt[256,K]^T (bf16 in/out) ----------
static __device__ __forceinline__ int swz(int r, int lc) {
    return r * 4 + (lc ^ (r & 3) ^ ((r >> 2) & 1));
}

__global__ __launch_bounds__(256) void k_gemm_mfma(const unsigned short* __restrict__ A,
                                                   const unsigned short* __restrict__ Bt,
                                                   unsigned short* __restrict__ C,
                                                   int M, int K) {
    const int N = 256;
    __shared__ unsigned short Asm[128 * 32];
    __shared__ unsigned short Bsm[128 * 32];
    int tid = threadIdx.x;
    int lane = tid & 63, wid = tid >> 6;
    int bx = blockIdx.x & 1, by = blockIdx.x >> 1;
    int row0 = by * 128, col0 = bx * 128;
    int wr = wid >> 1, wc = wid & 1;
    f32x4 acc[4][4] = {};

    for (int k0 = 0; k0 < K; k0 += 32) {
        __syncthreads();
        #pragma unroll
        for (int s = 0; s < 2; s++) {
            int c = tid + s * 256;
            int row = c >> 2, lc = c & 3;
            int gr = row0 + row; if (gr >= M) gr = 0;
            uint4 va = *(const uint4*)(A + (size_t)gr * K + k0 + lc * 8);
            *(uint4*)(&Asm[swz(row, lc) * 8]) = va;
            uint4 vb = *(const uint4*)(Bt + (size_t)(col0 + row) * K + k0 + lc * 8);
            *(uint4*)(&Bsm[swz(row, lc) * 8]) = vb;
        }
        __syncthreads();
        short8v af[4], bf[4];
        int lq = lane >> 4;
        #pragma unroll
        for (int m = 0; m < 4; m++) {
            int r = wr * 64 + m * 16 + (lane & 15);
            af[m] = *(const short8v*)(&Asm[swz(r, lq) * 8]);
        }
        #pragma unroll
        for (int n = 0; n < 4; n++) {
            int r = wc * 64 + n * 16 + (lane & 15);
            bf[n] = *(const short8v*)(&Bsm[swz(r, lq) * 8]);
        }
        #pragma unroll
        for (int m = 0; m < 4; m++)
            #pragma unroll
            for (int n = 0; n < 4; n++)
                acc[m][n] = __builtin_amdgcn_mfma_f32_16x16x32_bf16(af[m], bf[n], acc[m][n], 0, 0, 0);
    }

    #pragma unroll
    for (int m = 0; m < 4; m++) {
        #pragma unroll
        for (int r = 0; r < 4; r++) {
            int row = row0 + wr * 64 + m * 16 + (lane >> 4) * 4 + r;
            if (row < M) {
                #pragma unroll
                for (int n = 0; n < 4; n++) {
                    C[(size_t)row * N + col0 + wc * 64 + n * 16 + (lane & 15)] = f2b(acc[m][n][r]);
                }
            }
        }
    }
}

// ---------------- attention scores s_src/s_dst (per node), layers 1&2 ----------------
__global__ void k_scores(const unsigned short* __restrict__ h, const float* __restrict__ a_src,
                         const float* __restrict__ a_dst, float* __restrict__ s_src,
                         float* __restrict__ s_dst, int n) {
    int wave = (blockIdx.x * blockDim.x + threadIdx.x) >> 6;
    int lane = threadIdx.x & 63;
    if (wave >= n) return;
    ushort4 hv  = *(const ushort4*)(h + (size_t)wave * 256 + lane * 4);
    float4 av1 = *(const float4*)(a_src + lane * 4);
    float4 av2 = *(const float4*)(a_dst + lane * 4);
    float h0 = b2f(hv.x), h1 = b2f(hv.y), h2 = b2f(hv.z), h3 = b2f(hv.w);
    float ps = h0 * av1.x + h1 * av1.y + h2 * av1.z + h3 * av1.w;
    float pd = h0 * av2.x + h1 * av2.y + h2 * av2.z + h3 * av2.w;
    #pragma unroll
    for (int off = 1; off < 16; off <<= 1) {
        ps += __shfl_xor(ps, off);
        pd += __shfl_xor(pd, off);
    }
    if ((lane & 15) == 0) {
        int head = lane >> 4;
        s_src[wave * 4 + head] = ps;
        s_dst[wave * 4 + head] = pd;
    }
}

// ---------------- single-pass segment-softmax + aggregation, layers 1&2 ----------------
// wave per node, lane = feature chunk (4 bf16). Max via lane-parallel sweep of
// contiguous CSR-ordered scores; accumulate pass reads scores sequentially.
__global__ void k_aggregate(const unsigned short* __restrict__ h, const int* __restrict__ rowptr,
                            const int* __restrict__ col, const float* __restrict__ escT,
                            const float* __restrict__ s_src, const float* __restrict__ s_dst,
                            const float* __restrict__ bias,
                            unsigned short* __restrict__ out, int n, int e) {
    int wave = (blockIdx.x * blockDim.x + threadIdx.x) >> 6;
    int lane = threadIdx.x & 63;
    if (wave >= n) return;
    int head = lane >> 4, c16 = lane & 15;
    int f0 = lane * 4;
    const float* esc = escT + (size_t)head * e;
    int rs = rowptr[wave], re = rowptr[wave + 1];

    // pass A: lane-parallel max over this node's contiguous score segment
    float mx = -INFINITY;
    for (int i = rs + c16; i < re; i += 16) mx = fmaxf(mx, esc[i]);
    #pragma unroll
    for (int off = 1; off < 16; off <<= 1) mx = fmaxf(mx, __shfl_xor(mx, off));
    float sd = s_dst[wave * 4 + head];
    float selfsc = lrelu(s_src[wave * 4 + head] + sd);
    float m = fmaxf(mx, selfsc);

    // pass B: single accumulate pass
    float z = 0.f;
    float a0 = 0.f, a1 = 0.f, a2 = 0.f, a3 = 0.f;
    {
        float p = __expf(selfsc - m);
        z += p;
        ushort4 hv = *(const ushort4*)(h + (size_t)wave * 256 + f0);
        a0 += p * b2f(hv.x); a1 += p * b2f(hv.y); a2 += p * b2f(hv.z); a3 += p * b2f(hv.w);
    }
    int i = rs;
    for (; i + 4 <= re; i += 4) {
        int s0 = col[i], s1 = col[i + 1], s2 = col[i + 2], s3 = col[i + 3];
        float e0 = esc[i], e1 = esc[i + 1], e2 = esc[i + 2], e3 = esc[i + 3];
        ushort4 h0 = *(const ushort4*)(h + (size_t)s0 * 256 + f0);
        ushort4 h1 = *(const ushort4*)(h + (size_t)s1 * 256 + f0);
        ushort4 h2 = *(const ushort4*)(h + (size_t)s2 * 256 + f0);
        ushort4 h3 = *(const ushort4*)(h + (size_t)s3 * 256 + f0);
        float p0 = __expf(e0 - m), p1 = __expf(e1 - m), p2 = __expf(e2 - m), p3 = __expf(e3 - m);
        z += (p0 + p1) + (p2 + p3);
        a0 += p0 * b2f(h0.x) + p1 * b2f(h1.x) + p2 * b2f(h2.x) + p3 * b2f(h3.x);
        a1 += p0 * b2f(h0.y) + p1 * b2f(h1.y) + p2 * b2f(h2.y) + p3 * b2f(h3.y);
        a2 += p0 * b2f(h0.z) + p1 * b2f(h1.z) + p2 * b2f(h2.z) + p3 * b2f(h3.z);
        a3 += p0 * b2f(h0.w) + p1 * b2f(h1.w) + p2 * b2f(h2.w) + p3 * b2f(h3.w);
    }
    for (; i < re; i++) {
        int s = col[i];
        float p = __expf(esc[i] - m);
        z += p;
        ushort4 hv = *(const ushort4*)(h + (size_t)s * 256 + f0);
        a0 += p * b2f(hv.x); a1 += p * b2f(hv.y); a2 += p * b2f(hv.z); a3 += p * b2f(hv.w);
    }
    float inv = 1.f / z;
    float4 bv = *(const float4*)(bias + f0);
    float o0 = a0 * inv + bv.x;
    float o1 = a1 * inv + bv.y;
    float o2 = a2 * inv + bv.z;
    float o3 = a3 * inv + bv.w;
    o0 = o0 > 0.f ? o0 : expm1f(o0);
    o1 = o1 > 0.f ? o1 : expm1f(o1);
    o2 = o2 > 0.f ? o2 : expm1f(o2);
    o3 = o3 > 0.f ? o3 : expm1f(o3);
    ushort4 ov = { f2b(o0), f2b(o1), f2b(o2), f2b(o3) };
    *(ushort4*)(out + (size_t)wave * 256 + f0) = ov;
}

// ---------------- layer 3: GEMM [M,256](bf16) @ [256,16](f32) -> f32 ----------------
__global__ __launch_bounds__(256) void k_gemm3(const unsigned short* __restrict__ A,
                                               const float* __restrict__ B,
                                               float* __restrict__ C, int M, int K) {
    __shared__ float Bs[256 * 16];
    for (int i = threadIdx.x; i < K * 16; i += 256) Bs[i] = B[i];
    __syncthreads();
    int tx = threadIdx.x & 15;
    int ty = threadIdx.x >> 4;
    int row = blockIdx.x * 16 + ty;
    if (row >= M) return;
    const unsigned short* Ar = A + (size_t)row * K;
    float acc = 0.f;
    for (int kk = 0; kk < K; kk += 8) {
        uint4 va = *(const uint4*)(Ar + kk);
        const unsigned* u = (const unsigned*)&va;
        #pragma unroll
        for (int j = 0; j < 4; j++) {
            float lo = __uint_as_float(u[j] << 16);
            float hi = __uint_as_float(u[j] & 0xffff0000u);
            acc += lo * Bs[(kk + 2 * j) * 16 + tx] + hi * Bs[(kk + 2 * j + 1) * 16 + tx];
        }
    }
    C[(size_t)row * 16 + tx] = acc;
}

// ---------------- layer 3 scores (H=1, D=16) ----------------
__global__ void k_scores3(const float* __restrict__ h3, const float* __restrict__ a_src,
                          const float* __restrict__ a_dst, float* __restrict__ s_src,
                          float* __restrict__ s_dst, int n) {
    int i = blockIdx.x * blockDim.x + threadIdx.x;
    if (i >= n) return;
    float ps = 0.f, pd = 0.f;
    #pragma unroll
    for (int c = 0; c < 16; c++) {
        float v = h3[(size_t)i * 16 + c];
        ps += v * a_src[c];
        pd += v * a_dst[c];
    }
    s_src[i] = ps;
    s_dst[i] = pd;
}

// ---------------- layer 3 aggregation + bias + log_softmax ----------------
__global__ void k_agg3(const float* __restrict__ h3, const int* __restrict__ rowptr,
                       const int* __restrict__ col, const float* __restrict__ esc,
                       const float* __restrict__ s_src, const float* __restrict__ s_dst,
                       const float* __restrict__ b3,
                       float* __restrict__ outp, int n) {
    int wave = (blockIdx.x * blockDim.x + threadIdx.x) >> 6;
    int lane = threadIdx.x & 63;
    if (wave >= n) return;
    int g = lane >> 4, c = lane & 15;
    int rs = rowptr[wave], re = rowptr[wave + 1];

    float mx = -INFINITY;
    for (int i = rs + lane; i < re; i += 64) mx = fmaxf(mx, esc[i]);
    #pragma unroll
    for (int off = 1; off < 64; off <<= 1) mx = fmaxf(mx, __shfl_xor(mx, off));
    float selfsc = lrelu(s_src[wave] + s_dst[wave]);
    float m = fmaxf(mx, selfsc);

    float z = 0.f, acc = 0.f;
    if (g == 0) {
        float p = __expf(selfsc - m);
        z += p;
        acc += p * h3[(size_t)wave * 16 + c];
    }
    for (int i = rs + g; i < re; i += 4) {
        int s = col[i];
        float p = __expf(esc[i] - m);
        z += p;
        acc += p * h3[(size_t)s * 16 + c];
    }
    z += __shfl_xor(z, 16);  z += __shfl_xor(z, 32);
    acc += __shfl_xor(acc, 16); acc += __shfl_xor(acc, 32);
    if (lane < 16) {
        float v = acc / z + b3[c];
        float mm = v;
        #pragma unroll
        for (int off = 1; off < 16; off <<= 1) mm = fmaxf(mm, __shfl_xor(mm, off));
        float se = __expf(v - mm);
        #pragma unroll
        for (int off = 1; off < 16; off <<= 1) se += __shfl_xor(se, off);
        outp[(size_t)wave * 16 + c] = v - mm - logf(se);
    }
}

extern "C" void kernel_launch(void* const* d_in, const int* in_sizes, int n_in,
                              void* d_out, int out_size, void* d_ws, size_t ws_size,
                              hipStream_t stream) {
    const float* x      = (const float*)d_in[0];
    const int*   ei     = (const int*)d_in[1];
    const float* W1     = (const float*)d_in[2];
    const float* a1_src = (const float*)d_in[3];
    const float* a1_dst = (const float*)d_in[4];
    const float* b1     = (const float*)d_in[5];
    const float* W2     = (const float*)d_in[6];
    const float* a2_src = (const float*)d_in[7];
    const float* a2_dst = (const float*)d_in[8];
    const float* b2     = (const float*)d_in[9];
    const float* W3     = (const float*)d_in[10];
    const float* a3_src = (const float*)d_in[11];
    const float* a3_dst = (const float*)d_in[12];
    const float* b3     = (const float*)d_in[13];
    float* outp = (float*)d_out;

    const int N = N_NODES, E = N_EDGES;
    const int* src = ei;
    const int* dst = ei + E;

    char* ws = (char*)d_ws;
    size_t off = 0;
    auto alloc = [&](size_t bytes) {
        void* p = ws + off;
        off = (off + bytes + 255) & ~(size_t)255;
        return p;
    };
    int*   rowptr = (int*)alloc((N + 1) * sizeof(int));
    int*   counts = (int*)alloc(N * sizeof(int));      // reused as cursor
    int*   col    = (int*)alloc(E * sizeof(int));
    int*   dstv   = (int*)alloc(E * sizeof(int));
    int*   incl   = (int*)alloc(N * sizeof(int));
    int*   bsums  = (int*)alloc(64 * sizeof(int));
    int*   boffs  = (int*)alloc(64 * sizeof(int));
    float* s_src  = (float*)alloc((size_t)N * HEADS * sizeof(float));
    float* s_dst  = (float*)alloc((size_t)N * HEADS * sizeof(float));
    float* escT   = (float*)alloc((size_t)E * HEADS * sizeof(float));
    unsigned short* xb  = (unsigned short*)alloc((size_t)N * F_IN * sizeof(short));
    unsigned short* W1t = (unsigned short*)alloc((size_t)256 * F_IN * sizeof(short));
    unsigned short* W2t = (unsigned short*)alloc((size_t)256 * 256 * sizeof(short));
    unsigned short* hA  = (unsigned short*)alloc((size_t)N * 256 * sizeof(short));
    unsigned short* hB  = (unsigned short*)alloc((size_t)N * 256 * sizeof(short));
    float* h3     = (float*)alloc((size_t)N * 16 * sizeof(float));
    (void)ws_size;

    // ---- converts ----
    k_f2b4<<<(N * F_IN / 4 + 255) / 256, 256, 0, stream>>>(x, xb, N * F_IN / 4);
    k_wt<<<(F_IN * 256 + 255) / 256, 256, 0, stream>>>(W1, W1t, F_IN, 256);
    k_wt<<<(256 * 256 + 255) / 256, 256, 0, stream>>>(W2, W2t, 256, 256);

    // ---- CSR build (by dst) ----
    hipMemsetAsync(counts, 0, N * sizeof(int), stream);
    k_hist<<<(E + 255) / 256, 256, 0, stream>>>(dst, counts, E);
    const int nb = (N + 1023) / 1024;
    k_scan1<<<nb, 256, 0, stream>>>(counts, incl, bsums, N);
    k_scan2<<<1, 64, 0, stream>>>(bsums, boffs, nb, rowptr + N);
    k_scan3<<<(N + 255) / 256, 256, 0, stream>>>(incl, counts, boffs, rowptr, N);
    hipMemsetAsync(counts, 0, N * sizeof(int), stream);
    k_scatter<<<(E + 255) / 256, 256, 0, stream>>>(src, dst, rowptr, counts, col, dstv, E);

    const int aggBlocks = (N + 3) / 4;
    const int gemmBlocks = ((N + 127) / 128) * 2;
    const int edgeBlocks = (E + 255) / 256;

    // ---- layer 1 ----
    k_gemm_mfma<<<gemmBlocks, 256, 0, stream>>>(xb, W1t, hA, N, F_IN);
    k_scores<<<aggBlocks, 256, 0, stream>>>(hA, a1_src, a1_dst, s_src, s_dst, N);
    k_escore<<<edgeBlocks, 256, 0, stream>>>(col, dstv, s_src, s_dst, escT, E);
    k_aggregate<<<aggBlocks, 256, 0, stream>>>(hA, rowptr, col, escT, s_src, s_dst, b1, hB, N, E);
    // ---- layer 2 ----
    k_gemm_mfma<<<gemmBlocks, 256, 0, stream>>>(hB, W2t, hA, N, 256);
    k_scores<<<aggBlocks, 256, 0, stream>>>(hA, a2_src, a2_dst, s_src, s_dst, N);
    k_escore<<<edgeBlocks, 256, 0, stream>>>(col, dstv, s_src, s_dst, escT, E);
    k_aggregate<<<aggBlocks, 256, 0, stream>>>(hA, rowptr, col, escT, s_src, s_dst, b2, hB, N, E);
    // ---- layer 3 ----
    k_gemm3<<<(N + 15) / 16, 256, 0, stream>>>(hB, W3, h3, N, 256);
    k_scores3<<<(N + 255) / 256, 256, 0, stream>>>(h3, a3_src, a3_dst, s_src, s_dst, N);
    k_escore3<<<edgeBlocks, 256, 0, stream>>>(col, dstv, s_src, s_dst, escT, E);
    k_agg3<<<aggBlocks, 256, 0, stream>>>(h3, rowptr, col, escT, s_src, s_dst, b3, outp, N);
}

// Round 5
// 367.588 us; speedup vs baseline: 1.7396x; 1.0381x over previous
//
#include <hip/hip_runtime.h>
#include <hip/hip_bf16.h>
#include <math.h>

#define N_NODES 50000
#define N_EDGES 800000
#define F_IN    128
#define HID     64
#define HEADS   4
#define NCLS    16
#define NEG_SLOPE 0.2f

typedef __attribute__((ext_vector_type(8))) short short8v;
typedef __attribute__((ext_vector_type(4))) float f32x4;

static __device__ __forceinline__ float lrelu(float x) {
    return x >= 0.f ? x : NEG_SLOPE * x;
}
static __device__ __forceinline__ float b2f(unsigned short u) {
    return __uint_as_float(((unsigned)u) << 16);
}
static __device__ __forceinline__ unsigned short f2b(float f) {
    __hip_bfloat16 b = __float2bfloat16(f);
    return *(unsigned short*)&b;
}

// ---------------- converts ----------------
__global__ void k_f2b4(const float* __restrict__ in, unsigned short* __restrict__ out, int n4) {
    int i = blockIdx.x * blockDim.x + threadIdx.x;
    if (i < n4) {
        float4 v = *(const float4*)(in + i * 4);
        ushort4 o = { f2b(v.x), f2b(v.y), f2b(v.z), f2b(v.w) };
        *(ushort4*)(out + i * 4) = o;
    }
}

// Wt[c][k] = W[k][c], bf16
__global__ void k_wt(const float* __restrict__ W, unsigned short* __restrict__ Wt, int K, int N) {
    int i = blockIdx.x * blockDim.x + threadIdx.x;
    if (i < K * N) {
        int k = i / N, c = i % N;
        Wt[c * K + k] = f2b(W[i]);
    }
}

// ---------------- CSR build ----------------
__global__ void k_hist(const int* __restrict__ dst, int* __restrict__ counts, int e) {
    int i = blockIdx.x * blockDim.x + threadIdx.x;
    if (i < e) atomicAdd(&counts[dst[i]], 1);
}

__global__ __launch_bounds__(256) void k_scan1(const int* __restrict__ counts, int* __restrict__ incl,
                                               int* __restrict__ bsums, int n) {
    __shared__ int wsum[4];
    int blk = blockIdx.x, tid = threadIdx.x;
    int lane = tid & 63, w = tid >> 6;
    int i0 = blk * 1024 + tid * 4;
    int v[4];
    #pragma unroll
    for (int j = 0; j < 4; j++) v[j] = (i0 + j < n) ? counts[i0 + j] : 0;
    int t = v[0] + v[1] + v[2] + v[3];
    int x = t;
    #pragma unroll
    for (int d = 1; d < 64; d <<= 1) { int y = __shfl_up(x, d); if (lane >= d) x += y; }
    if (lane == 63) wsum[w] = x;
    __syncthreads();
    int woff = 0;
    #pragma unroll
    for (int ww = 0; ww < 4; ww++) woff += (ww < w) ? wsum[ww] : 0;
    int p = woff + x - t;
    #pragma unroll
    for (int j = 0; j < 4; j++) { p += v[j]; if (i0 + j < n) incl[i0 + j] = p; }
    if (tid == 255) bsums[blk] = woff + x;
}

__global__ void k_scan2(const int* __restrict__ bsums, int* __restrict__ boffs, int nb, int* rowptr_end) {
    int lane = threadIdx.x;
    int v = (lane < nb) ? bsums[lane] : 0;
    int x = v;
    #pragma unroll
    for (int d = 1; d < 64; d <<= 1) { int y = __shfl_up(x, d); if (lane >= d) x += y; }
    if (lane < nb) boffs[lane] = x - v;
    if (lane == 63) *rowptr_end = x;
}

__global__ void k_scan3(const int* __restrict__ incl, const int* __restrict__ counts,
                        const int* __restrict__ boffs, int* __restrict__ rowptr, int n) {
    int i = blockIdx.x * blockDim.x + threadIdx.x;
    if (i < n) rowptr[i] = boffs[i >> 10] + incl[i] - counts[i];
}

__global__ void k_scatter(const int* __restrict__ src, const int* __restrict__ dst,
                          const int* __restrict__ rowptr, int* __restrict__ cursor,
                          int* __restrict__ col, int* __restrict__ dstv, int e) {
    int i = blockIdx.x * blockDim.x + threadIdx.x;
    if (i < e) {
        int d = dst[i];
        int pos = rowptr[d] + atomicAdd(&cursor[d], 1);
        col[pos] = src[i];
        dstv[pos] = d;
    }
}

// ---------------- per-edge scores in CSR order, head-transposed (layers 1&2) ----------
__global__ void k_escore(const int* __restrict__ col, const int* __restrict__ dstv,
                         const float* __restrict__ s_src, const float* __restrict__ s_dst,
                         float* __restrict__ escT, int e) {
    int i = blockIdx.x * blockDim.x + threadIdx.x;
    if (i >= e) return;
    int s = col[i], d = dstv[i];
    float4 ss = *(const float4*)(s_src + (size_t)s * 4);
    float4 ds = *(const float4*)(s_dst + (size_t)d * 4);
    escT[i]         = lrelu(ss.x + ds.x);
    escT[e + i]     = lrelu(ss.y + ds.y);
    escT[2 * e + i] = lrelu(ss.z + ds.z);
    escT[3 * e + i] = lrelu(ss.w + ds.w);
}

// layer-3 scores (H=1)
__global__ void k_escore3(const int* __restrict__ col, const int* __restrict__ dstv,
                          const float* __restrict__ s_src, const float* __restrict__ s_dst,
                          float* __restrict__ esc, int e) {
    int i = blockIdx.x * blockDim.x + threadIdx.x;
    if (i >= e) return;
    esc[i] = lrelu(s_src[col[i]] + s_dst[dstv[i]]);
}

// ---------------- MFMA GEMM + fused per-node scores: C = A @ Bt^T ----------
// N fixed 256 (heads*hid). Wave (wr,wc) covers rows wr*64.., one head (bx*2+wc).
static __device__ __forceinline__ int swz(int r, int lc) {
    return r * 4 + (lc ^ (r & 3) ^ ((r >> 2) & 1));
}

__global__ __launch_bounds__(256) void k_gemm_mfma(const unsigned short* __restrict__ A,
                                                   const unsigned short* __restrict__ Bt,
                                                   const float* __restrict__ asrc,
                                                   const float* __restrict__ adst,
                                                   unsigned short* __restrict__ C,
                                                   float* __restrict__ s_src,
                                                   float* __restrict__ s_dst,
                                                   int M, int K) {
    const int N = 256;
    __shared__ unsigned short Asm[128 * 32];
    __shared__ unsigned short Bsm[128 * 32];
    int tid = threadIdx.x;
    int lane = tid & 63, wid = tid >> 6;
    int bx = blockIdx.x & 1, by = blockIdx.x >> 1;
    int row0 = by * 128, col0 = bx * 128;
    int wr = wid >> 1, wc = wid & 1;
    f32x4 acc[4][4] = {};

    for (int k0 = 0; k0 < K; k0 += 32) {
        __syncthreads();
        #pragma unroll
        for (int s = 0; s < 2; s++) {
            int c = tid + s * 256;
            int row = c >> 2, lc = c & 3;
            int gr = row0 + row; if (gr >= M) gr = 0;
            uint4 va = *(const uint4*)(A + (size_t)gr * K + k0 + lc * 8);
            *(uint4*)(&Asm[swz(row, lc) * 8]) = va;
            uint4 vb = *(const uint4*)(Bt + (size_t)(col0 + row) * K + k0 + lc * 8);
            *(uint4*)(&Bsm[swz(row, lc) * 8]) = vb;
        }
        __syncthreads();
        short8v af[4], bf[4];
        int lq = lane >> 4;
        #pragma unroll
        for (int m = 0; m < 4; m++) {
            int r = wr * 64 + m * 16 + (lane & 15);
            af[m] = *(const short8v*)(&Asm[swz(r, lq) * 8]);
        }
        #pragma unroll
        for (int n = 0; n < 4; n++) {
            int r = wc * 64 + n * 16 + (lane & 15);
            bf[n] = *(const short8v*)(&Bsm[swz(r, lq) * 8]);
        }
        #pragma unroll
        for (int m = 0; m < 4; m++)
            #pragma unroll
            for (int n = 0; n < 4; n++)
                acc[m][n] = __builtin_amdgcn_mfma_f32_16x16x32_bf16(af[m], bf[n], acc[m][n], 0, 0, 0);
    }

    // C write (bf16)
    #pragma unroll
    for (int m = 0; m < 4; m++) {
        #pragma unroll
        for (int r = 0; r < 4; r++) {
            int row = row0 + wr * 64 + m * 16 + (lane >> 4) * 4 + r;
            if (row < M) {
                #pragma unroll
                for (int n = 0; n < 4; n++) {
                    C[(size_t)row * N + col0 + wc * 64 + n * 16 + (lane & 15)] = f2b(acc[m][n][r]);
                }
            }
        }
    }

    // fused attention scores: this wave's 64 cols = head (bx*2+wc)
    {
        int c16 = lane & 15, lq = lane >> 4;
        int head = bx * 2 + wc;
        float avs[4], avd[4];
        #pragma unroll
        for (int nn = 0; nn < 4; nn++) {
            avs[nn] = asrc[head * 64 + nn * 16 + c16];
            avd[nn] = adst[head * 64 + nn * 16 + c16];
        }
        #pragma unroll
        for (int mm = 0; mm < 4; mm++) {
            #pragma unroll
            for (int r = 0; r < 4; r++) {
                float ps = 0.f, pd = 0.f;
                #pragma unroll
                for (int nn = 0; nn < 4; nn++) {
                    ps += acc[mm][nn][r] * avs[nn];
                    pd += acc[mm][nn][r] * avd[nn];
                }
                #pragma unroll
                for (int off = 1; off < 16; off <<= 1) {
                    ps += __shfl_xor(ps, off);
                    pd += __shfl_xor(pd, off);
                }
                if (c16 == 0) {
                    int grow = row0 + wr * 64 + mm * 16 + lq * 4 + r;
                    if (grow < M) {
                        s_src[grow * 4 + head] = ps;
                        s_dst[grow * 4 + head] = pd;
                    }
                }
            }
        }
    }
}

// ---------------- single-pass segment-softmax + aggregation, layers 1&2 ----------------
// wave per node; 2 edges in flight: half = lane>>5 handles edges rs+half, +2, ...
// each lane owns 8 features (16B load). Final shfl_xor(…,32) merges halves.
__global__ void k_aggregate(const unsigned short* __restrict__ h, const int* __restrict__ rowptr,
                            const int* __restrict__ col, const float* __restrict__ escT,
                            const float* __restrict__ s_src, const float* __restrict__ s_dst,
                            const float* __restrict__ bias,
                            unsigned short* __restrict__ out, int n, int e) {
    int wave = (blockIdx.x * blockDim.x + threadIdx.x) >> 6;
    int lane = threadIdx.x & 63;
    if (wave >= n) return;
    int half = lane >> 5, l5 = lane & 31;
    int head = l5 >> 3;          // 8 lanes x 8 feats = 64 feats per head
    int f0 = l5 * 8;
    const float* esc = escT + (size_t)head * e;
    int rs = rowptr[wave], re = rowptr[wave + 1];

    // max over this head's contiguous score segment (16 lanes per head)
    float mx = -INFINITY;
    for (int i = rs + (l5 & 7) + half * 8; i < re; i += 16) mx = fmaxf(mx, esc[i]);
    mx = fmaxf(mx, __shfl_xor(mx, 1));
    mx = fmaxf(mx, __shfl_xor(mx, 2));
    mx = fmaxf(mx, __shfl_xor(mx, 4));
    mx = fmaxf(mx, __shfl_xor(mx, 32));
    float selfsc = lrelu(s_src[wave * 4 + head] + s_dst[wave * 4 + head]);
    float m = fmaxf(mx, selfsc);

    float z = 0.f;
    float a[8] = {};
    if (half == 0) {
        float p = __expf(selfsc - m);
        z += p;
        uint4 hv = *(const uint4*)(h + (size_t)wave * 256 + f0);
        const unsigned* u = (const unsigned*)&hv;
        #pragma unroll
        for (int j = 0; j < 4; j++) {
            a[2 * j]     += p * __uint_as_float(u[j] << 16);
            a[2 * j + 1] += p * __uint_as_float(u[j] & 0xffff0000u);
        }
    }
    int i = rs + half;
    for (; i + 2 < re; i += 4) {
        int s0 = col[i], s1 = col[i + 2];
        float p0 = __expf(esc[i] - m), p1 = __expf(esc[i + 2] - m);
        uint4 h0 = *(const uint4*)(h + (size_t)s0 * 256 + f0);
        uint4 h1 = *(const uint4*)(h + (size_t)s1 * 256 + f0);
        const unsigned* u0 = (const unsigned*)&h0;
        const unsigned* u1 = (const unsigned*)&h1;
        z += p0 + p1;
        #pragma unroll
        for (int j = 0; j < 4; j++) {
            a[2 * j]     += p0 * __uint_as_float(u0[j] << 16)
                          + p1 * __uint_as_float(u1[j] << 16);
            a[2 * j + 1] += p0 * __uint_as_float(u0[j] & 0xffff0000u)
                          + p1 * __uint_as_float(u1[j] & 0xffff0000u);
        }
    }
    for (; i < re; i += 2) {
        int s0 = col[i];
        float p0 = __expf(esc[i] - m);
        uint4 h0 = *(const uint4*)(h + (size_t)s0 * 256 + f0);
        const unsigned* u0 = (const unsigned*)&h0;
        z += p0;
        #pragma unroll
        for (int j = 0; j < 4; j++) {
            a[2 * j]     += p0 * __uint_as_float(u0[j] << 16);
            a[2 * j + 1] += p0 * __uint_as_float(u0[j] & 0xffff0000u);
        }
    }
    // merge halves
    z += __shfl_xor(z, 32);
    #pragma unroll
    for (int j = 0; j < 8; j++) a[j] += __shfl_xor(a[j], 32);

    if (half == 0) {
        float inv = 1.f / z;
        float4 bv0 = *(const float4*)(bias + f0);
        float4 bv1 = *(const float4*)(bias + f0 + 4);
        float o[8];
        o[0] = a[0] * inv + bv0.x; o[1] = a[1] * inv + bv0.y;
        o[2] = a[2] * inv + bv0.z; o[3] = a[3] * inv + bv0.w;
        o[4] = a[4] * inv + bv1.x; o[5] = a[5] * inv + bv1.y;
        o[6] = a[6] * inv + bv1.z; o[7] = a[7] * inv + bv1.w;
        #pragma unroll
        for (int j = 0; j < 8; j++) o[j] = o[j] > 0.f ? o[j] : expm1f(o[j]);
        uint4 ov;
        unsigned* w = (unsigned*)&ov;
        #pragma unroll
        for (int j = 0; j < 4; j++)
            w[j] = (unsigned)f2b(o[2 * j]) | ((unsigned)f2b(o[2 * j + 1]) << 16);
        *(uint4*)(out + (size_t)wave * 256 + f0) = ov;
    }
}

// ---------------- layer 3: GEMM [M,256](bf16)@[256,16](f32) + fused scores ----------
__global__ __launch_bounds__(256) void k_gemm3(const unsigned short* __restrict__ A,
                                               const float* __restrict__ B,
                                               const float* __restrict__ a3s,
                                               const float* __restrict__ a3d,
                                               float* __restrict__ C,
                                               float* __restrict__ s_src,
                                               float* __restrict__ s_dst,
                                               int M, int K) {
    __shared__ float Bs[256 * 16];
    for (int i = threadIdx.x; i < K * 16; i += 256) Bs[i] = B[i];
    __syncthreads();
    int tx = threadIdx.x & 15;
    int ty = threadIdx.x >> 4;
    int row = blockIdx.x * 16 + ty;
    if (row >= M) return;   // M % 16 == 0, never diverges within a block
    const unsigned short* Ar = A + (size_t)row * K;
    float acc = 0.f;
    for (int kk = 0; kk < K; kk += 8) {
        uint4 va = *(const uint4*)(Ar + kk);
        const unsigned* u = (const unsigned*)&va;
        #pragma unroll
        for (int j = 0; j < 4; j++) {
            float lo = __uint_as_float(u[j] << 16);
            float hi = __uint_as_float(u[j] & 0xffff0000u);
            acc += lo * Bs[(kk + 2 * j) * 16 + tx] + hi * Bs[(kk + 2 * j + 1) * 16 + tx];
        }
    }
    C[(size_t)row * 16 + tx] = acc;
    float ps = acc * a3s[tx], pd = acc * a3d[tx];
    #pragma unroll
    for (int off = 1; off < 16; off <<= 1) {
        ps += __shfl_xor(ps, off);
        pd += __shfl_xor(pd, off);
    }
    if (tx == 0) { s_src[row] = ps; s_dst[row] = pd; }
}

// ---------------- layer 3 aggregation + bias + log_softmax ----------------
__global__ void k_agg3(const float* __restrict__ h3, const int* __restrict__ rowptr,
                       const int* __restrict__ col, const float* __restrict__ esc,
                       const float* __restrict__ s_src, const float* __restrict__ s_dst,
                       const float* __restrict__ b3,
                       float* __restrict__ outp, int n) {
    int wave = (blockIdx.x * blockDim.x + threadIdx.x) >> 6;
    int lane = threadIdx.x & 63;
    if (wave >= n) return;
    int g = lane >> 4, c = lane & 15;
    int rs = rowptr[wave], re = rowptr[wave + 1];

    float mx = -INFINITY;
    for (int i = rs + lane; i < re; i += 64) mx = fmaxf(mx, esc[i]);
    #pragma unroll
    for (int off = 1; off < 64; off <<= 1) mx = fmaxf(mx, __shfl_xor(mx, off));
    float selfsc = lrelu(s_src[wave] + s_dst[wave]);
    float m = fmaxf(mx, selfsc);

    float z = 0.f, acc = 0.f;
    if (g == 0) {
        float p = __expf(selfsc - m);
        z += p;
        acc += p * h3[(size_t)wave * 16 + c];
    }
    for (int i = rs + g; i < re; i += 4) {
        int s = col[i];
        float p = __expf(esc[i] - m);
        z += p;
        acc += p * h3[(size_t)s * 16 + c];
    }
    z += __shfl_xor(z, 16);  z += __shfl_xor(z, 32);
    acc += __shfl_xor(acc, 16); acc += __shfl_xor(acc, 32);
    if (lane < 16) {
        float v = acc / z + b3[c];
        float mm = v;
        #pragma unroll
        for (int off = 1; off < 16; off <<= 1) mm = fmaxf(mm, __shfl_xor(mm, off));
        float se = __expf(v - mm);
        #pragma unroll
        for (int off = 1; off < 16; off <<= 1) se += __shfl_xor(se, off);
        outp[(size_t)wave * 16 + c] = v - mm - logf(se);
    }
}

extern "C" void kernel_launch(void* const* d_in, const int* in_sizes, int n_in,
                              void* d_out, int out_size, void* d_ws, size_t ws_size,
                              hipStream_t stream) {
    const float* x      = (const float*)d_in[0];
    const int*   ei     = (const int*)d_in[1];
    const float* W1     = (const float*)d_in[2];
    const float* a1_src = (const float*)d_in[3];
    const float* a1_dst = (const float*)d_in[4];
    const float* b1     = (const float*)d_in[5];
    const float* W2     = (const float*)d_in[6];
    const float* a2_src = (const float*)d_in[7];
    const float* a2_dst = (const float*)d_in[8];
    const float* b2     = (const float*)d_in[9];
    const float* W3     = (const float*)d_in[10];
    const float* a3_src = (const float*)d_in[11];
    const float* a3_dst = (const float*)d_in[12];
    const float* b3     = (const float*)d_in[13];
    float* outp = (float*)d_out;

    const int N = N_NODES, E = N_EDGES;
    const int* src = ei;
    const int* dst = ei + E;

    char* ws = (char*)d_ws;
    size_t off = 0;
    auto alloc = [&](size_t bytes) {
        void* p = ws + off;
        off = (off + bytes + 255) & ~(size_t)255;
        return p;
    };
    int*   rowptr = (int*)alloc((N + 1) * sizeof(int));
    int*   counts = (int*)alloc(N * sizeof(int));      // reused as cursor
    int*   col    = (int*)alloc(E * sizeof(int));
    int*   dstv   = (int*)alloc(E * sizeof(int));
    int*   incl   = (int*)alloc(N * sizeof(int));
    int*   bsums  = (int*)alloc(64 * sizeof(int));
    int*   boffs  = (int*)alloc(64 * sizeof(int));
    float* s_src  = (float*)alloc((size_t)N * HEADS * sizeof(float));
    float* s_dst  = (float*)alloc((size_t)N * HEADS * sizeof(float));
    float* escT   = (float*)alloc((size_t)E * HEADS * sizeof(float));
    unsigned short* xb  = (unsigned short*)alloc((size_t)N * F_IN * sizeof(short));
    unsigned short* W1t = (unsigned short*)alloc((size_t)256 * F_IN * sizeof(short));
    unsigned short* W2t = (unsigned short*)alloc((size_t)256 * 256 * sizeof(short));
    unsigned short* hA  = (unsigned short*)alloc((size_t)N * 256 * sizeof(short));
    unsigned short* hB  = (unsigned short*)alloc((size_t)N * 256 * sizeof(short));
    float* h3     = (float*)alloc((size_t)N * 16 * sizeof(float));
    (void)ws_size;

    // ---- converts ----
    k_f2b4<<<(N * F_IN / 4 + 255) / 256, 256, 0, stream>>>(x, xb, N * F_IN / 4);
    k_wt<<<(F_IN * 256 + 255) / 256, 256, 0, stream>>>(W1, W1t, F_IN, 256);
    k_wt<<<(256 * 256 + 255) / 256, 256, 0, stream>>>(W2, W2t, 256, 256);

    // ---- CSR build (by dst) ----
    hipMemsetAsync(counts, 0, N * sizeof(int), stream);
    k_hist<<<(E + 255) / 256, 256, 0, stream>>>(dst, counts, E);
    const int nb = (N + 1023) / 1024;
    k_scan1<<<nb, 256, 0, stream>>>(counts, incl, bsums, N);
    k_scan2<<<1, 64, 0, stream>>>(bsums, boffs, nb, rowptr + N);
    k_scan3<<<(N + 255) / 256, 256, 0, stream>>>(incl, counts, boffs, rowptr, N);
    hipMemsetAsync(counts, 0, N * sizeof(int), stream);
    k_scatter<<<(E + 255) / 256, 256, 0, stream>>>(src, dst, rowptr, counts, col, dstv, E);

    const int aggBlocks = (N + 3) / 4;
    const int gemmBlocks = ((N + 127) / 128) * 2;
    const int edgeBlocks = (E + 255) / 256;

    // ---- layer 1 ----
    k_gemm_mfma<<<gemmBlocks, 256, 0, stream>>>(xb, W1t, a1_src, a1_dst, hA, s_src, s_dst, N, F_IN);
    k_escore<<<edgeBlocks, 256, 0, stream>>>(col, dstv, s_src, s_dst, escT, E);
    k_aggregate<<<aggBlocks, 256, 0, stream>>>(hA, rowptr, col, escT, s_src, s_dst, b1, hB, N, E);
    // ---- layer 2 ----
    k_gemm_mfma<<<gemmBlocks, 256, 0, stream>>>(hB, W2t, a2_src, a2_dst, hA, s_src, s_dst, N, 256);
    k_escore<<<edgeBlocks, 256, 0, stream>>>(col, dstv, s_src, s_dst, escT, E);
    k_aggregate<<<aggBlocks, 256, 0, stream>>>(hA, rowptr, col, escT, s_src, s_dst, b2, hB, N, E);
    // ---- layer 3 ----
    k_gemm3<<<(N + 15) / 16, 256, 0, stream>>>(hB, W3, a3_src, a3_dst, h3, s_src, s_dst, N, 256);
    k_escore3<<<edgeBlocks, 256, 0, stream>>>(col, dstv, s_src, s_dst, escT, E);
    k_agg3<<<aggBlocks, 256, 0, stream>>>(h3, rowptr, col, escT, s_src, s_dst, b3, outp, N);
}

// Round 6
// 357.030 us; speedup vs baseline: 1.7911x; 1.0296x over previous
//
#include <hip/hip_runtime.h>
#include <hip/hip_bf16.h>
#include <math.h>

#define N_NODES 50000
#define N_EDGES 800000
#define F_IN    128
#define HID     64
#define HEADS   4
#define NCLS    16
#define NEG_SLOPE 0.2f

typedef __attribute__((ext_vector_type(8))) short short8v;
typedef __attribute__((ext_vector_type(4))) float f32x4;

static __device__ __forceinline__ float lrelu(float x) {
    return x >= 0.f ? x : NEG_SLOPE * x;
}
static __device__ __forceinline__ float b2f(unsigned short u) {
    return __uint_as_float(((unsigned)u) << 16);
}
static __device__ __forceinline__ unsigned short f2b(float f) {
    __hip_bfloat16 b = __float2bfloat16(f);
    return *(unsigned short*)&b;
}

// ---------------- converts ----------------
__global__ void k_f2b4(const float* __restrict__ in, unsigned short* __restrict__ out, int n4) {
    int i = blockIdx.x * blockDim.x + threadIdx.x;
    if (i < n4) {
        float4 v = *(const float4*)(in + i * 4);
        ushort4 o = { f2b(v.x), f2b(v.y), f2b(v.z), f2b(v.w) };
        *(ushort4*)(out + i * 4) = o;
    }
}

// Wt[c][k] = W[k][c], bf16
__global__ void k_wt(const float* __restrict__ W, unsigned short* __restrict__ Wt, int K, int N) {
    int i = blockIdx.x * blockDim.x + threadIdx.x;
    if (i < K * N) {
        int k = i / N, c = i % N;
        Wt[c * K + k] = f2b(W[i]);
    }
}

// ---------------- CSR build ----------------
__global__ void k_hist(const int* __restrict__ dst, int* __restrict__ counts, int e) {
    int i = blockIdx.x * blockDim.x + threadIdx.x;
    if (i < e) atomicAdd(&counts[dst[i]], 1);
}

__global__ __launch_bounds__(256) void k_scan1(const int* __restrict__ counts, int* __restrict__ incl,
                                               int* __restrict__ bsums, int n) {
    __shared__ int wsum[4];
    int blk = blockIdx.x, tid = threadIdx.x;
    int lane = tid & 63, w = tid >> 6;
    int i0 = blk * 1024 + tid * 4;
    int v[4];
    #pragma unroll
    for (int j = 0; j < 4; j++) v[j] = (i0 + j < n) ? counts[i0 + j] : 0;
    int t = v[0] + v[1] + v[2] + v[3];
    int x = t;
    #pragma unroll
    for (int d = 1; d < 64; d <<= 1) { int y = __shfl_up(x, d); if (lane >= d) x += y; }
    if (lane == 63) wsum[w] = x;
    __syncthreads();
    int woff = 0;
    #pragma unroll
    for (int ww = 0; ww < 4; ww++) woff += (ww < w) ? wsum[ww] : 0;
    int p = woff + x - t;
    #pragma unroll
    for (int j = 0; j < 4; j++) { p += v[j]; if (i0 + j < n) incl[i0 + j] = p; }
    if (tid == 255) bsums[blk] = woff + x;
}

__global__ void k_scan2(const int* __restrict__ bsums, int* __restrict__ boffs, int nb, int* rowptr_end) {
    int lane = threadIdx.x;
    int v = (lane < nb) ? bsums[lane] : 0;
    int x = v;
    #pragma unroll
    for (int d = 1; d < 64; d <<= 1) { int y = __shfl_up(x, d); if (lane >= d) x += y; }
    if (lane < nb) boffs[lane] = x - v;
    if (lane == 63) *rowptr_end = x;
}

__global__ void k_scan3(const int* __restrict__ incl, const int* __restrict__ counts,
                        const int* __restrict__ boffs, int* __restrict__ rowptr, int n) {
    int i = blockIdx.x * blockDim.x + threadIdx.x;
    if (i < n) rowptr[i] = boffs[i >> 10] + incl[i] - counts[i];
}

// scatter packed (src | dst<<16); 2 edges per thread (independent atomic chains)
__global__ void k_scatter(const int* __restrict__ src, const int* __restrict__ dst,
                          const int* __restrict__ rowptr, int* __restrict__ cursor,
                          unsigned* __restrict__ colp, int e) {
    int half = (e + 1) >> 1;
    int i = blockIdx.x * blockDim.x + threadIdx.x;
    if (i < half) {
        int d = dst[i];
        int pos = rowptr[d] + atomicAdd(&cursor[d], 1);
        colp[pos] = (unsigned)src[i] | ((unsigned)d << 16);
    }
    int j = i + half;
    if (j < e) {
        int d = dst[j];
        int pos = rowptr[d] + atomicAdd(&cursor[d], 1);
        colp[pos] = (unsigned)src[j] | ((unsigned)d << 16);
    }
}

// ---------------- per-edge scores in CSR order, head-transposed (layers 1&2) ----------
__global__ void k_escore(const unsigned* __restrict__ colp,
                         const float* __restrict__ s_src, const float* __restrict__ s_dst,
                         float* __restrict__ escT, int e) {
    int i = blockIdx.x * blockDim.x + threadIdx.x;
    if (i >= e) return;
    unsigned v = colp[i];
    int s = v & 0xffff, d = v >> 16;
    float4 ss = *(const float4*)(s_src + (size_t)s * 4);
    float4 ds = *(const float4*)(s_dst + (size_t)d * 4);
    escT[i]         = lrelu(ss.x + ds.x);
    escT[e + i]     = lrelu(ss.y + ds.y);
    escT[2 * e + i] = lrelu(ss.z + ds.z);
    escT[3 * e + i] = lrelu(ss.w + ds.w);
}

// layer-3 scores (H=1)
__global__ void k_escore3(const unsigned* __restrict__ colp,
                          const float* __restrict__ s_src, const float* __restrict__ s_dst,
                          float* __restrict__ esc, int e) {
    int i = blockIdx.x * blockDim.x + threadIdx.x;
    if (i >= e) return;
    unsigned v = colp[i];
    esc[i] = lrelu(s_src[v & 0xffff] + s_dst[v >> 16]);
}

// ---------------- MFMA GEMM + fused per-node scores: C = A @ Bt^T ----------
static __device__ __forceinline__ int swz(int r, int lc) {
    return r * 4 + (lc ^ (r & 3) ^ ((r >> 2) & 1));
}

__global__ __launch_bounds__(256) void k_gemm_mfma(const unsigned short* __restrict__ A,
                                                   const unsigned short* __restrict__ Bt,
                                                   const float* __restrict__ asrc,
                                                   const float* __restrict__ adst,
                                                   unsigned short* __restrict__ C,
                                                   float* __restrict__ s_src,
                                                   float* __restrict__ s_dst,
                                                   int M, int K) {
    const int N = 256;
    __shared__ unsigned short Asm[128 * 32];
    __shared__ unsigned short Bsm[128 * 32];
    int tid = threadIdx.x;
    int lane = tid & 63, wid = tid >> 6;
    int bx = blockIdx.x & 1, by = blockIdx.x >> 1;
    int row0 = by * 128, col0 = bx * 128;
    int wr = wid >> 1, wc = wid & 1;
    f32x4 acc[4][4] = {};

    for (int k0 = 0; k0 < K; k0 += 32) {
        __syncthreads();
        #pragma unroll
        for (int s = 0; s < 2; s++) {
            int c = tid + s * 256;
            int row = c >> 2, lc = c & 3;
            int gr = row0 + row; if (gr >= M) gr = 0;
            uint4 va = *(const uint4*)(A + (size_t)gr * K + k0 + lc * 8);
            *(uint4*)(&Asm[swz(row, lc) * 8]) = va;
            uint4 vb = *(const uint4*)(Bt + (size_t)(col0 + row) * K + k0 + lc * 8);
            *(uint4*)(&Bsm[swz(row, lc) * 8]) = vb;
        }
        __syncthreads();
        short8v af[4], bf[4];
        int lq = lane >> 4;
        #pragma unroll
        for (int m = 0; m < 4; m++) {
            int r = wr * 64 + m * 16 + (lane & 15);
            af[m] = *(const short8v*)(&Asm[swz(r, lq) * 8]);
        }
        #pragma unroll
        for (int n = 0; n < 4; n++) {
            int r = wc * 64 + n * 16 + (lane & 15);
            bf[n] = *(const short8v*)(&Bsm[swz(r, lq) * 8]);
        }
        #pragma unroll
        for (int m = 0; m < 4; m++)
            #pragma unroll
            for (int n = 0; n < 4; n++)
                acc[m][n] = __builtin_amdgcn_mfma_f32_16x16x32_bf16(af[m], bf[n], acc[m][n], 0, 0, 0);
    }

    // C write (bf16)
    #pragma unroll
    for (int m = 0; m < 4; m++) {
        #pragma unroll
        for (int r = 0; r < 4; r++) {
            int row = row0 + wr * 64 + m * 16 + (lane >> 4) * 4 + r;
            if (row < M) {
                #pragma unroll
                for (int n = 0; n < 4; n++) {
                    C[(size_t)row * N + col0 + wc * 64 + n * 16 + (lane & 15)] = f2b(acc[m][n][r]);
                }
            }
        }
    }

    // fused attention scores: this wave's 64 cols = head (bx*2+wc)
    {
        int c16 = lane & 15, lq = lane >> 4;
        int head = bx * 2 + wc;
        float avs[4], avd[4];
        #pragma unroll
        for (int nn = 0; nn < 4; nn++) {
            avs[nn] = asrc[head * 64 + nn * 16 + c16];
            avd[nn] = adst[head * 64 + nn * 16 + c16];
        }
        #pragma unroll
        for (int mm = 0; mm < 4; mm++) {
            #pragma unroll
            for (int r = 0; r < 4; r++) {
                float ps = 0.f, pd = 0.f;
                #pragma unroll
                for (int nn = 0; nn < 4; nn++) {
                    ps += acc[mm][nn][r] * avs[nn];
                    pd += acc[mm][nn][r] * avd[nn];
                }
                #pragma unroll
                for (int off = 1; off < 16; off <<= 1) {
                    ps += __shfl_xor(ps, off);
                    pd += __shfl_xor(pd, off);
                }
                if (c16 == 0) {
                    int grow = row0 + wr * 64 + mm * 16 + lq * 4 + r;
                    if (grow < M) {
                        s_src[grow * 4 + head] = ps;
                        s_dst[grow * 4 + head] = pd;
                    }
                }
            }
        }
    }
}

// ---------------- single-pass segment-softmax + aggregation, layers 1&2 ----------------
// wave per node; halves interleave edges; 4 edges in flight per half.
__global__ void k_aggregate(const unsigned short* __restrict__ h, const int* __restrict__ rowptr,
                            const unsigned* __restrict__ colp, const float* __restrict__ escT,
                            const float* __restrict__ s_src, const float* __restrict__ s_dst,
                            const float* __restrict__ bias,
                            unsigned short* __restrict__ out, int n, int e) {
    int wave = (blockIdx.x * blockDim.x + threadIdx.x) >> 6;
    int lane = threadIdx.x & 63;
    if (wave >= n) return;
    int half = lane >> 5, l5 = lane & 31;
    int head = l5 >> 3;          // 8 lanes x 8 feats = 64 feats per head
    int f0 = l5 * 8;
    const float* esc = escT + (size_t)head * e;
    int rs = rowptr[wave], re = rowptr[wave + 1];

    // max over this head's contiguous score segment (16 lanes per head)
    float mx = -INFINITY;
    for (int i = rs + (l5 & 7) + half * 8; i < re; i += 16) mx = fmaxf(mx, esc[i]);
    mx = fmaxf(mx, __shfl_xor(mx, 1));
    mx = fmaxf(mx, __shfl_xor(mx, 2));
    mx = fmaxf(mx, __shfl_xor(mx, 4));
    mx = fmaxf(mx, __shfl_xor(mx, 32));
    float selfsc = lrelu(s_src[wave * 4 + head] + s_dst[wave * 4 + head]);
    float m = fmaxf(mx, selfsc);

    float z = 0.f;
    float a[8] = {};
    if (half == 0) {
        float p = __expf(selfsc - m);
        z += p;
        uint4 hv = *(const uint4*)(h + (size_t)wave * 256 + f0);
        const unsigned* u = (const unsigned*)&hv;
        #pragma unroll
        for (int j = 0; j < 4; j++) {
            a[2 * j]     += p * __uint_as_float(u[j] << 16);
            a[2 * j + 1] += p * __uint_as_float(u[j] & 0xffff0000u);
        }
    }
    int i = rs + half;
    // 4 edges in flight per half
    for (; i + 6 < re; i += 8) {
        int s0 = colp[i]     & 0xffff;
        int s1 = colp[i + 2] & 0xffff;
        int s2 = colp[i + 4] & 0xffff;
        int s3 = colp[i + 6] & 0xffff;
        float e0 = esc[i], e1 = esc[i + 2], e2 = esc[i + 4], e3 = esc[i + 6];
        uint4 h0 = *(const uint4*)(h + (size_t)s0 * 256 + f0);
        uint4 h1 = *(const uint4*)(h + (size_t)s1 * 256 + f0);
        uint4 h2 = *(const uint4*)(h + (size_t)s2 * 256 + f0);
        uint4 h3 = *(const uint4*)(h + (size_t)s3 * 256 + f0);
        float p0 = __expf(e0 - m), p1 = __expf(e1 - m);
        float p2 = __expf(e2 - m), p3 = __expf(e3 - m);
        z += (p0 + p1) + (p2 + p3);
        const unsigned* u0 = (const unsigned*)&h0;
        const unsigned* u1 = (const unsigned*)&h1;
        const unsigned* u2 = (const unsigned*)&h2;
        const unsigned* u3 = (const unsigned*)&h3;
        #pragma unroll
        for (int j = 0; j < 4; j++) {
            a[2 * j]     += p0 * __uint_as_float(u0[j] << 16)
                          + p1 * __uint_as_float(u1[j] << 16)
                          + p2 * __uint_as_float(u2[j] << 16)
                          + p3 * __uint_as_float(u3[j] << 16);
            a[2 * j + 1] += p0 * __uint_as_float(u0[j] & 0xffff0000u)
                          + p1 * __uint_as_float(u1[j] & 0xffff0000u)
                          + p2 * __uint_as_float(u2[j] & 0xffff0000u)
                          + p3 * __uint_as_float(u3[j] & 0xffff0000u);
        }
    }
    for (; i + 2 < re; i += 4) {
        int s0 = colp[i] & 0xffff, s1 = colp[i + 2] & 0xffff;
        float e0 = esc[i], e1 = esc[i + 2];
        uint4 h0 = *(const uint4*)(h + (size_t)s0 * 256 + f0);
        uint4 h1 = *(const uint4*)(h + (size_t)s1 * 256 + f0);
        float p0 = __expf(e0 - m), p1 = __expf(e1 - m);
        z += p0 + p1;
        const unsigned* u0 = (const unsigned*)&h0;
        const unsigned* u1 = (const unsigned*)&h1;
        #pragma unroll
        for (int j = 0; j < 4; j++) {
            a[2 * j]     += p0 * __uint_as_float(u0[j] << 16)
                          + p1 * __uint_as_float(u1[j] << 16);
            a[2 * j + 1] += p0 * __uint_as_float(u0[j] & 0xffff0000u)
                          + p1 * __uint_as_float(u1[j] & 0xffff0000u);
        }
    }
    for (; i < re; i += 2) {
        int s0 = colp[i] & 0xffff;
        float p0 = __expf(esc[i] - m);
        uint4 h0 = *(const uint4*)(h + (size_t)s0 * 256 + f0);
        const unsigned* u0 = (const unsigned*)&h0;
        z += p0;
        #pragma unroll
        for (int j = 0; j < 4; j++) {
            a[2 * j]     += p0 * __uint_as_float(u0[j] << 16);
            a[2 * j + 1] += p0 * __uint_as_float(u0[j] & 0xffff0000u);
        }
    }
    // merge halves
    z += __shfl_xor(z, 32);
    #pragma unroll
    for (int j = 0; j < 8; j++) a[j] += __shfl_xor(a[j], 32);

    if (half == 0) {
        float inv = 1.f / z;
        float4 bv0 = *(const float4*)(bias + f0);
        float4 bv1 = *(const float4*)(bias + f0 + 4);
        float o[8];
        o[0] = a[0] * inv + bv0.x; o[1] = a[1] * inv + bv0.y;
        o[2] = a[2] * inv + bv0.z; o[3] = a[3] * inv + bv0.w;
        o[4] = a[4] * inv + bv1.x; o[5] = a[5] * inv + bv1.y;
        o[6] = a[6] * inv + bv1.z; o[7] = a[7] * inv + bv1.w;
        #pragma unroll
        for (int j = 0; j < 8; j++) o[j] = o[j] > 0.f ? o[j] : expm1f(o[j]);
        uint4 ov;
        unsigned* w = (unsigned*)&ov;
        #pragma unroll
        for (int j = 0; j < 4; j++)
            w[j] = (unsigned)f2b(o[2 * j]) | ((unsigned)f2b(o[2 * j + 1]) << 16);
        *(uint4*)(out + (size_t)wave * 256 + f0) = ov;
    }
}

// ---------------- layer 3: GEMM [M,256](bf16)@[256,16](f32) + fused scores ----------
__global__ __launch_bounds__(256) void k_gemm3(const unsigned short* __restrict__ A,
                                               const float* __restrict__ B,
                                               const float* __restrict__ a3s,
                                               const float* __restrict__ a3d,
                                               float* __restrict__ C,
                                               float* __restrict__ s_src,
                                               float* __restrict__ s_dst,
                                               int M, int K) {
    __shared__ float Bs[256 * 16];
    for (int i = threadIdx.x; i < K * 16; i += 256) Bs[i] = B[i];
    __syncthreads();
    int tx = threadIdx.x & 15;
    int ty = threadIdx.x >> 4;
    int row = blockIdx.x * 16 + ty;
    if (row >= M) return;
    const unsigned short* Ar = A + (size_t)row * K;
    float acc = 0.f;
    for (int kk = 0; kk < K; kk += 8) {
        uint4 va = *(const uint4*)(Ar + kk);
        const unsigned* u = (const unsigned*)&va;
        #pragma unroll
        for (int j = 0; j < 4; j++) {
            float lo = __uint_as_float(u[j] << 16);
            float hi = __uint_as_float(u[j] & 0xffff0000u);
            acc += lo * Bs[(kk + 2 * j) * 16 + tx] + hi * Bs[(kk + 2 * j + 1) * 16 + tx];
        }
    }
    C[(size_t)row * 16 + tx] = acc;
    float ps = acc * a3s[tx], pd = acc * a3d[tx];
    #pragma unroll
    for (int off = 1; off < 16; off <<= 1) {
        ps += __shfl_xor(ps, off);
        pd += __shfl_xor(pd, off);
    }
    if (tx == 0) { s_src[row] = ps; s_dst[row] = pd; }
}

// ---------------- layer 3 aggregation + bias + log_softmax ----------------
__global__ void k_agg3(const float* __restrict__ h3, const int* __restrict__ rowptr,
                       const unsigned* __restrict__ colp, const float* __restrict__ esc,
                       const float* __restrict__ s_src, const float* __restrict__ s_dst,
                       const float* __restrict__ b3,
                       float* __restrict__ outp, int n) {
    int wave = (blockIdx.x * blockDim.x + threadIdx.x) >> 6;
    int lane = threadIdx.x & 63;
    if (wave >= n) return;
    int g = lane >> 4, c = lane & 15;
    int rs = rowptr[wave], re = rowptr[wave + 1];

    float mx = -INFINITY;
    for (int i = rs + lane; i < re; i += 64) mx = fmaxf(mx, esc[i]);
    #pragma unroll
    for (int off = 1; off < 64; off <<= 1) mx = fmaxf(mx, __shfl_xor(mx, off));
    float selfsc = lrelu(s_src[wave] + s_dst[wave]);
    float m = fmaxf(mx, selfsc);

    float z = 0.f, acc = 0.f;
    if (g == 0) {
        float p = __expf(selfsc - m);
        z += p;
        acc += p * h3[(size_t)wave * 16 + c];
    }
    for (int i = rs + g; i < re; i += 4) {
        int s = colp[i] & 0xffff;
        float p = __expf(esc[i] - m);
        z += p;
        acc += p * h3[(size_t)s * 16 + c];
    }
    z += __shfl_xor(z, 16);  z += __shfl_xor(z, 32);
    acc += __shfl_xor(acc, 16); acc += __shfl_xor(acc, 32);
    if (lane < 16) {
        float v = acc / z + b3[c];
        float mm = v;
        #pragma unroll
        for (int off = 1; off < 16; off <<= 1) mm = fmaxf(mm, __shfl_xor(mm, off));
        float se = __expf(v - mm);
        #pragma unroll
        for (int off = 1; off < 16; off <<= 1) se += __shfl_xor(se, off);
        outp[(size_t)wave * 16 + c] = v - mm - logf(se);
    }
}

extern "C" void kernel_launch(void* const* d_in, const int* in_sizes, int n_in,
                              void* d_out, int out_size, void* d_ws, size_t ws_size,
                              hipStream_t stream) {
    const float* x      = (const float*)d_in[0];
    const int*   ei     = (const int*)d_in[1];
    const float* W1     = (const float*)d_in[2];
    const float* a1_src = (const float*)d_in[3];
    const float* a1_dst = (const float*)d_in[4];
    const float* b1     = (const float*)d_in[5];
    const float* W2     = (const float*)d_in[6];
    const float* a2_src = (const float*)d_in[7];
    const float* a2_dst = (const float*)d_in[8];
    const float* b2     = (const float*)d_in[9];
    const float* W3     = (const float*)d_in[10];
    const float* a3_src = (const float*)d_in[11];
    const float* a3_dst = (const float*)d_in[12];
    const float* b3     = (const float*)d_in[13];
    float* outp = (float*)d_out;

    const int N = N_NODES, E = N_EDGES;
    const int* src = ei;
    const int* dst = ei + E;

    char* ws = (char*)d_ws;
    size_t off = 0;
    auto alloc = [&](size_t bytes) {
        void* p = ws + off;
        off = (off + bytes + 255) & ~(size_t)255;
        return p;
    };
    int*   rowptr = (int*)alloc((N + 1) * sizeof(int));
    int*   counts = (int*)alloc(N * sizeof(int));      // reused as cursor
    unsigned* colp = (unsigned*)alloc(E * sizeof(unsigned));
    int*   incl   = (int*)alloc(N * sizeof(int));
    int*   bsums  = (int*)alloc(64 * sizeof(int));
    int*   boffs  = (int*)alloc(64 * sizeof(int));
    float* s_src  = (float*)alloc((size_t)N * HEADS * sizeof(float));
    float* s_dst  = (float*)alloc((size_t)N * HEADS * sizeof(float));
    float* escT   = (float*)alloc((size_t)E * HEADS * sizeof(float));
    unsigned short* xb  = (unsigned short*)alloc((size_t)N * F_IN * sizeof(short));
    unsigned short* W1t = (unsigned short*)alloc((size_t)256 * F_IN * sizeof(short));
    unsigned short* W2t = (unsigned short*)alloc((size_t)256 * 256 * sizeof(short));
    unsigned short* hA  = (unsigned short*)alloc((size_t)N * 256 * sizeof(short));
    unsigned short* hB  = (unsigned short*)alloc((size_t)N * 256 * sizeof(short));
    float* h3     = (float*)alloc((size_t)N * 16 * sizeof(float));
    (void)ws_size;

    // ---- converts ----
    k_f2b4<<<(N * F_IN / 4 + 255) / 256, 256, 0, stream>>>(x, xb, N * F_IN / 4);
    k_wt<<<(F_IN * 256 + 255) / 256, 256, 0, stream>>>(W1, W1t, F_IN, 256);
    k_wt<<<(256 * 256 + 255) / 256, 256, 0, stream>>>(W2, W2t, 256, 256);

    // ---- CSR build (by dst) ----
    hipMemsetAsync(counts, 0, N * sizeof(int), stream);
    k_hist<<<(E + 255) / 256, 256, 0, stream>>>(dst, counts, E);
    const int nb = (N + 1023) / 1024;
    k_scan1<<<nb, 256, 0, stream>>>(counts, incl, bsums, N);
    k_scan2<<<1, 64, 0, stream>>>(bsums, boffs, nb, rowptr + N);
    k_scan3<<<(N + 255) / 256, 256, 0, stream>>>(incl, counts, boffs, rowptr, N);
    hipMemsetAsync(counts, 0, N * sizeof(int), stream);
    k_scatter<<<((E + 1) / 2 + 255) / 256, 256, 0, stream>>>(src, dst, rowptr, counts, colp, E);

    const int aggBlocks = (N + 3) / 4;
    const int gemmBlocks = ((N + 127) / 128) * 2;
    const int edgeBlocks = (E + 255) / 256;

    // ---- layer 1 ----
    k_gemm_mfma<<<gemmBlocks, 256, 0, stream>>>(xb, W1t, a1_src, a1_dst, hA, s_src, s_dst, N, F_IN);
    k_escore<<<edgeBlocks, 256, 0, stream>>>(colp, s_src, s_dst, escT, E);
    k_aggregate<<<aggBlocks, 256, 0, stream>>>(hA, rowptr, colp, escT, s_src, s_dst, b1, hB, N, E);
    // ---- layer 2 ----
    k_gemm_mfma<<<gemmBlocks, 256, 0, stream>>>(hB, W2t, a2_src, a2_dst, hA, s_src, s_dst, N, 256);
    k_escore<<<edgeBlocks, 256, 0, stream>>>(colp, s_src, s_dst, escT, E);
    k_aggregate<<<aggBlocks, 256, 0, stream>>>(hA, rowptr, colp, escT, s_src, s_dst, b2, hB, N, E);
    // ---- layer 3 ----
    k_gemm3<<<(N + 15) / 16, 256, 0, stream>>>(hB, W3, a3_src, a3_dst, h3, s_src, s_dst, N, 256);
    k_escore3<<<edgeBlocks, 256, 0, stream>>>(colp, s_src, s_dst, escT, E);
    k_agg3<<<aggBlocks, 256, 0, stream>>>(h3, rowptr, colp, escT, s_src, s_dst, b3, outp, N);
}

// Round 7
// 354.824 us; speedup vs baseline: 1.8022x; 1.0062x over previous
//
#include <hip/hip_runtime.h>
#include <hip/hip_bf16.h>
#include <math.h>

#define N_NODES 50000
#define N_EDGES 800000
#define F_IN    128
#define HID     64
#define HEADS   4
#define NCLS    16
#define NEG_SLOPE 0.2f

typedef __attribute__((ext_vector_type(8))) _Float16 half8v;
typedef __attribute__((ext_vector_type(4))) float f32x4;

static __device__ __forceinline__ float lrelu(float x) {
    return x >= 0.f ? x : NEG_SLOPE * x;
}
static __device__ __forceinline__ unsigned short f2h(float f) {
    _Float16 h = (_Float16)f;
    return __builtin_bit_cast(unsigned short, h);
}
static __device__ __forceinline__ float h2f(unsigned short u) {
    return (float)__builtin_bit_cast(_Float16, u);
}
// a_lo += p * f16lo(hu); a_hi += p * f16hi(hu)   (v_fma_mix_f32)
static __device__ __forceinline__ void fma_mix2(float& alo, float& ahi, float p, unsigned hu) {
    asm("v_fma_mix_f32 %0, %1, %2, %0 op_sel:[0,0,0] op_sel_hi:[0,1,0]"
        : "+v"(alo) : "v"(p), "v"(hu));
    asm("v_fma_mix_f32 %0, %1, %2, %0 op_sel:[0,1,0] op_sel_hi:[0,1,0]"
        : "+v"(ahi) : "v"(p), "v"(hu));
}

// ---------------- converts ----------------
__global__ void k_f2h4(const float* __restrict__ in, unsigned short* __restrict__ out, int n4) {
    int i = blockIdx.x * blockDim.x + threadIdx.x;
    if (i < n4) {
        float4 v = *(const float4*)(in + i * 4);
        ushort4 o = { f2h(v.x), f2h(v.y), f2h(v.z), f2h(v.w) };
        *(ushort4*)(out + i * 4) = o;
    }
}

// Wt[c][k] = W[k][c], f16
__global__ void k_wt(const float* __restrict__ W, unsigned short* __restrict__ Wt, int K, int N) {
    int i = blockIdx.x * blockDim.x + threadIdx.x;
    if (i < K * N) {
        int k = i / N, c = i % N;
        Wt[c * K + k] = f2h(W[i]);
    }
}

// ---------------- CSR build ----------------
__global__ void k_hist(const int* __restrict__ dst, int* __restrict__ counts, int e) {
    int i = blockIdx.x * blockDim.x + threadIdx.x;
    if (i < e) atomicAdd(&counts[dst[i]], 1);
}

__global__ __launch_bounds__(256) void k_scan1(const int* __restrict__ counts, int* __restrict__ incl,
                                               int* __restrict__ bsums, int n) {
    __shared__ int wsum[4];
    int blk = blockIdx.x, tid = threadIdx.x;
    int lane = tid & 63, w = tid >> 6;
    int i0 = blk * 1024 + tid * 4;
    int v[4];
    #pragma unroll
    for (int j = 0; j < 4; j++) v[j] = (i0 + j < n) ? counts[i0 + j] : 0;
    int t = v[0] + v[1] + v[2] + v[3];
    int x = t;
    #pragma unroll
    for (int d = 1; d < 64; d <<= 1) { int y = __shfl_up(x, d); if (lane >= d) x += y; }
    if (lane == 63) wsum[w] = x;
    __syncthreads();
    int woff = 0;
    #pragma unroll
    for (int ww = 0; ww < 4; ww++) woff += (ww < w) ? wsum[ww] : 0;
    int p = woff + x - t;
    #pragma unroll
    for (int j = 0; j < 4; j++) { p += v[j]; if (i0 + j < n) incl[i0 + j] = p; }
    if (tid == 255) bsums[blk] = woff + x;
}

__global__ void k_scan2(const int* __restrict__ bsums, int* __restrict__ boffs, int nb, int* rowptr_end) {
    int lane = threadIdx.x;
    int v = (lane < nb) ? bsums[lane] : 0;
    int x = v;
    #pragma unroll
    for (int d = 1; d < 64; d <<= 1) { int y = __shfl_up(x, d); if (lane >= d) x += y; }
    if (lane < nb) boffs[lane] = x - v;
    if (lane == 63) *rowptr_end = x;
}

__global__ void k_scan3(const int* __restrict__ incl, const int* __restrict__ counts,
                        const int* __restrict__ boffs, int* __restrict__ rowptr, int n) {
    int i = blockIdx.x * blockDim.x + threadIdx.x;
    if (i < n) rowptr[i] = boffs[i >> 10] + incl[i] - counts[i];
}

// scatter packed (src | dst<<16); 2 edges per thread
__global__ void k_scatter(const int* __restrict__ src, const int* __restrict__ dst,
                          const int* __restrict__ rowptr, int* __restrict__ cursor,
                          unsigned* __restrict__ colp, int e) {
    int half = (e + 1) >> 1;
    int i = blockIdx.x * blockDim.x + threadIdx.x;
    if (i < half) {
        int d = dst[i];
        int pos = rowptr[d] + atomicAdd(&cursor[d], 1);
        colp[pos] = (unsigned)src[i] | ((unsigned)d << 16);
    }
    int j = i + half;
    if (j < e) {
        int d = dst[j];
        int pos = rowptr[d] + atomicAdd(&cursor[d], 1);
        colp[pos] = (unsigned)src[j] | ((unsigned)d << 16);
    }
}

// ---------------- per-edge p = exp(score), CSR order, head-transposed (layers 1&2) ----
__global__ void k_escore(const unsigned* __restrict__ colp,
                         const float* __restrict__ s_src, const float* __restrict__ s_dst,
                         float* __restrict__ pT, int e) {
    int i = blockIdx.x * blockDim.x + threadIdx.x;
    if (i >= e) return;
    unsigned v = colp[i];
    int s = v & 0xffff, d = v >> 16;
    float4 ss = *(const float4*)(s_src + (size_t)s * 4);
    float4 ds = *(const float4*)(s_dst + (size_t)d * 4);
    pT[i]         = __expf(fminf(lrelu(ss.x + ds.x), 80.f));
    pT[e + i]     = __expf(fminf(lrelu(ss.y + ds.y), 80.f));
    pT[2 * e + i] = __expf(fminf(lrelu(ss.z + ds.z), 80.f));
    pT[3 * e + i] = __expf(fminf(lrelu(ss.w + ds.w), 80.f));
}

// layer-3 p (H=1)
__global__ void k_escore3(const unsigned* __restrict__ colp,
                          const float* __restrict__ s_src, const float* __restrict__ s_dst,
                          float* __restrict__ p, int e) {
    int i = blockIdx.x * blockDim.x + threadIdx.x;
    if (i >= e) return;
    unsigned v = colp[i];
    p[i] = __expf(fminf(lrelu(s_src[v & 0xffff] + s_dst[v >> 16]), 80.f));
}

// ---------------- MFMA GEMM (f16) + fused per-node scores: C = A @ Bt^T ----------
static __device__ __forceinline__ int swz(int r, int lc) {
    return r * 4 + (lc ^ (r & 3) ^ ((r >> 2) & 1));
}

__global__ __launch_bounds__(256) void k_gemm_mfma(const unsigned short* __restrict__ A,
                                                   const unsigned short* __restrict__ Bt,
                                                   const float* __restrict__ asrc,
                                                   const float* __restrict__ adst,
                                                   unsigned short* __restrict__ C,
                                                   float* __restrict__ s_src,
                                                   float* __restrict__ s_dst,
                                                   int M, int K) {
    const int N = 256;
    __shared__ unsigned short Asm[128 * 32];
    __shared__ unsigned short Bsm[128 * 32];
    int tid = threadIdx.x;
    int lane = tid & 63, wid = tid >> 6;
    int bx = blockIdx.x & 1, by = blockIdx.x >> 1;
    int row0 = by * 128, col0 = bx * 128;
    int wr = wid >> 1, wc = wid & 1;
    f32x4 acc[4][4] = {};

    for (int k0 = 0; k0 < K; k0 += 32) {
        __syncthreads();
        #pragma unroll
        for (int s = 0; s < 2; s++) {
            int c = tid + s * 256;
            int row = c >> 2, lc = c & 3;
            int gr = row0 + row; if (gr >= M) gr = 0;
            uint4 va = *(const uint4*)(A + (size_t)gr * K + k0 + lc * 8);
            *(uint4*)(&Asm[swz(row, lc) * 8]) = va;
            uint4 vb = *(const uint4*)(Bt + (size_t)(col0 + row) * K + k0 + lc * 8);
            *(uint4*)(&Bsm[swz(row, lc) * 8]) = vb;
        }
        __syncthreads();
        half8v af[4], bg[4];
        int lq = lane >> 4;
        #pragma unroll
        for (int m = 0; m < 4; m++) {
            int r = wr * 64 + m * 16 + (lane & 15);
            af[m] = *(const half8v*)(&Asm[swz(r, lq) * 8]);
        }
        #pragma unroll
        for (int n = 0; n < 4; n++) {
            int r = wc * 64 + n * 16 + (lane & 15);
            bg[n] = *(const half8v*)(&Bsm[swz(r, lq) * 8]);
        }
        #pragma unroll
        for (int m = 0; m < 4; m++)
            #pragma unroll
            for (int n = 0; n < 4; n++)
                acc[m][n] = __builtin_amdgcn_mfma_f32_16x16x32_f16(af[m], bg[n], acc[m][n], 0, 0, 0);
    }

    // C write (f16)
    #pragma unroll
    for (int m = 0; m < 4; m++) {
        #pragma unroll
        for (int r = 0; r < 4; r++) {
            int row = row0 + wr * 64 + m * 16 + (lane >> 4) * 4 + r;
            if (row < M) {
                #pragma unroll
                for (int n = 0; n < 4; n++) {
                    C[(size_t)row * N + col0 + wc * 64 + n * 16 + (lane & 15)] = f2h(acc[m][n][r]);
                }
            }
        }
    }

    // fused attention scores: this wave's 64 cols = head (bx*2+wc)
    {
        int c16 = lane & 15, lq = lane >> 4;
        int head = bx * 2 + wc;
        float avs[4], avd[4];
        #pragma unroll
        for (int nn = 0; nn < 4; nn++) {
            avs[nn] = asrc[head * 64 + nn * 16 + c16];
            avd[nn] = adst[head * 64 + nn * 16 + c16];
        }
        #pragma unroll
        for (int mm = 0; mm < 4; mm++) {
            #pragma unroll
            for (int r = 0; r < 4; r++) {
                float ps = 0.f, pd = 0.f;
                #pragma unroll
                for (int nn = 0; nn < 4; nn++) {
                    ps += acc[mm][nn][r] * avs[nn];
                    pd += acc[mm][nn][r] * avd[nn];
                }
                #pragma unroll
                for (int off = 1; off < 16; off <<= 1) {
                    ps += __shfl_xor(ps, off);
                    pd += __shfl_xor(pd, off);
                }
                if (c16 == 0) {
                    int grow = row0 + wr * 64 + mm * 16 + lq * 4 + r;
                    if (grow < M) {
                        s_src[grow * 4 + head] = ps;
                        s_dst[grow * 4 + head] = pd;
                    }
                }
            }
        }
    }
}

// ---------------- single-pass aggregation, layers 1&2 (f16 h, precomputed p) --------
// wave per node; halves interleave edges; 4 edges in flight per half; fma_mix.
__global__ void k_aggregate(const unsigned short* __restrict__ h, const int* __restrict__ rowptr,
                            const unsigned* __restrict__ colp, const float* __restrict__ pT,
                            const float* __restrict__ s_src, const float* __restrict__ s_dst,
                            const float* __restrict__ bias,
                            unsigned short* __restrict__ out, int n, int e) {
    int wave = (blockIdx.x * blockDim.x + threadIdx.x) >> 6;
    int lane = threadIdx.x & 63;
    if (wave >= n) return;
    int half = lane >> 5, l5 = lane & 31;
    int head = l5 >> 3;          // 8 lanes x 8 feats = 64 feats per head
    unsigned foff = (unsigned)(l5 * 16);   // byte offset of this lane's 8 f16 feats
    const float* pp = pT + (size_t)head * e;
    const char* hc = (const char*)h;
    int rs = rowptr[wave], re = rowptr[wave + 1];

    float z = 0.f;
    float a[8] = {};
    if (half == 0) {
        float pself = __expf(fminf(lrelu(s_src[wave * 4 + head] + s_dst[wave * 4 + head]), 80.f));
        z = pself;
        uint4 own = *(const uint4*)(hc + (((unsigned)wave << 9) + foff));
        fma_mix2(a[0], a[1], pself, own.x);
        fma_mix2(a[2], a[3], pself, own.y);
        fma_mix2(a[4], a[5], pself, own.z);
        fma_mix2(a[6], a[7], pself, own.w);
    }
    int i = rs + half;
    for (; i + 6 < re; i += 8) {
        unsigned c0 = colp[i], c1 = colp[i + 2], c2 = colp[i + 4], c3 = colp[i + 6];
        float p0 = pp[i], p1 = pp[i + 2], p2 = pp[i + 4], p3 = pp[i + 6];
        uint4 h0 = *(const uint4*)(hc + (((c0 & 0xffffu) << 9) + foff));
        uint4 h1 = *(const uint4*)(hc + (((c1 & 0xffffu) << 9) + foff));
        uint4 h2 = *(const uint4*)(hc + (((c2 & 0xffffu) << 9) + foff));
        uint4 h3 = *(const uint4*)(hc + (((c3 & 0xffffu) << 9) + foff));
        z += (p0 + p1) + (p2 + p3);
        fma_mix2(a[0], a[1], p0, h0.x); fma_mix2(a[2], a[3], p0, h0.y);
        fma_mix2(a[4], a[5], p0, h0.z); fma_mix2(a[6], a[7], p0, h0.w);
        fma_mix2(a[0], a[1], p1, h1.x); fma_mix2(a[2], a[3], p1, h1.y);
        fma_mix2(a[4], a[5], p1, h1.z); fma_mix2(a[6], a[7], p1, h1.w);
        fma_mix2(a[0], a[1], p2, h2.x); fma_mix2(a[2], a[3], p2, h2.y);
        fma_mix2(a[4], a[5], p2, h2.z); fma_mix2(a[6], a[7], p2, h2.w);
        fma_mix2(a[0], a[1], p3, h3.x); fma_mix2(a[2], a[3], p3, h3.y);
        fma_mix2(a[4], a[5], p3, h3.z); fma_mix2(a[6], a[7], p3, h3.w);
    }
    for (; i + 2 < re; i += 4) {
        unsigned c0 = colp[i], c1 = colp[i + 2];
        float p0 = pp[i], p1 = pp[i + 2];
        uint4 h0 = *(const uint4*)(hc + (((c0 & 0xffffu) << 9) + foff));
        uint4 h1 = *(const uint4*)(hc + (((c1 & 0xffffu) << 9) + foff));
        z += p0 + p1;
        fma_mix2(a[0], a[1], p0, h0.x); fma_mix2(a[2], a[3], p0, h0.y);
        fma_mix2(a[4], a[5], p0, h0.z); fma_mix2(a[6], a[7], p0, h0.w);
        fma_mix2(a[0], a[1], p1, h1.x); fma_mix2(a[2], a[3], p1, h1.y);
        fma_mix2(a[4], a[5], p1, h1.z); fma_mix2(a[6], a[7], p1, h1.w);
    }
    for (; i < re; i += 2) {
        unsigned c0 = colp[i];
        float p0 = pp[i];
        uint4 h0 = *(const uint4*)(hc + (((c0 & 0xffffu) << 9) + foff));
        z += p0;
        fma_mix2(a[0], a[1], p0, h0.x); fma_mix2(a[2], a[3], p0, h0.y);
        fma_mix2(a[4], a[5], p0, h0.z); fma_mix2(a[6], a[7], p0, h0.w);
    }
    // merge halves
    z += __shfl_xor(z, 32);
    #pragma unroll
    for (int j = 0; j < 8; j++) a[j] += __shfl_xor(a[j], 32);

    if (half == 0) {
        float inv = 1.f / z;
        int f0 = l5 * 8;
        float4 bv0 = *(const float4*)(bias + f0);
        float4 bv1 = *(const float4*)(bias + f0 + 4);
        float o[8];
        o[0] = a[0] * inv + bv0.x; o[1] = a[1] * inv + bv0.y;
        o[2] = a[2] * inv + bv0.z; o[3] = a[3] * inv + bv0.w;
        o[4] = a[4] * inv + bv1.x; o[5] = a[5] * inv + bv1.y;
        o[6] = a[6] * inv + bv1.z; o[7] = a[7] * inv + bv1.w;
        #pragma unroll
        for (int j = 0; j < 8; j++) o[j] = o[j] > 0.f ? o[j] : expm1f(o[j]);
        uint4 ov;
        unsigned* w = (unsigned*)&ov;
        #pragma unroll
        for (int j = 0; j < 4; j++)
            w[j] = (unsigned)f2h(o[2 * j]) | ((unsigned)f2h(o[2 * j + 1]) << 16);
        *(uint4*)(out + (size_t)wave * 256 + f0) = ov;
    }
}

// ---------------- layer 3: GEMM [M,256](f16)@[256,16](f32) + fused scores ----------
__global__ __launch_bounds__(256) void k_gemm3(const unsigned short* __restrict__ A,
                                               const float* __restrict__ B,
                                               const float* __restrict__ a3s,
                                               const float* __restrict__ a3d,
                                               float* __restrict__ C,
                                               float* __restrict__ s_src,
                                               float* __restrict__ s_dst,
                                               int M, int K) {
    __shared__ float Bs[256 * 16];
    for (int i = threadIdx.x; i < K * 16; i += 256) Bs[i] = B[i];
    __syncthreads();
    int tx = threadIdx.x & 15;
    int ty = threadIdx.x >> 4;
    int row = blockIdx.x * 16 + ty;
    if (row >= M) return;
    const unsigned short* Ar = A + (size_t)row * K;
    float acc = 0.f;
    for (int kk = 0; kk < K; kk += 8) {
        uint4 va = *(const uint4*)(Ar + kk);
        const unsigned* u = (const unsigned*)&va;
        #pragma unroll
        for (int j = 0; j < 4; j++) {
            float lo = h2f((unsigned short)(u[j] & 0xffff));
            float hi = h2f((unsigned short)(u[j] >> 16));
            acc += lo * Bs[(kk + 2 * j) * 16 + tx] + hi * Bs[(kk + 2 * j + 1) * 16 + tx];
        }
    }
    C[(size_t)row * 16 + tx] = acc;
    float ps = acc * a3s[tx], pd = acc * a3d[tx];
    #pragma unroll
    for (int off = 1; off < 16; off <<= 1) {
        ps += __shfl_xor(ps, off);
        pd += __shfl_xor(pd, off);
    }
    if (tx == 0) { s_src[row] = ps; s_dst[row] = pd; }
}

// ---------------- layer 3 aggregation + bias + log_softmax (precomputed p) ----------
__global__ void k_agg3(const float* __restrict__ h3, const int* __restrict__ rowptr,
                       const unsigned* __restrict__ colp, const float* __restrict__ pE,
                       const float* __restrict__ s_src, const float* __restrict__ s_dst,
                       const float* __restrict__ b3,
                       float* __restrict__ outp, int n) {
    int wave = (blockIdx.x * blockDim.x + threadIdx.x) >> 6;
    int lane = threadIdx.x & 63;
    if (wave >= n) return;
    int g = lane >> 4, c = lane & 15;
    int rs = rowptr[wave], re = rowptr[wave + 1];

    float z = 0.f, acc = 0.f;
    if (g == 0) {
        float p = __expf(fminf(lrelu(s_src[wave] + s_dst[wave]), 80.f));
        z += p;
        acc += p * h3[(size_t)wave * 16 + c];
    }
    for (int i = rs + g; i < re; i += 4) {
        int s = colp[i] & 0xffff;
        float p = pE[i];
        z += p;
        acc += p * h3[(size_t)s * 16 + c];
    }
    z += __shfl_xor(z, 16);  z += __shfl_xor(z, 32);
    acc += __shfl_xor(acc, 16); acc += __shfl_xor(acc, 32);
    if (lane < 16) {
        float v = acc / z + b3[c];
        float mm = v;
        #pragma unroll
        for (int off = 1; off < 16; off <<= 1) mm = fmaxf(mm, __shfl_xor(mm, off));
        float se = __expf(v - mm);
        #pragma unroll
        for (int off = 1; off < 16; off <<= 1) se += __shfl_xor(se, off);
        outp[(size_t)wave * 16 + c] = v - mm - logf(se);
    }
}

extern "C" void kernel_launch(void* const* d_in, const int* in_sizes, int n_in,
                              void* d_out, int out_size, void* d_ws, size_t ws_size,
                              hipStream_t stream) {
    const float* x      = (const float*)d_in[0];
    const int*   ei     = (const int*)d_in[1];
    const float* W1     = (const float*)d_in[2];
    const float* a1_src = (const float*)d_in[3];
    const float* a1_dst = (const float*)d_in[4];
    const float* b1     = (const float*)d_in[5];
    const float* W2     = (const float*)d_in[6];
    const float* a2_src = (const float*)d_in[7];
    const float* a2_dst = (const float*)d_in[8];
    const float* b2     = (const float*)d_in[9];
    const float* W3     = (const float*)d_in[10];
    const float* a3_src = (const float*)d_in[11];
    const float* a3_dst = (const float*)d_in[12];
    const float* b3     = (const float*)d_in[13];
    float* outp = (float*)d_out;

    const int N = N_NODES, E = N_EDGES;
    const int* src = ei;
    const int* dst = ei + E;

    char* ws = (char*)d_ws;
    size_t off = 0;
    auto alloc = [&](size_t bytes) {
        void* p = ws + off;
        off = (off + bytes + 255) & ~(size_t)255;
        return p;
    };
    int*   rowptr = (int*)alloc((N + 1) * sizeof(int));
    int*   counts = (int*)alloc(N * sizeof(int));      // reused as cursor
    unsigned* colp = (unsigned*)alloc(E * sizeof(unsigned));
    int*   incl   = (int*)alloc(N * sizeof(int));
    int*   bsums  = (int*)alloc(64 * sizeof(int));
    int*   boffs  = (int*)alloc(64 * sizeof(int));
    float* s_src  = (float*)alloc((size_t)N * HEADS * sizeof(float));
    float* s_dst  = (float*)alloc((size_t)N * HEADS * sizeof(float));
    float* pT     = (float*)alloc((size_t)E * HEADS * sizeof(float));
    unsigned short* xb  = (unsigned short*)alloc((size_t)N * F_IN * sizeof(short));
    unsigned short* W1t = (unsigned short*)alloc((size_t)256 * F_IN * sizeof(short));
    unsigned short* W2t = (unsigned short*)alloc((size_t)256 * 256 * sizeof(short));
    unsigned short* hA  = (unsigned short*)alloc((size_t)N * 256 * sizeof(short));
    unsigned short* hB  = (unsigned short*)alloc((size_t)N * 256 * sizeof(short));
    float* h3     = (float*)alloc((size_t)N * 16 * sizeof(float));
    (void)ws_size;

    // ---- converts ----
    k_f2h4<<<(N * F_IN / 4 + 255) / 256, 256, 0, stream>>>(x, xb, N * F_IN / 4);
    k_wt<<<(F_IN * 256 + 255) / 256, 256, 0, stream>>>(W1, W1t, F_IN, 256);
    k_wt<<<(256 * 256 + 255) / 256, 256, 0, stream>>>(W2, W2t, 256, 256);

    // ---- CSR build (by dst) ----
    hipMemsetAsync(counts, 0, N * sizeof(int), stream);
    k_hist<<<(E + 255) / 256, 256, 0, stream>>>(dst, counts, E);
    const int nb = (N + 1023) / 1024;
    k_scan1<<<nb, 256, 0, stream>>>(counts, incl, bsums, N);
    k_scan2<<<1, 64, 0, stream>>>(bsums, boffs, nb, rowptr + N);
    k_scan3<<<(N + 255) / 256, 256, 0, stream>>>(incl, counts, boffs, rowptr, N);
    hipMemsetAsync(counts, 0, N * sizeof(int), stream);
    k_scatter<<<((E + 1) / 2 + 255) / 256, 256, 0, stream>>>(src, dst, rowptr, counts, colp, E);

    const int aggBlocks = (N + 3) / 4;
    const int gemmBlocks = ((N + 127) / 128) * 2;
    const int edgeBlocks = (E + 255) / 256;

    // ---- layer 1 ----
    k_gemm_mfma<<<gemmBlocks, 256, 0, stream>>>(xb, W1t, a1_src, a1_dst, hA, s_src, s_dst, N, F_IN);
    k_escore<<<edgeBlocks, 256, 0, stream>>>(colp, s_src, s_dst, pT, E);
    k_aggregate<<<aggBlocks, 256, 0, stream>>>(hA, rowptr, colp, pT, s_src, s_dst, b1, hB, N, E);
    // ---- layer 2 ----
    k_gemm_mfma<<<gemmBlocks, 256, 0, stream>>>(hB, W2t, a2_src, a2_dst, hA, s_src, s_dst, N, 256);
    k_escore<<<edgeBlocks, 256, 0, stream>>>(colp, s_src, s_dst, pT, E);
    k_aggregate<<<aggBlocks, 256, 0, stream>>>(hA, rowptr, colp, pT, s_src, s_dst, b2, hB, N, E);
    // ---- layer 3 ----
    k_gemm3<<<(N + 15) / 16, 256, 0, stream>>>(hB, W3, a3_src, a3_dst, h3, s_src, s_dst, N, 256);
    k_escore3<<<edgeBlocks, 256, 0, stream>>>(colp, s_src, s_dst, pT, E);
    k_agg3<<<aggBlocks, 256, 0, stream>>>(h3, rowptr, colp, pT, s_src, s_dst, b3, outp, N);
}

// Round 8
// 339.516 us; speedup vs baseline: 1.8835x; 1.0451x over previous
//
#include <hip/hip_runtime.h>
#include <hip/hip_bf16.h>
#include <math.h>

#define N_NODES 50000
#define N_EDGES 800000
#define F_IN    128
#define HID     64
#define HEADS   4
#define NCLS    16
#define NEG_SLOPE 0.2f

typedef __attribute__((ext_vector_type(8))) _Float16 half8v;
typedef __attribute__((ext_vector_type(4))) float f32x4;

static __device__ __forceinline__ float lrelu(float x) {
    return x >= 0.f ? x : NEG_SLOPE * x;
}
static __device__ __forceinline__ unsigned short f2h(float f) {
    _Float16 h = (_Float16)f;
    return __builtin_bit_cast(unsigned short, h);
}
static __device__ __forceinline__ float h2f(unsigned short u) {
    return (float)__builtin_bit_cast(_Float16, u);
}
// a_lo += p * f16lo(hu); a_hi += p * f16hi(hu)   (v_fma_mix_f32)
static __device__ __forceinline__ void fma_mix2(float& alo, float& ahi, float p, unsigned hu) {
    asm("v_fma_mix_f32 %0, %1, %2, %0 op_sel:[0,0,0] op_sel_hi:[0,1,0]"
        : "+v"(alo) : "v"(p), "v"(hu));
    asm("v_fma_mix_f32 %0, %1, %2, %0 op_sel:[0,1,0] op_sel_hi:[0,1,0]"
        : "+v"(ahi) : "v"(p), "v"(hu));
}

// ---------------- fused prep: x->f16, W1t, W2t, edge histogram ----------------
#define NB_F2H  6250          // N*F_IN/4 / 256
#define NB_WT1  128           // 128*256 / 256
#define NB_WT2  256           // 256*256 / 256
#define NB_HIST 3125          // E / 256
__global__ void k_prep(const float* __restrict__ x, unsigned short* __restrict__ xb,
                       const float* __restrict__ W1, unsigned short* __restrict__ W1t,
                       const float* __restrict__ W2, unsigned short* __restrict__ W2t,
                       const int* __restrict__ dst, int* __restrict__ counts) {
    int bid = blockIdx.x, tid = threadIdx.x;
    if (bid < NB_F2H) {
        int i = bid * 256 + tid;
        float4 v = *(const float4*)(x + (size_t)i * 4);
        ushort4 o = { f2h(v.x), f2h(v.y), f2h(v.z), f2h(v.w) };
        *(ushort4*)(xb + (size_t)i * 4) = o;
    } else if (bid < NB_F2H + NB_WT1) {
        int i = (bid - NB_F2H) * 256 + tid;
        int k = i >> 8, c = i & 255;
        W1t[c * F_IN + k] = f2h(W1[i]);
    } else if (bid < NB_F2H + NB_WT1 + NB_WT2) {
        int i = (bid - NB_F2H - NB_WT1) * 256 + tid;
        int k = i >> 8, c = i & 255;
        W2t[c * 256 + k] = f2h(W2[i]);
    } else {
        int i = (bid - NB_F2H - NB_WT1 - NB_WT2) * 256 + tid;
        if (i < N_EDGES) atomicAdd(&counts[dst[i]], 1);
    }
}

// ---------------- CSR scan ----------------
__global__ __launch_bounds__(256) void k_scan1(const int* __restrict__ counts, int* __restrict__ incl,
                                               int* __restrict__ bsums, int n) {
    __shared__ int wsum[4];
    int blk = blockIdx.x, tid = threadIdx.x;
    int lane = tid & 63, w = tid >> 6;
    int i0 = blk * 1024 + tid * 4;
    int v[4];
    #pragma unroll
    for (int j = 0; j < 4; j++) v[j] = (i0 + j < n) ? counts[i0 + j] : 0;
    int t = v[0] + v[1] + v[2] + v[3];
    int x = t;
    #pragma unroll
    for (int d = 1; d < 64; d <<= 1) { int y = __shfl_up(x, d); if (lane >= d) x += y; }
    if (lane == 63) wsum[w] = x;
    __syncthreads();
    int woff = 0;
    #pragma unroll
    for (int ww = 0; ww < 4; ww++) woff += (ww < w) ? wsum[ww] : 0;
    int p = woff + x - t;
    #pragma unroll
    for (int j = 0; j < 4; j++) { p += v[j]; if (i0 + j < n) incl[i0 + j] = p; }
    if (tid == 255) bsums[blk] = woff + x;
}

__global__ void k_scan2(const int* __restrict__ bsums, int* __restrict__ boffs, int nb, int* rowptr_end) {
    int lane = threadIdx.x;
    int v = (lane < nb) ? bsums[lane] : 0;
    int x = v;
    #pragma unroll
    for (int d = 1; d < 64; d <<= 1) { int y = __shfl_up(x, d); if (lane >= d) x += y; }
    if (lane < nb) boffs[lane] = x - v;
    if (lane == 63) *rowptr_end = x;
}

// also zeroes the cursor (aliased with counts) for the scatter
__global__ void k_scan3(const int* __restrict__ incl, int* __restrict__ counts,
                        const int* __restrict__ boffs, int* __restrict__ rowptr, int n) {
    int i = blockIdx.x * blockDim.x + threadIdx.x;
    if (i < n) {
        int cv = counts[i];
        rowptr[i] = boffs[i >> 10] + incl[i] - cv;
        counts[i] = 0;
    }
}

// ---------------- GEMM body (f16 MFMA, N=256) + fused per-node scores ----------
static __device__ __forceinline__ int swz(int r, int lc) {
    return r * 4 + (lc ^ (r & 3) ^ ((r >> 2) & 1));
}

static __device__ __forceinline__ void gemm_body(
        int bid, const unsigned short* __restrict__ A, const unsigned short* __restrict__ Bt,
        const float* __restrict__ asrc, const float* __restrict__ adst,
        unsigned short* __restrict__ C, float* __restrict__ s_src, float* __restrict__ s_dst,
        int M, int K, unsigned short* Asm, unsigned short* Bsm) {
    const int N = 256;
    int tid = threadIdx.x;
    int lane = tid & 63, wid = tid >> 6;
    int bx = bid & 1, by = bid >> 1;
    int row0 = by * 128, col0 = bx * 128;
    int wr = wid >> 1, wc = wid & 1;
    f32x4 acc[4][4] = {};

    for (int k0 = 0; k0 < K; k0 += 32) {
        __syncthreads();
        #pragma unroll
        for (int s = 0; s < 2; s++) {
            int c = tid + s * 256;
            int row = c >> 2, lc = c & 3;
            int gr = row0 + row; if (gr >= M) gr = 0;
            uint4 va = *(const uint4*)(A + (size_t)gr * K + k0 + lc * 8);
            *(uint4*)(&Asm[swz(row, lc) * 8]) = va;
            uint4 vb = *(const uint4*)(Bt + (size_t)(col0 + row) * K + k0 + lc * 8);
            *(uint4*)(&Bsm[swz(row, lc) * 8]) = vb;
        }
        __syncthreads();
        half8v af[4], bg[4];
        int lq = lane >> 4;
        #pragma unroll
        for (int m = 0; m < 4; m++) {
            int r = wr * 64 + m * 16 + (lane & 15);
            af[m] = *(const half8v*)(&Asm[swz(r, lq) * 8]);
        }
        #pragma unroll
        for (int n = 0; n < 4; n++) {
            int r = wc * 64 + n * 16 + (lane & 15);
            bg[n] = *(const half8v*)(&Bsm[swz(r, lq) * 8]);
        }
        #pragma unroll
        for (int m = 0; m < 4; m++)
            #pragma unroll
            for (int n = 0; n < 4; n++)
                acc[m][n] = __builtin_amdgcn_mfma_f32_16x16x32_f16(af[m], bg[n], acc[m][n], 0, 0, 0);
    }

    #pragma unroll
    for (int m = 0; m < 4; m++) {
        #pragma unroll
        for (int r = 0; r < 4; r++) {
            int row = row0 + wr * 64 + m * 16 + (lane >> 4) * 4 + r;
            if (row < M) {
                #pragma unroll
                for (int n = 0; n < 4; n++) {
                    C[(size_t)row * N + col0 + wc * 64 + n * 16 + (lane & 15)] = f2h(acc[m][n][r]);
                }
            }
        }
    }

    // fused attention scores: this wave's 64 cols = head (bx*2+wc)
    int c16 = lane & 15, lq = lane >> 4;
    int head = bx * 2 + wc;
    float avs[4], avd[4];
    #pragma unroll
    for (int nn = 0; nn < 4; nn++) {
        avs[nn] = asrc[head * 64 + nn * 16 + c16];
        avd[nn] = adst[head * 64 + nn * 16 + c16];
    }
    #pragma unroll
    for (int mm = 0; mm < 4; mm++) {
        #pragma unroll
        for (int r = 0; r < 4; r++) {
            float ps = 0.f, pd = 0.f;
            #pragma unroll
            for (int nn = 0; nn < 4; nn++) {
                ps += acc[mm][nn][r] * avs[nn];
                pd += acc[mm][nn][r] * avd[nn];
            }
            #pragma unroll
            for (int off = 1; off < 16; off <<= 1) {
                ps += __shfl_xor(ps, off);
                pd += __shfl_xor(pd, off);
            }
            if (c16 == 0) {
                int grow = row0 + wr * 64 + mm * 16 + lq * 4 + r;
                if (grow < M) {
                    s_src[grow * 4 + head] = ps;
                    s_dst[grow * 4 + head] = pd;
                }
            }
        }
    }
}

// standalone GEMM (layer 2)
__global__ __launch_bounds__(256) void k_gemm_mfma(const unsigned short* __restrict__ A,
                                                   const unsigned short* __restrict__ Bt,
                                                   const float* __restrict__ asrc,
                                                   const float* __restrict__ adst,
                                                   unsigned short* __restrict__ C,
                                                   float* __restrict__ s_src,
                                                   float* __restrict__ s_dst,
                                                   int M, int K) {
    __shared__ unsigned short Asm[128 * 32];
    __shared__ unsigned short Bsm[128 * 32];
    gemm_body(blockIdx.x, A, Bt, asrc, adst, C, s_src, s_dst, M, K, Asm, Bsm);
}

// fused: layer-1 GEMM (blocks [0,gemmBlocks)) + CSR scatter (rest)
__global__ __launch_bounds__(256) void k_b(const unsigned short* __restrict__ A,
                                           const unsigned short* __restrict__ Bt,
                                           const float* __restrict__ asrc,
                                           const float* __restrict__ adst,
                                           unsigned short* __restrict__ C,
                                           float* __restrict__ s_src,
                                           float* __restrict__ s_dst,
                                           int M, int K, int gemmBlocks,
                                           const int* __restrict__ src, const int* __restrict__ dst,
                                           const int* __restrict__ rowptr, int* __restrict__ cursor,
                                           unsigned* __restrict__ colp, int e) {
    __shared__ unsigned short Asm[128 * 32];
    __shared__ unsigned short Bsm[128 * 32];
    int bid = blockIdx.x;
    if (bid < gemmBlocks) {
        gemm_body(bid, A, Bt, asrc, adst, C, s_src, s_dst, M, K, Asm, Bsm);
    } else {
        int half = (e + 1) >> 1;
        int i = (bid - gemmBlocks) * 256 + (int)threadIdx.x;
        if (i < half) {
            int d = dst[i];
            int pos = rowptr[d] + atomicAdd(&cursor[d], 1);
            colp[pos] = (unsigned)src[i] | ((unsigned)d << 16);
        }
        int j = i + half;
        if (j < e) {
            int d = dst[j];
            int pos = rowptr[d] + atomicAdd(&cursor[d], 1);
            colp[pos] = (unsigned)src[j] | ((unsigned)d << 16);
        }
    }
}

// ---------------- per-edge p = exp(score), CSR order, head-transposed (layers 1&2) ----
__global__ void k_escore(const unsigned* __restrict__ colp,
                         const float* __restrict__ s_src, const float* __restrict__ s_dst,
                         float* __restrict__ pT, int e) {
    int i = blockIdx.x * blockDim.x + threadIdx.x;
    if (i >= e) return;
    unsigned v = colp[i];
    int s = v & 0xffff, d = v >> 16;
    float4 ss = *(const float4*)(s_src + (size_t)s * 4);
    float4 ds = *(const float4*)(s_dst + (size_t)d * 4);
    pT[i]         = __expf(fminf(lrelu(ss.x + ds.x), 80.f));
    pT[e + i]     = __expf(fminf(lrelu(ss.y + ds.y), 80.f));
    pT[2 * e + i] = __expf(fminf(lrelu(ss.z + ds.z), 80.f));
    pT[3 * e + i] = __expf(fminf(lrelu(ss.w + ds.w), 80.f));
}

// layer-3 p (H=1)
__global__ void k_escore3(const unsigned* __restrict__ colp,
                          const float* __restrict__ s_src, const float* __restrict__ s_dst,
                          float* __restrict__ p, int e) {
    int i = blockIdx.x * blockDim.x + threadIdx.x;
    if (i >= e) return;
    unsigned v = colp[i];
    p[i] = __expf(fminf(lrelu(s_src[v & 0xffff] + s_dst[v >> 16]), 80.f));
}

// ---------------- single-pass aggregation, layers 1&2 (f16 h, precomputed p) --------
// wave per node; halves interleave edges; 8 gathers in flight per half; fma_mix.
__global__ void k_aggregate(const unsigned short* __restrict__ h, const int* __restrict__ rowptr,
                            const unsigned* __restrict__ colp, const float* __restrict__ pT,
                            const float* __restrict__ s_src, const float* __restrict__ s_dst,
                            const float* __restrict__ bias,
                            unsigned short* __restrict__ out, int n, int e) {
    int wave = (blockIdx.x * blockDim.x + threadIdx.x) >> 6;
    int lane = threadIdx.x & 63;
    if (wave >= n) return;
    int half = lane >> 5, l5 = lane & 31;
    int head = l5 >> 3;          // 8 lanes x 8 feats = 64 feats per head
    unsigned foff = (unsigned)(l5 * 16);   // byte offset of this lane's 8 f16 feats
    const float* pp = pT + (size_t)head * e;
    const char* hc = (const char*)h;
    int rs = rowptr[wave], re = rowptr[wave + 1];

    float z = 0.f;
    float a[8] = {};
    if (half == 0) {
        float pself = __expf(fminf(lrelu(s_src[wave * 4 + head] + s_dst[wave * 4 + head]), 80.f));
        z = pself;
        uint4 own = *(const uint4*)(hc + (((unsigned)wave << 9) + foff));
        fma_mix2(a[0], a[1], pself, own.x);
        fma_mix2(a[2], a[3], pself, own.y);
        fma_mix2(a[4], a[5], pself, own.z);
        fma_mix2(a[6], a[7], pself, own.w);
    }
    int i = rs + half;
    // 8 gathers in flight per half (covers avg degree in one round)
    for (; i + 14 < re; i += 16) {
        unsigned cc[8]; float pv[8]; uint4 hv[8];
        #pragma unroll
        for (int j = 0; j < 8; j++) { cc[j] = colp[i + 2 * j]; pv[j] = pp[i + 2 * j]; }
        #pragma unroll
        for (int j = 0; j < 8; j++)
            hv[j] = *(const uint4*)(hc + (((cc[j] & 0xffffu) << 9) + foff));
        #pragma unroll
        for (int j = 0; j < 8; j++) {
            z += pv[j];
            fma_mix2(a[0], a[1], pv[j], hv[j].x); fma_mix2(a[2], a[3], pv[j], hv[j].y);
            fma_mix2(a[4], a[5], pv[j], hv[j].z); fma_mix2(a[6], a[7], pv[j], hv[j].w);
        }
    }
    for (; i + 6 < re; i += 8) {
        unsigned cc[4]; float pv[4]; uint4 hv[4];
        #pragma unroll
        for (int j = 0; j < 4; j++) { cc[j] = colp[i + 2 * j]; pv[j] = pp[i + 2 * j]; }
        #pragma unroll
        for (int j = 0; j < 4; j++)
            hv[j] = *(const uint4*)(hc + (((cc[j] & 0xffffu) << 9) + foff));
        #pragma unroll
        for (int j = 0; j < 4; j++) {
            z += pv[j];
            fma_mix2(a[0], a[1], pv[j], hv[j].x); fma_mix2(a[2], a[3], pv[j], hv[j].y);
            fma_mix2(a[4], a[5], pv[j], hv[j].z); fma_mix2(a[6], a[7], pv[j], hv[j].w);
        }
    }
    for (; i < re; i += 2) {
        unsigned c0 = colp[i];
        float p0 = pp[i];
        uint4 h0 = *(const uint4*)(hc + (((c0 & 0xffffu) << 9) + foff));
        z += p0;
        fma_mix2(a[0], a[1], p0, h0.x); fma_mix2(a[2], a[3], p0, h0.y);
        fma_mix2(a[4], a[5], p0, h0.z); fma_mix2(a[6], a[7], p0, h0.w);
    }
    // merge halves
    z += __shfl_xor(z, 32);
    #pragma unroll
    for (int j = 0; j < 8; j++) a[j] += __shfl_xor(a[j], 32);

    if (half == 0) {
        float inv = 1.f / z;
        int f0 = l5 * 8;
        float4 bv0 = *(const float4*)(bias + f0);
        float4 bv1 = *(const float4*)(bias + f0 + 4);
        float o[8];
        o[0] = a[0] * inv + bv0.x; o[1] = a[1] * inv + bv0.y;
        o[2] = a[2] * inv + bv0.z; o[3] = a[3] * inv + bv0.w;
        o[4] = a[4] * inv + bv1.x; o[5] = a[5] * inv + bv1.y;
        o[6] = a[6] * inv + bv1.z; o[7] = a[7] * inv + bv1.w;
        #pragma unroll
        for (int j = 0; j < 8; j++) o[j] = o[j] > 0.f ? o[j] : expm1f(o[j]);
        uint4 ov;
        unsigned* w = (unsigned*)&ov;
        #pragma unroll
        for (int j = 0; j < 4; j++)
            w[j] = (unsigned)f2h(o[2 * j]) | ((unsigned)f2h(o[2 * j + 1]) << 16);
        *(uint4*)(out + (size_t)wave * 256 + f0) = ov;
    }
}

// ---------------- layer 3: GEMM [M,256](f16)@[256,16](f32) + fused scores ----------
__global__ __launch_bounds__(256) void k_gemm3(const unsigned short* __restrict__ A,
                                               const float* __restrict__ B,
                                               const float* __restrict__ a3s,
                                               const float* __restrict__ a3d,
                                               float* __restrict__ C,
                                               float* __restrict__ s_src,
                                               float* __restrict__ s_dst,
                                               int M, int K) {
    __shared__ float Bs[256 * 16];
    for (int i = threadIdx.x; i < K * 16; i += 256) Bs[i] = B[i];
    __syncthreads();
    int tx = threadIdx.x & 15;
    int ty = threadIdx.x >> 4;
    int row = blockIdx.x * 16 + ty;
    if (row >= M) return;
    const unsigned short* Ar = A + (size_t)row * K;
    float acc = 0.f;
    for (int kk = 0; kk < K; kk += 8) {
        uint4 va = *(const uint4*)(Ar + kk);
        const unsigned* u = (const unsigned*)&va;
        #pragma unroll
        for (int j = 0; j < 4; j++) {
            float lo = h2f((unsigned short)(u[j] & 0xffff));
            float hi = h2f((unsigned short)(u[j] >> 16));
            acc += lo * Bs[(kk + 2 * j) * 16 + tx] + hi * Bs[(kk + 2 * j + 1) * 16 + tx];
        }
    }
    C[(size_t)row * 16 + tx] = acc;
    float ps = acc * a3s[tx], pd = acc * a3d[tx];
    #pragma unroll
    for (int off = 1; off < 16; off <<= 1) {
        ps += __shfl_xor(ps, off);
        pd += __shfl_xor(pd, off);
    }
    if (tx == 0) { s_src[row] = ps; s_dst[row] = pd; }
}

// ---------------- layer 3 aggregation + bias + log_softmax (precomputed p) ----------
__global__ void k_agg3(const float* __restrict__ h3, const int* __restrict__ rowptr,
                       const unsigned* __restrict__ colp, const float* __restrict__ pE,
                       const float* __restrict__ s_src, const float* __restrict__ s_dst,
                       const float* __restrict__ b3,
                       float* __restrict__ outp, int n) {
    int wave = (blockIdx.x * blockDim.x + threadIdx.x) >> 6;
    int lane = threadIdx.x & 63;
    if (wave >= n) return;
    int g = lane >> 4, c = lane & 15;
    int rs = rowptr[wave], re = rowptr[wave + 1];

    float z = 0.f, acc = 0.f;
    if (g == 0) {
        float p = __expf(fminf(lrelu(s_src[wave] + s_dst[wave]), 80.f));
        z += p;
        acc += p * h3[(size_t)wave * 16 + c];
    }
    for (int i = rs + g; i < re; i += 4) {
        int s = colp[i] & 0xffff;
        float p = pE[i];
        z += p;
        acc += p * h3[(size_t)s * 16 + c];
    }
    z += __shfl_xor(z, 16);  z += __shfl_xor(z, 32);
    acc += __shfl_xor(acc, 16); acc += __shfl_xor(acc, 32);
    if (lane < 16) {
        float v = acc / z + b3[c];
        float mm = v;
        #pragma unroll
        for (int off = 1; off < 16; off <<= 1) mm = fmaxf(mm, __shfl_xor(mm, off));
        float se = __expf(v - mm);
        #pragma unroll
        for (int off = 1; off < 16; off <<= 1) se += __shfl_xor(se, off);
        outp[(size_t)wave * 16 + c] = v - mm - logf(se);
    }
}

extern "C" void kernel_launch(void* const* d_in, const int* in_sizes, int n_in,
                              void* d_out, int out_size, void* d_ws, size_t ws_size,
                              hipStream_t stream) {
    const float* x      = (const float*)d_in[0];
    const int*   ei     = (const int*)d_in[1];
    const float* W1     = (const float*)d_in[2];
    const float* a1_src = (const float*)d_in[3];
    const float* a1_dst = (const float*)d_in[4];
    const float* b1     = (const float*)d_in[5];
    const float* W2     = (const float*)d_in[6];
    const float* a2_src = (const float*)d_in[7];
    const float* a2_dst = (const float*)d_in[8];
    const float* b2     = (const float*)d_in[9];
    const float* W3     = (const float*)d_in[10];
    const float* a3_src = (const float*)d_in[11];
    const float* a3_dst = (const float*)d_in[12];
    const float* b3     = (const float*)d_in[13];
    float* outp = (float*)d_out;

    const int N = N_NODES, E = N_EDGES;
    const int* src = ei;
    const int* dst = ei + E;

    char* ws = (char*)d_ws;
    size_t off = 0;
    auto alloc = [&](size_t bytes) {
        void* p = ws + off;
        off = (off + bytes + 255) & ~(size_t)255;
        return p;
    };
    int*   rowptr = (int*)alloc((N + 1) * sizeof(int));
    int*   counts = (int*)alloc(N * sizeof(int));      // reused as cursor
    unsigned* colp = (unsigned*)alloc(E * sizeof(unsigned));
    int*   incl   = (int*)alloc(N * sizeof(int));
    int*   bsums  = (int*)alloc(64 * sizeof(int));
    int*   boffs  = (int*)alloc(64 * sizeof(int));
    float* s_src  = (float*)alloc((size_t)N * HEADS * sizeof(float));
    float* s_dst  = (float*)alloc((size_t)N * HEADS * sizeof(float));
    float* pT     = (float*)alloc((size_t)E * HEADS * sizeof(float));
    unsigned short* xb  = (unsigned short*)alloc((size_t)N * F_IN * sizeof(short));
    unsigned short* W1t = (unsigned short*)alloc((size_t)256 * F_IN * sizeof(short));
    unsigned short* W2t = (unsigned short*)alloc((size_t)256 * 256 * sizeof(short));
    unsigned short* hA  = (unsigned short*)alloc((size_t)N * 256 * sizeof(short));
    unsigned short* hB  = (unsigned short*)alloc((size_t)N * 256 * sizeof(short));
    float* h3     = (float*)alloc((size_t)N * 16 * sizeof(float));
    (void)ws_size;

    const int aggBlocks = (N + 3) / 4;
    const int gemmBlocks = ((N + 127) / 128) * 2;
    const int edgeBlocks = (E + 255) / 256;
    const int scatBlocks = ((E + 1) / 2 + 255) / 256;

    // ---- prep: converts + histogram (fused) ----
    hipMemsetAsync(counts, 0, N * sizeof(int), stream);
    k_prep<<<NB_F2H + NB_WT1 + NB_WT2 + NB_HIST, 256, 0, stream>>>(x, xb, W1, W1t, W2, W2t, dst, counts);

    // ---- CSR scan (scan3 also zeroes cursor) ----
    const int nb = (N + 1023) / 1024;
    k_scan1<<<nb, 256, 0, stream>>>(counts, incl, bsums, N);
    k_scan2<<<1, 64, 0, stream>>>(bsums, boffs, nb, rowptr + N);
    k_scan3<<<(N + 255) / 256, 256, 0, stream>>>(incl, counts, boffs, rowptr, N);

    // ---- fused: layer-1 GEMM + CSR scatter ----
    k_b<<<gemmBlocks + scatBlocks, 256, 0, stream>>>(xb, W1t, a1_src, a1_dst, hA, s_src, s_dst,
                                                     N, F_IN, gemmBlocks,
                                                     src, dst, rowptr, counts, colp, E);
    // ---- layer 1 ----
    k_escore<<<edgeBlocks, 256, 0, stream>>>(colp, s_src, s_dst, pT, E);
    k_aggregate<<<aggBlocks, 256, 0, stream>>>(hA, rowptr, colp, pT, s_src, s_dst, b1, hB, N, E);
    // ---- layer 2 ----
    k_gemm_mfma<<<gemmBlocks, 256, 0, stream>>>(hB, W2t, a2_src, a2_dst, hA, s_src, s_dst, N, 256);
    k_escore<<<edgeBlocks, 256, 0, stream>>>(colp, s_src, s_dst, pT, E);
    k_aggregate<<<aggBlocks, 256, 0, stream>>>(hA, rowptr, colp, pT, s_src, s_dst, b2, hB, N, E);
    // ---- layer 3 ----
    k_gemm3<<<(N + 15) / 16, 256, 0, stream>>>(hB, W3, a3_src, a3_dst, h3, s_src, s_dst, N, 256);
    k_escore3<<<edgeBlocks, 256, 0, stream>>>(colp, s_src, s_dst, pT, E);
    k_agg3<<<aggBlocks, 256, 0, stream>>>(h3, rowptr, colp, pT, s_src, s_dst, b3, outp, N);
}

// Round 9
// 308.059 us; speedup vs baseline: 2.0758x; 1.1021x over previous
//
#include <hip/hip_runtime.h>
#include <hip/hip_bf16.h>
#include <math.h>

#define N_NODES 50000
#define N_EDGES 800000
#define F_IN    128
#define HID     64
#define HEADS   4
#define NCLS    16
#define NEG_SLOPE 0.2f

typedef __attribute__((ext_vector_type(8))) _Float16 half8v;
typedef __attribute__((ext_vector_type(4))) float f32x4;

static __device__ __forceinline__ float lrelu(float x) {
    return x >= 0.f ? x : NEG_SLOPE * x;
}
static __device__ __forceinline__ unsigned short f2h(float f) {
    _Float16 h = (_Float16)f;
    return __builtin_bit_cast(unsigned short, h);
}
static __device__ __forceinline__ float h2f(unsigned short u) {
    return (float)__builtin_bit_cast(_Float16, u);
}
// a_lo += p * f16lo(hu); a_hi += p * f16hi(hu)   (v_fma_mix_f32)
static __device__ __forceinline__ void fma_mix2(float& alo, float& ahi, float p, unsigned hu) {
    asm("v_fma_mix_f32 %0, %1, %2, %0 op_sel:[0,0,0] op_sel_hi:[0,1,0]"
        : "+v"(alo) : "v"(p), "v"(hu));
    asm("v_fma_mix_f32 %0, %1, %2, %0 op_sel:[0,1,0] op_sel_hi:[0,1,0]"
        : "+v"(ahi) : "v"(p), "v"(hu));
}

// ---------------- fused prep: x->f16, W1t, W2t, edge histogram + ranks ----------------
#define NB_F2H  6250          // N*F_IN/4 / 256
#define NB_WT1  128           // 128*256 / 256
#define NB_WT2  256           // 256*256 / 256
#define NB_HIST 3125          // E / 256
__global__ void k_prep(const float* __restrict__ x, unsigned short* __restrict__ xb,
                       const float* __restrict__ W1, unsigned short* __restrict__ W1t,
                       const float* __restrict__ W2, unsigned short* __restrict__ W2t,
                       const int* __restrict__ dst, int* __restrict__ counts,
                       unsigned short* __restrict__ rank) {
    int bid = blockIdx.x, tid = threadIdx.x;
    if (bid < NB_F2H) {
        int i = bid * 256 + tid;
        float4 v = *(const float4*)(x + (size_t)i * 4);
        ushort4 o = { f2h(v.x), f2h(v.y), f2h(v.z), f2h(v.w) };
        *(ushort4*)(xb + (size_t)i * 4) = o;
    } else if (bid < NB_F2H + NB_WT1) {
        int i = (bid - NB_F2H) * 256 + tid;
        int k = i >> 8, c = i & 255;
        W1t[c * F_IN + k] = f2h(W1[i]);
    } else if (bid < NB_F2H + NB_WT1 + NB_WT2) {
        int i = (bid - NB_F2H - NB_WT1) * 256 + tid;
        int k = i >> 8, c = i & 255;
        W2t[c * 256 + k] = f2h(W2[i]);
    } else {
        int i = (bid - NB_F2H - NB_WT1 - NB_WT2) * 256 + tid;
        if (i < N_EDGES) rank[i] = (unsigned short)atomicAdd(&counts[dst[i]], 1);
    }
}

// ---------------- CSR scan ----------------
__global__ __launch_bounds__(256) void k_scan1(const int* __restrict__ counts, int* __restrict__ incl,
                                               int* __restrict__ bsums, int n) {
    __shared__ int wsum[4];
    int blk = blockIdx.x, tid = threadIdx.x;
    int lane = tid & 63, w = tid >> 6;
    int i0 = blk * 1024 + tid * 4;
    int v[4];
    #pragma unroll
    for (int j = 0; j < 4; j++) v[j] = (i0 + j < n) ? counts[i0 + j] : 0;
    int t = v[0] + v[1] + v[2] + v[3];
    int x = t;
    #pragma unroll
    for (int d = 1; d < 64; d <<= 1) { int y = __shfl_up(x, d); if (lane >= d) x += y; }
    if (lane == 63) wsum[w] = x;
    __syncthreads();
    int woff = 0;
    #pragma unroll
    for (int ww = 0; ww < 4; ww++) woff += (ww < w) ? wsum[ww] : 0;
    int p = woff + x - t;
    #pragma unroll
    for (int j = 0; j < 4; j++) { p += v[j]; if (i0 + j < n) incl[i0 + j] = p; }
    if (tid == 255) bsums[blk] = woff + x;
}

__global__ void k_scan2(const int* __restrict__ bsums, int* __restrict__ boffs, int nb, int* rowptr_end) {
    int lane = threadIdx.x;
    int v = (lane < nb) ? bsums[lane] : 0;
    int x = v;
    #pragma unroll
    for (int d = 1; d < 64; d <<= 1) { int y = __shfl_up(x, d); if (lane >= d) x += y; }
    if (lane < nb) boffs[lane] = x - v;
    if (lane == 63) *rowptr_end = x;
}

__global__ void k_scan3(const int* __restrict__ incl, const int* __restrict__ counts,
                        const int* __restrict__ boffs, int* __restrict__ rowptr, int n) {
    int i = blockIdx.x * blockDim.x + threadIdx.x;
    if (i < n) rowptr[i] = boffs[i >> 10] + incl[i] - counts[i];
}

// ---------------- GEMM body (f16 MFMA, N=256) + fused per-node scores ----------
static __device__ __forceinline__ int swz(int r, int lc) {
    return r * 4 + (lc ^ (r & 3) ^ ((r >> 2) & 1));
}

static __device__ __forceinline__ void gemm_body(
        int bid, const unsigned short* __restrict__ A, const unsigned short* __restrict__ Bt,
        const float* __restrict__ asrc, const float* __restrict__ adst,
        unsigned short* __restrict__ C, float* __restrict__ s_src, float* __restrict__ s_dst,
        int M, int K, unsigned short* Asm, unsigned short* Bsm) {
    const int N = 256;
    int tid = threadIdx.x;
    int lane = tid & 63, wid = tid >> 6;
    int bx = bid & 1, by = bid >> 1;
    int row0 = by * 128, col0 = bx * 128;
    int wr = wid >> 1, wc = wid & 1;
    f32x4 acc[4][4] = {};

    for (int k0 = 0; k0 < K; k0 += 32) {
        __syncthreads();
        #pragma unroll
        for (int s = 0; s < 2; s++) {
            int c = tid + s * 256;
            int row = c >> 2, lc = c & 3;
            int gr = row0 + row; if (gr >= M) gr = 0;
            uint4 va = *(const uint4*)(A + (size_t)gr * K + k0 + lc * 8);
            *(uint4*)(&Asm[swz(row, lc) * 8]) = va;
            uint4 vb = *(const uint4*)(Bt + (size_t)(col0 + row) * K + k0 + lc * 8);
            *(uint4*)(&Bsm[swz(row, lc) * 8]) = vb;
        }
        __syncthreads();
        half8v af[4], bg[4];
        int lq = lane >> 4;
        #pragma unroll
        for (int m = 0; m < 4; m++) {
            int r = wr * 64 + m * 16 + (lane & 15);
            af[m] = *(const half8v*)(&Asm[swz(r, lq) * 8]);
        }
        #pragma unroll
        for (int n = 0; n < 4; n++) {
            int r = wc * 64 + n * 16 + (lane & 15);
            bg[n] = *(const half8v*)(&Bsm[swz(r, lq) * 8]);
        }
        #pragma unroll
        for (int m = 0; m < 4; m++)
            #pragma unroll
            for (int n = 0; n < 4; n++)
                acc[m][n] = __builtin_amdgcn_mfma_f32_16x16x32_f16(af[m], bg[n], acc[m][n], 0, 0, 0);
    }

    #pragma unroll
    for (int m = 0; m < 4; m++) {
        #pragma unroll
        for (int r = 0; r < 4; r++) {
            int row = row0 + wr * 64 + m * 16 + (lane >> 4) * 4 + r;
            if (row < M) {
                #pragma unroll
                for (int n = 0; n < 4; n++) {
                    C[(size_t)row * N + col0 + wc * 64 + n * 16 + (lane & 15)] = f2h(acc[m][n][r]);
                }
            }
        }
    }

    // fused attention scores: this wave's 64 cols = head (bx*2+wc)
    int c16 = lane & 15, lq = lane >> 4;
    int head = bx * 2 + wc;
    float avs[4], avd[4];
    #pragma unroll
    for (int nn = 0; nn < 4; nn++) {
        avs[nn] = asrc[head * 64 + nn * 16 + c16];
        avd[nn] = adst[head * 64 + nn * 16 + c16];
    }
    #pragma unroll
    for (int mm = 0; mm < 4; mm++) {
        #pragma unroll
        for (int r = 0; r < 4; r++) {
            float ps = 0.f, pd = 0.f;
            #pragma unroll
            for (int nn = 0; nn < 4; nn++) {
                ps += acc[mm][nn][r] * avs[nn];
                pd += acc[mm][nn][r] * avd[nn];
            }
            #pragma unroll
            for (int off = 1; off < 16; off <<= 1) {
                ps += __shfl_xor(ps, off);
                pd += __shfl_xor(pd, off);
            }
            if (c16 == 0) {
                int grow = row0 + wr * 64 + mm * 16 + lq * 4 + r;
                if (grow < M) {
                    s_src[grow * 4 + head] = ps;
                    s_dst[grow * 4 + head] = pd;
                }
            }
        }
    }
}

// standalone GEMM (layer 2)
__global__ __launch_bounds__(256) void k_gemm_mfma(const unsigned short* __restrict__ A,
                                                   const unsigned short* __restrict__ Bt,
                                                   const float* __restrict__ asrc,
                                                   const float* __restrict__ adst,
                                                   unsigned short* __restrict__ C,
                                                   float* __restrict__ s_src,
                                                   float* __restrict__ s_dst,
                                                   int M, int K) {
    __shared__ unsigned short Asm[128 * 32];
    __shared__ unsigned short Bsm[128 * 32];
    gemm_body(blockIdx.x, A, Bt, asrc, adst, C, s_src, s_dst, M, K, Asm, Bsm);
}

// fused: layer-1 GEMM (blocks [0,gemmBlocks)) + atomic-free CSR scatter (rest)
__global__ __launch_bounds__(256) void k_b(const unsigned short* __restrict__ A,
                                           const unsigned short* __restrict__ Bt,
                                           const float* __restrict__ asrc,
                                           const float* __restrict__ adst,
                                           unsigned short* __restrict__ C,
                                           float* __restrict__ s_src,
                                           float* __restrict__ s_dst,
                                           int M, int K, int gemmBlocks,
                                           const int* __restrict__ src, const int* __restrict__ dst,
                                           const int* __restrict__ rowptr,
                                           const unsigned short* __restrict__ rank,
                                           unsigned* __restrict__ colp, int e) {
    __shared__ unsigned short Asm[128 * 32];
    __shared__ unsigned short Bsm[128 * 32];
    int bid = blockIdx.x;
    if (bid < gemmBlocks) {
        gemm_body(bid, A, Bt, asrc, adst, C, s_src, s_dst, M, K, Asm, Bsm);
    } else {
        int half = (e + 1) >> 1;
        int i = (bid - gemmBlocks) * 256 + (int)threadIdx.x;
        if (i < half) {
            int d = dst[i];
            colp[rowptr[d] + rank[i]] = (unsigned)src[i] | ((unsigned)d << 16);
        }
        int j = i + half;
        if (j < e) {
            int d = dst[j];
            colp[rowptr[d] + rank[j]] = (unsigned)src[j] | ((unsigned)d << 16);
        }
    }
}

// ---------------- per-edge p = exp(score), CSR order, head-transposed (layers 1&2) ----
__global__ void k_escore(const unsigned* __restrict__ colp,
                         const float* __restrict__ s_src, const float* __restrict__ s_dst,
                         float* __restrict__ pT, int e) {
    int i = blockIdx.x * blockDim.x + threadIdx.x;
    if (i >= e) return;
    unsigned v = colp[i];
    int s = v & 0xffff, d = v >> 16;
    float4 ss = *(const float4*)(s_src + (size_t)s * 4);
    float4 ds = *(const float4*)(s_dst + (size_t)d * 4);
    pT[i]         = __expf(fminf(lrelu(ss.x + ds.x), 80.f));
    pT[e + i]     = __expf(fminf(lrelu(ss.y + ds.y), 80.f));
    pT[2 * e + i] = __expf(fminf(lrelu(ss.z + ds.z), 80.f));
    pT[3 * e + i] = __expf(fminf(lrelu(ss.w + ds.w), 80.f));
}

// layer-3 p (H=1)
__global__ void k_escore3(const unsigned* __restrict__ colp,
                          const float* __restrict__ s_src, const float* __restrict__ s_dst,
                          float* __restrict__ p, int e) {
    int i = blockIdx.x * blockDim.x + threadIdx.x;
    if (i >= e) return;
    unsigned v = colp[i];
    p[i] = __expf(fminf(lrelu(s_src[v & 0xffff] + s_dst[v >> 16]), 80.f));
}

// ---------------- single-pass aggregation, layers 1&2 (f16 h, precomputed p) --------
__global__ void k_aggregate(const unsigned short* __restrict__ h, const int* __restrict__ rowptr,
                            const unsigned* __restrict__ colp, const float* __restrict__ pT,
                            const float* __restrict__ s_src, const float* __restrict__ s_dst,
                            const float* __restrict__ bias,
                            unsigned short* __restrict__ out, int n, int e) {
    int wave = (blockIdx.x * blockDim.x + threadIdx.x) >> 6;
    int lane = threadIdx.x & 63;
    if (wave >= n) return;
    int half = lane >> 5, l5 = lane & 31;
    int head = l5 >> 3;          // 8 lanes x 8 feats = 64 feats per head
    unsigned foff = (unsigned)(l5 * 16);   // byte offset of this lane's 8 f16 feats
    const float* pp = pT + (size_t)head * e;
    const char* hc = (const char*)h;
    int rs = rowptr[wave], re = rowptr[wave + 1];

    float z = 0.f;
    float a[8] = {};
    if (half == 0) {
        float pself = __expf(fminf(lrelu(s_src[wave * 4 + head] + s_dst[wave * 4 + head]), 80.f));
        z = pself;
        uint4 own = *(const uint4*)(hc + (((unsigned)wave << 9) + foff));
        fma_mix2(a[0], a[1], pself, own.x);
        fma_mix2(a[2], a[3], pself, own.y);
        fma_mix2(a[4], a[5], pself, own.z);
        fma_mix2(a[6], a[7], pself, own.w);
    }
    int i = rs + half;
    // 8 gathers in flight per half (covers avg degree in one round)
    for (; i + 14 < re; i += 16) {
        unsigned cc[8]; float pv[8]; uint4 hv[8];
        #pragma unroll
        for (int j = 0; j < 8; j++) { cc[j] = colp[i + 2 * j]; pv[j] = pp[i + 2 * j]; }
        #pragma unroll
        for (int j = 0; j < 8; j++)
            hv[j] = *(const uint4*)(hc + (((cc[j] & 0xffffu) << 9) + foff));
        #pragma unroll
        for (int j = 0; j < 8; j++) {
            z += pv[j];
            fma_mix2(a[0], a[1], pv[j], hv[j].x); fma_mix2(a[2], a[3], pv[j], hv[j].y);
            fma_mix2(a[4], a[5], pv[j], hv[j].z); fma_mix2(a[6], a[7], pv[j], hv[j].w);
        }
    }
    for (; i + 6 < re; i += 8) {
        unsigned cc[4]; float pv[4]; uint4 hv[4];
        #pragma unroll
        for (int j = 0; j < 4; j++) { cc[j] = colp[i + 2 * j]; pv[j] = pp[i + 2 * j]; }
        #pragma unroll
        for (int j = 0; j < 4; j++)
            hv[j] = *(const uint4*)(hc + (((cc[j] & 0xffffu) << 9) + foff));
        #pragma unroll
        for (int j = 0; j < 4; j++) {
            z += pv[j];
            fma_mix2(a[0], a[1], pv[j], hv[j].x); fma_mix2(a[2], a[3], pv[j], hv[j].y);
            fma_mix2(a[4], a[5], pv[j], hv[j].z); fma_mix2(a[6], a[7], pv[j], hv[j].w);
        }
    }
    for (; i < re; i += 2) {
        unsigned c0 = colp[i];
        float p0 = pp[i];
        uint4 h0 = *(const uint4*)(hc + (((c0 & 0xffffu) << 9) + foff));
        z += p0;
        fma_mix2(a[0], a[1], p0, h0.x); fma_mix2(a[2], a[3], p0, h0.y);
        fma_mix2(a[4], a[5], p0, h0.z); fma_mix2(a[6], a[7], p0, h0.w);
    }
    // merge halves
    z += __shfl_xor(z, 32);
    #pragma unroll
    for (int j = 0; j < 8; j++) a[j] += __shfl_xor(a[j], 32);

    if (half == 0) {
        float inv = 1.f / z;
        int f0 = l5 * 8;
        float4 bv0 = *(const float4*)(bias + f0);
        float4 bv1 = *(const float4*)(bias + f0 + 4);
        float o[8];
        o[0] = a[0] * inv + bv0.x; o[1] = a[1] * inv + bv0.y;
        o[2] = a[2] * inv + bv0.z; o[3] = a[3] * inv + bv0.w;
        o[4] = a[4] * inv + bv1.x; o[5] = a[5] * inv + bv1.y;
        o[6] = a[6] * inv + bv1.z; o[7] = a[7] * inv + bv1.w;
        #pragma unroll
        for (int j = 0; j < 8; j++) o[j] = o[j] > 0.f ? o[j] : expm1f(o[j]);
        uint4 ov;
        unsigned* w = (unsigned*)&ov;
        #pragma unroll
        for (int j = 0; j < 4; j++)
            w[j] = (unsigned)f2h(o[2 * j]) | ((unsigned)f2h(o[2 * j + 1]) << 16);
        *(uint4*)(out + (size_t)wave * 256 + f0) = ov;
    }
}

// ---------------- layer 3: GEMM [M,256](f16)@[256,16](f32) + fused scores ----------
__global__ __launch_bounds__(256) void k_gemm3(const unsigned short* __restrict__ A,
                                               const float* __restrict__ B,
                                               const float* __restrict__ a3s,
                                               const float* __restrict__ a3d,
                                               float* __restrict__ C,
                                               float* __restrict__ s_src,
                                               float* __restrict__ s_dst,
                                               int M, int K) {
    __shared__ float Bs[256 * 16];
    for (int i = threadIdx.x; i < K * 16; i += 256) Bs[i] = B[i];
    __syncthreads();
    int tx = threadIdx.x & 15;
    int ty = threadIdx.x >> 4;
    int row = blockIdx.x * 16 + ty;
    if (row >= M) return;
    const unsigned short* Ar = A + (size_t)row * K;
    float acc = 0.f;
    for (int kk = 0; kk < K; kk += 8) {
        uint4 va = *(const uint4*)(Ar + kk);
        const unsigned* u = (const unsigned*)&va;
        #pragma unroll
        for (int j = 0; j < 4; j++) {
            float lo = h2f((unsigned short)(u[j] & 0xffff));
            float hi = h2f((unsigned short)(u[j] >> 16));
            acc += lo * Bs[(kk + 2 * j) * 16 + tx] + hi * Bs[(kk + 2 * j + 1) * 16 + tx];
        }
    }
    C[(size_t)row * 16 + tx] = acc;
    float ps = acc * a3s[tx], pd = acc * a3d[tx];
    #pragma unroll
    for (int off = 1; off < 16; off <<= 1) {
        ps += __shfl_xor(ps, off);
        pd += __shfl_xor(pd, off);
    }
    if (tx == 0) { s_src[row] = ps; s_dst[row] = pd; }
}

// ---------------- layer 3 aggregation + bias + log_softmax (precomputed p) ----------
__global__ void k_agg3(const float* __restrict__ h3, const int* __restrict__ rowptr,
                       const unsigned* __restrict__ colp, const float* __restrict__ pE,
                       const float* __restrict__ s_src, const float* __restrict__ s_dst,
                       const float* __restrict__ b3,
                       float* __restrict__ outp, int n) {
    int wave = (blockIdx.x * blockDim.x + threadIdx.x) >> 6;
    int lane = threadIdx.x & 63;
    if (wave >= n) return;
    int g = lane >> 4, c = lane & 15;
    int rs = rowptr[wave], re = rowptr[wave + 1];

    float z = 0.f, acc = 0.f;
    if (g == 0) {
        float p = __expf(fminf(lrelu(s_src[wave] + s_dst[wave]), 80.f));
        z += p;
        acc += p * h3[(size_t)wave * 16 + c];
    }
    for (int i = rs + g; i < re; i += 4) {
        int s = colp[i] & 0xffff;
        float p = pE[i];
        z += p;
        acc += p * h3[(size_t)s * 16 + c];
    }
    z += __shfl_xor(z, 16);  z += __shfl_xor(z, 32);
    acc += __shfl_xor(acc, 16); acc += __shfl_xor(acc, 32);
    if (lane < 16) {
        float v = acc / z + b3[c];
        float mm = v;
        #pragma unroll
        for (int off = 1; off < 16; off <<= 1) mm = fmaxf(mm, __shfl_xor(mm, off));
        float se = __expf(v - mm);
        #pragma unroll
        for (int off = 1; off < 16; off <<= 1) se += __shfl_xor(se, off);
        outp[(size_t)wave * 16 + c] = v - mm - logf(se);
    }
}

extern "C" void kernel_launch(void* const* d_in, const int* in_sizes, int n_in,
                              void* d_out, int out_size, void* d_ws, size_t ws_size,
                              hipStream_t stream) {
    const float* x      = (const float*)d_in[0];
    const int*   ei     = (const int*)d_in[1];
    const float* W1     = (const float*)d_in[2];
    const float* a1_src = (const float*)d_in[3];
    const float* a1_dst = (const float*)d_in[4];
    const float* b1     = (const float*)d_in[5];
    const float* W2     = (const float*)d_in[6];
    const float* a2_src = (const float*)d_in[7];
    const float* a2_dst = (const float*)d_in[8];
    const float* b2     = (const float*)d_in[9];
    const float* W3     = (const float*)d_in[10];
    const float* a3_src = (const float*)d_in[11];
    const float* a3_dst = (const float*)d_in[12];
    const float* b3     = (const float*)d_in[13];
    float* outp = (float*)d_out;

    const int N = N_NODES, E = N_EDGES;
    const int* src = ei;
    const int* dst = ei + E;

    char* ws = (char*)d_ws;
    size_t off = 0;
    auto alloc = [&](size_t bytes) {
        void* p = ws + off;
        off = (off + bytes + 255) & ~(size_t)255;
        return p;
    };
    int*   rowptr = (int*)alloc((N + 1) * sizeof(int));
    int*   counts = (int*)alloc(N * sizeof(int));
    unsigned* colp = (unsigned*)alloc(E * sizeof(unsigned));
    unsigned short* rank = (unsigned short*)alloc(E * sizeof(short));
    int*   incl   = (int*)alloc(N * sizeof(int));
    int*   bsums  = (int*)alloc(64 * sizeof(int));
    int*   boffs  = (int*)alloc(64 * sizeof(int));
    float* s_src  = (float*)alloc((size_t)N * HEADS * sizeof(float));
    float* s_dst  = (float*)alloc((size_t)N * HEADS * sizeof(float));
    float* pT     = (float*)alloc((size_t)E * HEADS * sizeof(float));
    unsigned short* xb  = (unsigned short*)alloc((size_t)N * F_IN * sizeof(short));
    unsigned short* W1t = (unsigned short*)alloc((size_t)256 * F_IN * sizeof(short));
    unsigned short* W2t = (unsigned short*)alloc((size_t)256 * 256 * sizeof(short));
    unsigned short* hA  = (unsigned short*)alloc((size_t)N * 256 * sizeof(short));
    unsigned short* hB  = (unsigned short*)alloc((size_t)N * 256 * sizeof(short));
    float* h3     = (float*)alloc((size_t)N * 16 * sizeof(float));
    (void)ws_size;

    const int aggBlocks = (N + 3) / 4;
    const int gemmBlocks = ((N + 127) / 128) * 2;
    const int edgeBlocks = (E + 255) / 256;
    const int scatBlocks = ((E + 1) / 2 + 255) / 256;

    // ---- prep: converts + histogram/ranks (fused) ----
    hipMemsetAsync(counts, 0, N * sizeof(int), stream);
    k_prep<<<NB_F2H + NB_WT1 + NB_WT2 + NB_HIST, 256, 0, stream>>>(x, xb, W1, W1t, W2, W2t,
                                                                   dst, counts, rank);

    // ---- CSR scan ----
    const int nb = (N + 1023) / 1024;
    k_scan1<<<nb, 256, 0, stream>>>(counts, incl, bsums, N);
    k_scan2<<<1, 64, 0, stream>>>(bsums, boffs, nb, rowptr + N);
    k_scan3<<<(N + 255) / 256, 256, 0, stream>>>(incl, counts, boffs, rowptr, N);

    // ---- fused: layer-1 GEMM + atomic-free scatter ----
    k_b<<<gemmBlocks + scatBlocks, 256, 0, stream>>>(xb, W1t, a1_src, a1_dst, hA, s_src, s_dst,
                                                     N, F_IN, gemmBlocks,
                                                     src, dst, rowptr, rank, colp, E);
    // ---- layer 1 ----
    k_escore<<<edgeBlocks, 256, 0, stream>>>(colp, s_src, s_dst, pT, E);
    k_aggregate<<<aggBlocks, 256, 0, stream>>>(hA, rowptr, colp, pT, s_src, s_dst, b1, hB, N, E);
    // ---- layer 2 ----
    k_gemm_mfma<<<gemmBlocks, 256, 0, stream>>>(hB, W2t, a2_src, a2_dst, hA, s_src, s_dst, N, 256);
    k_escore<<<edgeBlocks, 256, 0, stream>>>(colp, s_src, s_dst, pT, E);
    k_aggregate<<<aggBlocks, 256, 0, stream>>>(hA, rowptr, colp, pT, s_src, s_dst, b2, hB, N, E);
    // ---- layer 3 ----
    k_gemm3<<<(N + 15) / 16, 256, 0, stream>>>(hB, W3, a3_src, a3_dst, h3, s_src, s_dst, N, 256);
    k_escore3<<<edgeBlocks, 256, 0, stream>>>(colp, s_src, s_dst, pT, E);
    k_agg3<<<aggBlocks, 256, 0, stream>>>(h3, rowptr, colp, pT, s_src, s_dst, b3, outp, N);
}

// Round 10
// 289.927 us; speedup vs baseline: 2.2056x; 1.0625x over previous
//
#include <hip/hip_runtime.h>
#include <hip/hip_bf16.h>
#include <math.h>

#define N_NODES 50000
#define N_EDGES 800000
#define F_IN    128
#define HID     64
#define HEADS   4
#define NCLS    16
#define NEG_SLOPE 0.2f

typedef __attribute__((ext_vector_type(8))) _Float16 half8v;
typedef __attribute__((ext_vector_type(4))) float f32x4;

static __device__ __forceinline__ float lrelu(float x) {
    return x >= 0.f ? x : NEG_SLOPE * x;
}
static __device__ __forceinline__ unsigned short f2h(float f) {
    _Float16 h = (_Float16)f;
    return __builtin_bit_cast(unsigned short, h);
}
static __device__ __forceinline__ float h2f(unsigned short u) {
    return (float)__builtin_bit_cast(_Float16, u);
}
// a_lo += p * f16lo(hu); a_hi += p * f16hi(hu)   (v_fma_mix_f32)
static __device__ __forceinline__ void fma_mix2(float& alo, float& ahi, float p, unsigned hu) {
    asm("v_fma_mix_f32 %0, %1, %2, %0 op_sel:[0,0,0] op_sel_hi:[0,1,0]"
        : "+v"(alo) : "v"(p), "v"(hu));
    asm("v_fma_mix_f32 %0, %1, %2, %0 op_sel:[0,1,0] op_sel_hi:[0,1,0]"
        : "+v"(ahi) : "v"(p), "v"(hu));
}

// ---------------- fused prep: W1t, W2t, edge histogram + ranks ----------------
#define NB_WT1  128           // 128*256 / 256
#define NB_WT2  256           // 256*256 / 256
#define NB_HIST 3125          // E / 256
__global__ void k_prep(const float* __restrict__ W1, unsigned short* __restrict__ W1t,
                       const float* __restrict__ W2, unsigned short* __restrict__ W2t,
                       const int* __restrict__ dst, int* __restrict__ counts,
                       unsigned short* __restrict__ rank) {
    int bid = blockIdx.x, tid = threadIdx.x;
    if (bid < NB_WT1) {
        int i = bid * 256 + tid;
        int k = i >> 8, c = i & 255;
        W1t[c * F_IN + k] = f2h(W1[i]);
    } else if (bid < NB_WT1 + NB_WT2) {
        int i = (bid - NB_WT1) * 256 + tid;
        int k = i >> 8, c = i & 255;
        W2t[c * 256 + k] = f2h(W2[i]);
    } else {
        int i = (bid - NB_WT1 - NB_WT2) * 256 + tid;
        if (i < N_EDGES) rank[i] = (unsigned short)atomicAdd(&counts[dst[i]], 1);
    }
}

// ---------------- CSR scan ----------------
__global__ __launch_bounds__(256) void k_scan1(const int* __restrict__ counts, int* __restrict__ incl,
                                               int* __restrict__ bsums, int n) {
    __shared__ int wsum[4];
    int blk = blockIdx.x, tid = threadIdx.x;
    int lane = tid & 63, w = tid >> 6;
    int i0 = blk * 1024 + tid * 4;
    int v[4];
    #pragma unroll
    for (int j = 0; j < 4; j++) v[j] = (i0 + j < n) ? counts[i0 + j] : 0;
    int t = v[0] + v[1] + v[2] + v[3];
    int x = t;
    #pragma unroll
    for (int d = 1; d < 64; d <<= 1) { int y = __shfl_up(x, d); if (lane >= d) x += y; }
    if (lane == 63) wsum[w] = x;
    __syncthreads();
    int woff = 0;
    #pragma unroll
    for (int ww = 0; ww < 4; ww++) woff += (ww < w) ? wsum[ww] : 0;
    int p = woff + x - t;
    #pragma unroll
    for (int j = 0; j < 4; j++) { p += v[j]; if (i0 + j < n) incl[i0 + j] = p; }
    if (tid == 255) bsums[blk] = woff + x;
}

__global__ void k_scan2(const int* __restrict__ bsums, int* __restrict__ boffs, int nb, int* rowptr_end) {
    int lane = threadIdx.x;
    int v = (lane < nb) ? bsums[lane] : 0;
    int x = v;
    #pragma unroll
    for (int d = 1; d < 64; d <<= 1) { int y = __shfl_up(x, d); if (lane >= d) x += y; }
    if (lane < nb) boffs[lane] = x - v;
    if (lane == 63) *rowptr_end = x;
}

__global__ void k_scan3(const int* __restrict__ incl, const int* __restrict__ counts,
                        const int* __restrict__ boffs, int* __restrict__ rowptr, int n) {
    int i = blockIdx.x * blockDim.x + threadIdx.x;
    if (i < n) rowptr[i] = boffs[i >> 10] + incl[i] - counts[i];
}

// ---------------- GEMM body (f16 MFMA, N=256) + fused per-node scores ----------
// CONVA: A is f32 and converted to f16 during LDS staging (layer 1 reads x directly)
static __device__ __forceinline__ int swz(int r, int lc) {
    return r * 4 + (lc ^ (r & 3) ^ ((r >> 2) & 1));
}

template<int CONVA>
static __device__ __forceinline__ void gemm_body(
        int bid, const void* __restrict__ Av, const unsigned short* __restrict__ Bt,
        const float* __restrict__ asrc, const float* __restrict__ adst,
        unsigned short* __restrict__ C, float* __restrict__ s_src, float* __restrict__ s_dst,
        int M, int K, unsigned short* Asm, unsigned short* Bsm) {
    const int N = 256;
    int tid = threadIdx.x;
    int lane = tid & 63, wid = tid >> 6;
    int bx = bid & 1, by = bid >> 1;
    int row0 = by * 128, col0 = bx * 128;
    int wr = wid >> 1, wc = wid & 1;
    f32x4 acc[4][4] = {};

    for (int k0 = 0; k0 < K; k0 += 32) {
        __syncthreads();
        #pragma unroll
        for (int s = 0; s < 2; s++) {
            int c = tid + s * 256;
            int row = c >> 2, lc = c & 3;
            int gr = row0 + row; if (gr >= M) gr = 0;
            uint4 va;
            if (CONVA) {
                const float* Af = (const float*)Av + (size_t)gr * K + k0 + lc * 8;
                float4 fa = *(const float4*)Af;
                float4 fb = *(const float4*)(Af + 4);
                va.x = (unsigned)f2h(fa.x) | ((unsigned)f2h(fa.y) << 16);
                va.y = (unsigned)f2h(fa.z) | ((unsigned)f2h(fa.w) << 16);
                va.z = (unsigned)f2h(fb.x) | ((unsigned)f2h(fb.y) << 16);
                va.w = (unsigned)f2h(fb.z) | ((unsigned)f2h(fb.w) << 16);
            } else {
                va = *(const uint4*)((const unsigned short*)Av + (size_t)gr * K + k0 + lc * 8);
            }
            *(uint4*)(&Asm[swz(row, lc) * 8]) = va;
            uint4 vb = *(const uint4*)(Bt + (size_t)(col0 + row) * K + k0 + lc * 8);
            *(uint4*)(&Bsm[swz(row, lc) * 8]) = vb;
        }
        __syncthreads();
        half8v af[4], bg[4];
        int lq = lane >> 4;
        #pragma unroll
        for (int m = 0; m < 4; m++) {
            int r = wr * 64 + m * 16 + (lane & 15);
            af[m] = *(const half8v*)(&Asm[swz(r, lq) * 8]);
        }
        #pragma unroll
        for (int n = 0; n < 4; n++) {
            int r = wc * 64 + n * 16 + (lane & 15);
            bg[n] = *(const half8v*)(&Bsm[swz(r, lq) * 8]);
        }
        #pragma unroll
        for (int m = 0; m < 4; m++)
            #pragma unroll
            for (int n = 0; n < 4; n++)
                acc[m][n] = __builtin_amdgcn_mfma_f32_16x16x32_f16(af[m], bg[n], acc[m][n], 0, 0, 0);
    }

    #pragma unroll
    for (int m = 0; m < 4; m++) {
        #pragma unroll
        for (int r = 0; r < 4; r++) {
            int row = row0 + wr * 64 + m * 16 + (lane >> 4) * 4 + r;
            if (row < M) {
                #pragma unroll
                for (int n = 0; n < 4; n++) {
                    C[(size_t)row * N + col0 + wc * 64 + n * 16 + (lane & 15)] = f2h(acc[m][n][r]);
                }
            }
        }
    }

    // fused attention scores: this wave's 64 cols = head (bx*2+wc)
    int c16 = lane & 15, lq = lane >> 4;
    int head = bx * 2 + wc;
    float avs[4], avd[4];
    #pragma unroll
    for (int nn = 0; nn < 4; nn++) {
        avs[nn] = asrc[head * 64 + nn * 16 + c16];
        avd[nn] = adst[head * 64 + nn * 16 + c16];
    }
    #pragma unroll
    for (int mm = 0; mm < 4; mm++) {
        #pragma unroll
        for (int r = 0; r < 4; r++) {
            float ps = 0.f, pd = 0.f;
            #pragma unroll
            for (int nn = 0; nn < 4; nn++) {
                ps += acc[mm][nn][r] * avs[nn];
                pd += acc[mm][nn][r] * avd[nn];
            }
            #pragma unroll
            for (int off = 1; off < 16; off <<= 1) {
                ps += __shfl_xor(ps, off);
                pd += __shfl_xor(pd, off);
            }
            if (c16 == 0) {
                int grow = row0 + wr * 64 + mm * 16 + lq * 4 + r;
                if (grow < M) {
                    s_src[grow * 4 + head] = ps;
                    s_dst[grow * 4 + head] = pd;
                }
            }
        }
    }
}

// standalone GEMM (layer 2, f16 A)
__global__ __launch_bounds__(256) void k_gemm_mfma(const unsigned short* __restrict__ A,
                                                   const unsigned short* __restrict__ Bt,
                                                   const float* __restrict__ asrc,
                                                   const float* __restrict__ adst,
                                                   unsigned short* __restrict__ C,
                                                   float* __restrict__ s_src,
                                                   float* __restrict__ s_dst,
                                                   int M, int K) {
    __shared__ unsigned short Asm[128 * 32];
    __shared__ unsigned short Bsm[128 * 32];
    gemm_body<0>(blockIdx.x, A, Bt, asrc, adst, C, s_src, s_dst, M, K, Asm, Bsm);
}

// fused: layer-1 GEMM (f32 A, converted in staging) + atomic-free CSR scatter
__global__ __launch_bounds__(256) void k_b(const float* __restrict__ A,
                                           const unsigned short* __restrict__ Bt,
                                           const float* __restrict__ asrc,
                                           const float* __restrict__ adst,
                                           unsigned short* __restrict__ C,
                                           float* __restrict__ s_src,
                                           float* __restrict__ s_dst,
                                           int M, int K, int gemmBlocks,
                                           const int* __restrict__ src, const int* __restrict__ dst,
                                           const int* __restrict__ rowptr,
                                           const unsigned short* __restrict__ rank,
                                           unsigned* __restrict__ colp, int e) {
    __shared__ unsigned short Asm[128 * 32];
    __shared__ unsigned short Bsm[128 * 32];
    int bid = blockIdx.x;
    if (bid < gemmBlocks) {
        gemm_body<1>(bid, A, Bt, asrc, adst, C, s_src, s_dst, M, K, Asm, Bsm);
    } else {
        int half = (e + 1) >> 1;
        int i = (bid - gemmBlocks) * 256 + (int)threadIdx.x;
        if (i < half) {
            int d = dst[i];
            colp[rowptr[d] + rank[i]] = (unsigned)src[i] | ((unsigned)d << 16);
        }
        int j = i + half;
        if (j < e) {
            int d = dst[j];
            colp[rowptr[d] + rank[j]] = (unsigned)src[j] | ((unsigned)d << 16);
        }
    }
}

// ---------------- per-edge p = exp(score), [edge][head] float4 layout ----------
__global__ void k_escore(const unsigned* __restrict__ colp,
                         const float* __restrict__ s_src, const float* __restrict__ s_dst,
                         float4* __restrict__ pT4, int e) {
    int i = blockIdx.x * blockDim.x + threadIdx.x;
    if (i >= e) return;
    unsigned v = colp[i];
    int s = v & 0xffff, d = v >> 16;
    float4 ss = *(const float4*)(s_src + (size_t)s * 4);
    float4 ds = *(const float4*)(s_dst + (size_t)d * 4);
    float4 o;
    o.x = __expf(fminf(lrelu(ss.x + ds.x), 80.f));
    o.y = __expf(fminf(lrelu(ss.y + ds.y), 80.f));
    o.z = __expf(fminf(lrelu(ss.z + ds.z), 80.f));
    o.w = __expf(fminf(lrelu(ss.w + ds.w), 80.f));
    pT4[i] = o;
}

// ---------------- single-pass aggregation, layers 1&2 (f16 h, precomputed p) --------
__global__ void k_aggregate(const unsigned short* __restrict__ h, const int* __restrict__ rowptr,
                            const unsigned* __restrict__ colp, const float* __restrict__ pT4,
                            const float* __restrict__ s_src, const float* __restrict__ s_dst,
                            const float* __restrict__ bias,
                            unsigned short* __restrict__ out, int n, int e) {
    int wave = (blockIdx.x * blockDim.x + threadIdx.x) >> 6;
    int lane = threadIdx.x & 63;
    if (wave >= n) return;
    int half = lane >> 5, l5 = lane & 31;
    int head = l5 >> 3;          // 8 lanes x 8 feats = 64 feats per head
    unsigned foff = (unsigned)(l5 * 16);   // byte offset of this lane's 8 f16 feats
    const float* pp = pT4 + head;          // [edge][head]
    const char* hc = (const char*)h;
    int rs = rowptr[wave], re = rowptr[wave + 1];

    float z = 0.f;
    float a[8] = {};
    if (half == 0) {
        float pself = __expf(fminf(lrelu(s_src[wave * 4 + head] + s_dst[wave * 4 + head]), 80.f));
        z = pself;
        uint4 own = *(const uint4*)(hc + (((unsigned)wave << 9) + foff));
        fma_mix2(a[0], a[1], pself, own.x);
        fma_mix2(a[2], a[3], pself, own.y);
        fma_mix2(a[4], a[5], pself, own.z);
        fma_mix2(a[6], a[7], pself, own.w);
    }
    int i = rs + half;
    // 8 gathers in flight per half (covers avg degree in one round)
    for (; i + 14 < re; i += 16) {
        unsigned cc[8]; float pv[8]; uint4 hv[8];
        #pragma unroll
        for (int j = 0; j < 8; j++) { cc[j] = colp[i + 2 * j]; pv[j] = pp[(i + 2 * j) * 4]; }
        #pragma unroll
        for (int j = 0; j < 8; j++)
            hv[j] = *(const uint4*)(hc + (((cc[j] & 0xffffu) << 9) + foff));
        #pragma unroll
        for (int j = 0; j < 8; j++) {
            z += pv[j];
            fma_mix2(a[0], a[1], pv[j], hv[j].x); fma_mix2(a[2], a[3], pv[j], hv[j].y);
            fma_mix2(a[4], a[5], pv[j], hv[j].z); fma_mix2(a[6], a[7], pv[j], hv[j].w);
        }
    }
    for (; i + 6 < re; i += 8) {
        unsigned cc[4]; float pv[4]; uint4 hv[4];
        #pragma unroll
        for (int j = 0; j < 4; j++) { cc[j] = colp[i + 2 * j]; pv[j] = pp[(i + 2 * j) * 4]; }
        #pragma unroll
        for (int j = 0; j < 4; j++)
            hv[j] = *(const uint4*)(hc + (((cc[j] & 0xffffu) << 9) + foff));
        #pragma unroll
        for (int j = 0; j < 4; j++) {
            z += pv[j];
            fma_mix2(a[0], a[1], pv[j], hv[j].x); fma_mix2(a[2], a[3], pv[j], hv[j].y);
            fma_mix2(a[4], a[5], pv[j], hv[j].z); fma_mix2(a[6], a[7], pv[j], hv[j].w);
        }
    }
    for (; i < re; i += 2) {
        unsigned c0 = colp[i];
        float p0 = pp[i * 4];
        uint4 h0 = *(const uint4*)(hc + (((c0 & 0xffffu) << 9) + foff));
        z += p0;
        fma_mix2(a[0], a[1], p0, h0.x); fma_mix2(a[2], a[3], p0, h0.y);
        fma_mix2(a[4], a[5], p0, h0.z); fma_mix2(a[6], a[7], p0, h0.w);
    }
    // merge halves
    z += __shfl_xor(z, 32);
    #pragma unroll
    for (int j = 0; j < 8; j++) a[j] += __shfl_xor(a[j], 32);

    if (half == 0) {
        float inv = 1.f / z;
        int f0 = l5 * 8;
        float4 bv0 = *(const float4*)(bias + f0);
        float4 bv1 = *(const float4*)(bias + f0 + 4);
        float o[8];
        o[0] = a[0] * inv + bv0.x; o[1] = a[1] * inv + bv0.y;
        o[2] = a[2] * inv + bv0.z; o[3] = a[3] * inv + bv0.w;
        o[4] = a[4] * inv + bv1.x; o[5] = a[5] * inv + bv1.y;
        o[6] = a[6] * inv + bv1.z; o[7] = a[7] * inv + bv1.w;
        #pragma unroll
        for (int j = 0; j < 8; j++) o[j] = o[j] > 0.f ? o[j] : expm1f(o[j]);
        uint4 ov;
        unsigned* w = (unsigned*)&ov;
        #pragma unroll
        for (int j = 0; j < 4; j++)
            w[j] = (unsigned)f2h(o[2 * j]) | ((unsigned)f2h(o[2 * j + 1]) << 16);
        *(uint4*)(out + (size_t)wave * 256 + f0) = ov;
    }
}

// ---------------- layer 3: GEMM [M,256](f16)@[256,16](f32) + fused scores ----------
__global__ __launch_bounds__(256) void k_gemm3(const unsigned short* __restrict__ A,
                                               const float* __restrict__ B,
                                               const float* __restrict__ a3s,
                                               const float* __restrict__ a3d,
                                               float* __restrict__ C,
                                               float* __restrict__ s_src,
                                               float* __restrict__ s_dst,
                                               int M, int K) {
    __shared__ float Bs[256 * 16];
    for (int i = threadIdx.x; i < K * 16; i += 256) Bs[i] = B[i];
    __syncthreads();
    int tx = threadIdx.x & 15;
    int ty = threadIdx.x >> 4;
    int row = blockIdx.x * 16 + ty;
    if (row >= M) return;
    const unsigned short* Ar = A + (size_t)row * K;
    float acc = 0.f;
    for (int kk = 0; kk < K; kk += 8) {
        uint4 va = *(const uint4*)(Ar + kk);
        const unsigned* u = (const unsigned*)&va;
        #pragma unroll
        for (int j = 0; j < 4; j++) {
            float lo = h2f((unsigned short)(u[j] & 0xffff));
            float hi = h2f((unsigned short)(u[j] >> 16));
            acc += lo * Bs[(kk + 2 * j) * 16 + tx] + hi * Bs[(kk + 2 * j + 1) * 16 + tx];
        }
    }
    C[(size_t)row * 16 + tx] = acc;
    float ps = acc * a3s[tx], pd = acc * a3d[tx];
    #pragma unroll
    for (int off = 1; off < 16; off <<= 1) {
        ps += __shfl_xor(ps, off);
        pd += __shfl_xor(pd, off);
    }
    if (tx == 0) { s_src[row] = ps; s_dst[row] = pd; }
}

// ---------------- layer 3 aggregation + inline scores + bias + log_softmax ----------
__global__ void k_agg3(const float* __restrict__ h3, const int* __restrict__ rowptr,
                       const unsigned* __restrict__ colp,
                       const float* __restrict__ s_src, const float* __restrict__ s_dst,
                       const float* __restrict__ b3,
                       float* __restrict__ outp, int n) {
    int wave = (blockIdx.x * blockDim.x + threadIdx.x) >> 6;
    int lane = threadIdx.x & 63;
    if (wave >= n) return;
    int g = lane >> 4, c = lane & 15;
    int rs = rowptr[wave], re = rowptr[wave + 1];
    float sdn = s_dst[wave];

    float z = 0.f, acc = 0.f;
    if (g == 0) {
        float p = __expf(fminf(lrelu(s_src[wave] + sdn), 80.f));
        z += p;
        acc += p * h3[(size_t)wave * 16 + c];
    }
    int i = rs + g;
    for (; i + 4 < re; i += 8) {
        int s0 = colp[i] & 0xffff, s1 = colp[i + 4] & 0xffff;
        float q0 = s_src[s0], q1 = s_src[s1];
        float v0 = h3[(size_t)s0 * 16 + c], v1 = h3[(size_t)s1 * 16 + c];
        float p0 = __expf(fminf(lrelu(q0 + sdn), 80.f));
        float p1 = __expf(fminf(lrelu(q1 + sdn), 80.f));
        z += p0 + p1;
        acc += p0 * v0 + p1 * v1;
    }
    for (; i < re; i += 4) {
        int s = colp[i] & 0xffff;
        float p = __expf(fminf(lrelu(s_src[s] + sdn), 80.f));
        z += p;
        acc += p * h3[(size_t)s * 16 + c];
    }
    z += __shfl_xor(z, 16);  z += __shfl_xor(z, 32);
    acc += __shfl_xor(acc, 16); acc += __shfl_xor(acc, 32);
    if (lane < 16) {
        float v = acc / z + b3[c];
        float mm = v;
        #pragma unroll
        for (int off = 1; off < 16; off <<= 1) mm = fmaxf(mm, __shfl_xor(mm, off));
        float se = __expf(v - mm);
        #pragma unroll
        for (int off = 1; off < 16; off <<= 1) se += __shfl_xor(se, off);
        outp[(size_t)wave * 16 + c] = v - mm - logf(se);
    }
}

extern "C" void kernel_launch(void* const* d_in, const int* in_sizes, int n_in,
                              void* d_out, int out_size, void* d_ws, size_t ws_size,
                              hipStream_t stream) {
    const float* x      = (const float*)d_in[0];
    const int*   ei     = (const int*)d_in[1];
    const float* W1     = (const float*)d_in[2];
    const float* a1_src = (const float*)d_in[3];
    const float* a1_dst = (const float*)d_in[4];
    const float* b1     = (const float*)d_in[5];
    const float* W2     = (const float*)d_in[6];
    const float* a2_src = (const float*)d_in[7];
    const float* a2_dst = (const float*)d_in[8];
    const float* b2     = (const float*)d_in[9];
    const float* W3     = (const float*)d_in[10];
    const float* a3_src = (const float*)d_in[11];
    const float* a3_dst = (const float*)d_in[12];
    const float* b3     = (const float*)d_in[13];
    float* outp = (float*)d_out;

    const int N = N_NODES, E = N_EDGES;
    const int* src = ei;
    const int* dst = ei + E;

    char* ws = (char*)d_ws;
    size_t off = 0;
    auto alloc = [&](size_t bytes) {
        void* p = ws + off;
        off = (off + bytes + 255) & ~(size_t)255;
        return p;
    };
    int*   rowptr = (int*)alloc((N + 1) * sizeof(int));
    int*   counts = (int*)alloc(N * sizeof(int));
    unsigned* colp = (unsigned*)alloc(E * sizeof(unsigned));
    unsigned short* rank = (unsigned short*)alloc(E * sizeof(short));
    int*   incl   = (int*)alloc(N * sizeof(int));
    int*   bsums  = (int*)alloc(64 * sizeof(int));
    int*   boffs  = (int*)alloc(64 * sizeof(int));
    float* s_src  = (float*)alloc((size_t)N * HEADS * sizeof(float));
    float* s_dst  = (float*)alloc((size_t)N * HEADS * sizeof(float));
    float4* pT4   = (float4*)alloc((size_t)E * sizeof(float4));
    unsigned short* W1t = (unsigned short*)alloc((size_t)256 * F_IN * sizeof(short));
    unsigned short* W2t = (unsigned short*)alloc((size_t)256 * 256 * sizeof(short));
    unsigned short* hA  = (unsigned short*)alloc((size_t)N * 256 * sizeof(short));
    unsigned short* hB  = (unsigned short*)alloc((size_t)N * 256 * sizeof(short));
    float* h3     = (float*)alloc((size_t)N * 16 * sizeof(float));
    (void)ws_size;

    const int aggBlocks = (N + 3) / 4;
    const int gemmBlocks = ((N + 127) / 128) * 2;
    const int edgeBlocks = (E + 255) / 256;
    const int scatBlocks = ((E + 1) / 2 + 255) / 256;

    // ---- prep: W transposes + histogram/ranks (fused) ----
    hipMemsetAsync(counts, 0, N * sizeof(int), stream);
    k_prep<<<NB_WT1 + NB_WT2 + NB_HIST, 256, 0, stream>>>(W1, W1t, W2, W2t, dst, counts, rank);

    // ---- CSR scan ----
    const int nb = (N + 1023) / 1024;
    k_scan1<<<nb, 256, 0, stream>>>(counts, incl, bsums, N);
    k_scan2<<<1, 64, 0, stream>>>(bsums, boffs, nb, rowptr + N);
    k_scan3<<<(N + 255) / 256, 256, 0, stream>>>(incl, counts, boffs, rowptr, N);

    // ---- fused: layer-1 GEMM (f32 x, converted in staging) + atomic-free scatter ----
    k_b<<<gemmBlocks + scatBlocks, 256, 0, stream>>>(x, W1t, a1_src, a1_dst, hA, s_src, s_dst,
                                                     N, F_IN, gemmBlocks,
                                                     src, dst, rowptr, rank, colp, E);
    // ---- layer 1 ----
    k_escore<<<edgeBlocks, 256, 0, stream>>>(colp, s_src, s_dst, pT4, E);
    k_aggregate<<<aggBlocks, 256, 0, stream>>>(hA, rowptr, colp, (const float*)pT4,
                                               s_src, s_dst, b1, hB, N, E);
    // ---- layer 2 ----
    k_gemm_mfma<<<gemmBlocks, 256, 0, stream>>>(hB, W2t, a2_src, a2_dst, hA, s_src, s_dst, N, 256);
    k_escore<<<edgeBlocks, 256, 0, stream>>>(colp, s_src, s_dst, pT4, E);
    k_aggregate<<<aggBlocks, 256, 0, stream>>>(hA, rowptr, colp, (const float*)pT4,
                                               s_src, s_dst, b2, hB, N, E);
    // ---- layer 3 ----
    k_gemm3<<<(N + 15) / 16, 256, 0, stream>>>(hB, W3, a3_src, a3_dst, h3, s_src, s_dst, N, 256);
    k_agg3<<<aggBlocks, 256, 0, stream>>>(h3, rowptr, colp, s_src, s_dst, b3, outp, N);
}

// Round 11
// 250.407 us; speedup vs baseline: 2.5537x; 1.1578x over previous
//
#include <hip/hip_runtime.h>
#include <hip/hip_bf16.h>
#include <math.h>

#define N_NODES 50000
#define N_EDGES 800000
#define F_IN    128
#define HID     64
#define HEADS   4
#define NCLS    16
#define NEG_SLOPE 0.2f

typedef __attribute__((ext_vector_type(8))) _Float16 half8v;
typedef __attribute__((ext_vector_type(4))) float f32x4;
typedef __attribute__((ext_vector_type(2))) float f32x2;

static __device__ __forceinline__ float lrelu(float x) {
    return x >= 0.f ? x : NEG_SLOPE * x;
}
static __device__ __forceinline__ unsigned short f2h(float f) {
    _Float16 h = (_Float16)f;
    return __builtin_bit_cast(unsigned short, h);
}
static __device__ __forceinline__ float h2f(unsigned short u) {
    return (float)__builtin_bit_cast(_Float16, u);
}

// ---------------- fused prep: W1t, W2t, edge histogram + ranks ----------------
#define NB_WT1  128           // 128*256 / 256
#define NB_WT2  256           // 256*256 / 256
#define NB_HIST 3125          // E / 256
__global__ void k_prep(const float* __restrict__ W1, unsigned short* __restrict__ W1t,
                       const float* __restrict__ W2, unsigned short* __restrict__ W2t,
                       const int* __restrict__ dst, int* __restrict__ counts,
                       unsigned short* __restrict__ rank) {
    int bid = blockIdx.x, tid = threadIdx.x;
    if (bid < NB_WT1) {
        int i = bid * 256 + tid;
        int k = i >> 8, c = i & 255;
        W1t[c * F_IN + k] = f2h(W1[i]);
    } else if (bid < NB_WT1 + NB_WT2) {
        int i = (bid - NB_WT1) * 256 + tid;
        int k = i >> 8, c = i & 255;
        W2t[c * 256 + k] = f2h(W2[i]);
    } else {
        int i = (bid - NB_WT1 - NB_WT2) * 256 + tid;
        if (i < N_EDGES) rank[i] = (unsigned short)atomicAdd(&counts[dst[i]], 1);
    }
}

// ---------------- CSR scan ----------------
__global__ __launch_bounds__(256) void k_scan1(const int* __restrict__ counts, int* __restrict__ incl,
                                               int* __restrict__ bsums, int n) {
    __shared__ int wsum[4];
    int blk = blockIdx.x, tid = threadIdx.x;
    int lane = tid & 63, w = tid >> 6;
    int i0 = blk * 1024 + tid * 4;
    int v[4];
    #pragma unroll
    for (int j = 0; j < 4; j++) v[j] = (i0 + j < n) ? counts[i0 + j] : 0;
    int t = v[0] + v[1] + v[2] + v[3];
    int x = t;
    #pragma unroll
    for (int d = 1; d < 64; d <<= 1) { int y = __shfl_up(x, d); if (lane >= d) x += y; }
    if (lane == 63) wsum[w] = x;
    __syncthreads();
    int woff = 0;
    #pragma unroll
    for (int ww = 0; ww < 4; ww++) woff += (ww < w) ? wsum[ww] : 0;
    int p = woff + x - t;
    #pragma unroll
    for (int j = 0; j < 4; j++) { p += v[j]; if (i0 + j < n) incl[i0 + j] = p; }
    if (tid == 255) bsums[blk] = woff + x;
}

__global__ void k_scan2(const int* __restrict__ bsums, int* __restrict__ boffs, int nb, int* rowptr_end) {
    int lane = threadIdx.x;
    int v = (lane < nb) ? bsums[lane] : 0;
    int x = v;
    #pragma unroll
    for (int d = 1; d < 64; d <<= 1) { int y = __shfl_up(x, d); if (lane >= d) x += y; }
    if (lane < nb) boffs[lane] = x - v;
    if (lane == 63) *rowptr_end = x;
}

__global__ void k_scan3(const int* __restrict__ incl, const int* __restrict__ counts,
                        const int* __restrict__ boffs, int* __restrict__ rowptr, int n) {
    int i = blockIdx.x * blockDim.x + threadIdx.x;
    if (i < n) rowptr[i] = boffs[i >> 10] + incl[i] - counts[i];
}

// ---------------- GEMM body (f16 MFMA, N=256) + fused per-node scores ----------
// CONVA: A is f32, converted to f16 during LDS staging. C output is fp8 e4m3.
static __device__ __forceinline__ int swz(int r, int lc) {
    return r * 4 + (lc ^ (r & 3) ^ ((r >> 2) & 1));
}

template<int CONVA>
static __device__ __forceinline__ void gemm_body(
        int bid, const void* __restrict__ Av, const unsigned short* __restrict__ Bt,
        const float* __restrict__ asrc, const float* __restrict__ adst,
        unsigned char* __restrict__ C8, float* __restrict__ s_src, float* __restrict__ s_dst,
        int M, int K, unsigned short* Asm, unsigned short* Bsm) {
    int tid = threadIdx.x;
    int lane = tid & 63, wid = tid >> 6;
    int bx = bid & 1, by = bid >> 1;
    int row0 = by * 128, col0 = bx * 128;
    int wr = wid >> 1, wc = wid & 1;
    f32x4 acc[4][4] = {};

    for (int k0 = 0; k0 < K; k0 += 32) {
        __syncthreads();
        #pragma unroll
        for (int s = 0; s < 2; s++) {
            int c = tid + s * 256;
            int row = c >> 2, lc = c & 3;
            int gr = row0 + row; if (gr >= M) gr = 0;
            uint4 va;
            if (CONVA) {
                const float* Af = (const float*)Av + (size_t)gr * K + k0 + lc * 8;
                float4 fa = *(const float4*)Af;
                float4 fb = *(const float4*)(Af + 4);
                va.x = (unsigned)f2h(fa.x) | ((unsigned)f2h(fa.y) << 16);
                va.y = (unsigned)f2h(fa.z) | ((unsigned)f2h(fa.w) << 16);
                va.z = (unsigned)f2h(fb.x) | ((unsigned)f2h(fb.y) << 16);
                va.w = (unsigned)f2h(fb.z) | ((unsigned)f2h(fb.w) << 16);
            } else {
                va = *(const uint4*)((const unsigned short*)Av + (size_t)gr * K + k0 + lc * 8);
            }
            *(uint4*)(&Asm[swz(row, lc) * 8]) = va;
            uint4 vb = *(const uint4*)(Bt + (size_t)(col0 + row) * K + k0 + lc * 8);
            *(uint4*)(&Bsm[swz(row, lc) * 8]) = vb;
        }
        __syncthreads();
        half8v af[4], bg[4];
        int lq = lane >> 4;
        #pragma unroll
        for (int m = 0; m < 4; m++) {
            int r = wr * 64 + m * 16 + (lane & 15);
            af[m] = *(const half8v*)(&Asm[swz(r, lq) * 8]);
        }
        #pragma unroll
        for (int n = 0; n < 4; n++) {
            int r = wc * 64 + n * 16 + (lane & 15);
            bg[n] = *(const half8v*)(&Bsm[swz(r, lq) * 8]);
        }
        #pragma unroll
        for (int m = 0; m < 4; m++)
            #pragma unroll
            for (int n = 0; n < 4; n++)
                acc[m][n] = __builtin_amdgcn_mfma_f32_16x16x32_f16(af[m], bg[n], acc[m][n], 0, 0, 0);
    }

    // C write: fp8 e4m3, row stride 256 B
    #pragma unroll
    for (int m = 0; m < 4; m++) {
        #pragma unroll
        for (int r = 0; r < 4; r++) {
            int row = row0 + wr * 64 + m * 16 + (lane >> 4) * 4 + r;
            if (row < M) {
                int q01 = __builtin_amdgcn_cvt_pk_fp8_f32(acc[m][0][r], acc[m][1][r], 0, false);
                int q23 = __builtin_amdgcn_cvt_pk_fp8_f32(acc[m][2][r], acc[m][3][r], 0, false);
                size_t base = (size_t)row * 256 + col0 + wc * 64 + (lane & 15);
                C8[base]      = (unsigned char)(q01 & 0xff);
                C8[base + 16] = (unsigned char)((q01 >> 8) & 0xff);
                C8[base + 32] = (unsigned char)(q23 & 0xff);
                C8[base + 48] = (unsigned char)((q23 >> 8) & 0xff);
            }
        }
    }

    // fused attention scores: this wave's 64 cols = head (bx*2+wc)
    int c16 = lane & 15, lq = lane >> 4;
    int head = bx * 2 + wc;
    float avs[4], avd[4];
    #pragma unroll
    for (int nn = 0; nn < 4; nn++) {
        avs[nn] = asrc[head * 64 + nn * 16 + c16];
        avd[nn] = adst[head * 64 + nn * 16 + c16];
    }
    #pragma unroll
    for (int mm = 0; mm < 4; mm++) {
        #pragma unroll
        for (int r = 0; r < 4; r++) {
            float ps = 0.f, pd = 0.f;
            #pragma unroll
            for (int nn = 0; nn < 4; nn++) {
                ps += acc[mm][nn][r] * avs[nn];
                pd += acc[mm][nn][r] * avd[nn];
            }
            #pragma unroll
            for (int off = 1; off < 16; off <<= 1) {
                ps += __shfl_xor(ps, off);
                pd += __shfl_xor(pd, off);
            }
            if (c16 == 0) {
                int grow = row0 + wr * 64 + mm * 16 + lq * 4 + r;
                if (grow < M) {
                    s_src[grow * 4 + head] = ps;
                    s_dst[grow * 4 + head] = pd;
                }
            }
        }
    }
}

// standalone GEMM (layer 2, f16 A, fp8 C)
__global__ __launch_bounds__(256) void k_gemm_mfma(const unsigned short* __restrict__ A,
                                                   const unsigned short* __restrict__ Bt,
                                                   const float* __restrict__ asrc,
                                                   const float* __restrict__ adst,
                                                   unsigned char* __restrict__ C8,
                                                   float* __restrict__ s_src,
                                                   float* __restrict__ s_dst,
                                                   int M, int K) {
    __shared__ unsigned short Asm[128 * 32];
    __shared__ unsigned short Bsm[128 * 32];
    gemm_body<0>(blockIdx.x, A, Bt, asrc, adst, C8, s_src, s_dst, M, K, Asm, Bsm);
}

// fused: layer-1 GEMM (f32 A, fp8 C) + atomic-free CSR scatter
__global__ __launch_bounds__(256) void k_b(const float* __restrict__ A,
                                           const unsigned short* __restrict__ Bt,
                                           const float* __restrict__ asrc,
                                           const float* __restrict__ adst,
                                           unsigned char* __restrict__ C8,
                                           float* __restrict__ s_src,
                                           float* __restrict__ s_dst,
                                           int M, int K, int gemmBlocks,
                                           const int* __restrict__ src, const int* __restrict__ dst,
                                           const int* __restrict__ rowptr,
                                           const unsigned short* __restrict__ rank,
                                           unsigned* __restrict__ colp, int e) {
    __shared__ unsigned short Asm[128 * 32];
    __shared__ unsigned short Bsm[128 * 32];
    int bid = blockIdx.x;
    if (bid < gemmBlocks) {
        gemm_body<1>(bid, A, Bt, asrc, adst, C8, s_src, s_dst, M, K, Asm, Bsm);
    } else {
        int half = (e + 1) >> 1;
        int i = (bid - gemmBlocks) * 256 + (int)threadIdx.x;
        if (i < half) {
            int d = dst[i];
            colp[rowptr[d] + rank[i]] = (unsigned)src[i] | ((unsigned)d << 16);
        }
        int j = i + half;
        if (j < e) {
            int d = dst[j];
            colp[rowptr[d] + rank[j]] = (unsigned)src[j] | ((unsigned)d << 16);
        }
    }
}

// ---------------- per-edge p = exp(score), [edge][head] float4 layout ----------
__global__ void k_escore(const unsigned* __restrict__ colp,
                         const float* __restrict__ s_src, const float* __restrict__ s_dst,
                         float4* __restrict__ pT4, int e) {
    int i = blockIdx.x * blockDim.x + threadIdx.x;
    if (i >= e) return;
    unsigned v = colp[i];
    int s = v & 0xffff, d = v >> 16;
    float4 ss = *(const float4*)(s_src + (size_t)s * 4);
    float4 ds = *(const float4*)(s_dst + (size_t)d * 4);
    float4 o;
    o.x = __expf(fminf(lrelu(ss.x + ds.x), 80.f));
    o.y = __expf(fminf(lrelu(ss.y + ds.y), 80.f));
    o.z = __expf(fminf(lrelu(ss.z + ds.z), 80.f));
    o.w = __expf(fminf(lrelu(ss.w + ds.w), 80.f));
    pT4[i] = o;
}

// ---------------- single-pass aggregation, layers 1&2 (fp8 h, precomputed p) --------
__global__ void k_aggregate(const unsigned char* __restrict__ h8, const int* __restrict__ rowptr,
                            const unsigned* __restrict__ colp, const float* __restrict__ pT4,
                            const float* __restrict__ s_src, const float* __restrict__ s_dst,
                            const float* __restrict__ bias,
                            unsigned short* __restrict__ out, int n, int e) {
    int wave = (blockIdx.x * blockDim.x + threadIdx.x) >> 6;
    int lane = threadIdx.x & 63;
    if (wave >= n) return;
    int half = lane >> 5, l5 = lane & 31;
    int head = l5 >> 3;          // 8 lanes x 8 feats = 64 feats per head
    unsigned foff = (unsigned)(l5 * 8);    // byte offset of this lane's 8 fp8 feats
    const float* pp = pT4 + head;          // [edge][head]
    int rs = rowptr[wave], re = rowptr[wave + 1];

    float z = 0.f;
    float a[8] = {};
    #define ACC8(P, HV) { \
        f32x2 v0 = __builtin_amdgcn_cvt_pk_f32_fp8((HV).x, false); \
        f32x2 v1 = __builtin_amdgcn_cvt_pk_f32_fp8((HV).x, true);  \
        f32x2 v2 = __builtin_amdgcn_cvt_pk_f32_fp8((HV).y, false); \
        f32x2 v3 = __builtin_amdgcn_cvt_pk_f32_fp8((HV).y, true);  \
        a[0] += (P) * v0.x; a[1] += (P) * v0.y; \
        a[2] += (P) * v1.x; a[3] += (P) * v1.y; \
        a[4] += (P) * v2.x; a[5] += (P) * v2.y; \
        a[6] += (P) * v3.x; a[7] += (P) * v3.y; }

    if (half == 0) {
        float pself = __expf(fminf(lrelu(s_src[wave * 4 + head] + s_dst[wave * 4 + head]), 80.f));
        z = pself;
        uint2 own = *(const uint2*)(h8 + (((unsigned)wave << 8) + foff));
        ACC8(pself, own);
    }
    int i = rs + half;
    // 8 gathers in flight per half
    for (; i + 14 < re; i += 16) {
        unsigned cc[8]; float pv[8]; uint2 hv[8];
        #pragma unroll
        for (int j = 0; j < 8; j++) { cc[j] = colp[i + 2 * j]; pv[j] = pp[(i + 2 * j) * 4]; }
        #pragma unroll
        for (int j = 0; j < 8; j++)
            hv[j] = *(const uint2*)(h8 + (((cc[j] & 0xffffu) << 8) + foff));
        #pragma unroll
        for (int j = 0; j < 8; j++) {
            z += pv[j];
            ACC8(pv[j], hv[j]);
        }
    }
    for (; i + 6 < re; i += 8) {
        unsigned cc[4]; float pv[4]; uint2 hv[4];
        #pragma unroll
        for (int j = 0; j < 4; j++) { cc[j] = colp[i + 2 * j]; pv[j] = pp[(i + 2 * j) * 4]; }
        #pragma unroll
        for (int j = 0; j < 4; j++)
            hv[j] = *(const uint2*)(h8 + (((cc[j] & 0xffffu) << 8) + foff));
        #pragma unroll
        for (int j = 0; j < 4; j++) {
            z += pv[j];
            ACC8(pv[j], hv[j]);
        }
    }
    for (; i < re; i += 2) {
        unsigned c0 = colp[i];
        float p0 = pp[i * 4];
        uint2 h0 = *(const uint2*)(h8 + (((c0 & 0xffffu) << 8) + foff));
        z += p0;
        ACC8(p0, h0);
    }
    #undef ACC8
    // merge halves
    z += __shfl_xor(z, 32);
    #pragma unroll
    for (int j = 0; j < 8; j++) a[j] += __shfl_xor(a[j], 32);

    if (half == 0) {
        float inv = 1.f / z;
        int f0 = l5 * 8;
        float4 bv0 = *(const float4*)(bias + f0);
        float4 bv1 = *(const float4*)(bias + f0 + 4);
        float o[8];
        o[0] = a[0] * inv + bv0.x; o[1] = a[1] * inv + bv0.y;
        o[2] = a[2] * inv + bv0.z; o[3] = a[3] * inv + bv0.w;
        o[4] = a[4] * inv + bv1.x; o[5] = a[5] * inv + bv1.y;
        o[6] = a[6] * inv + bv1.z; o[7] = a[7] * inv + bv1.w;
        #pragma unroll
        for (int j = 0; j < 8; j++) o[j] = o[j] > 0.f ? o[j] : expm1f(o[j]);
        uint4 ov;
        unsigned* w = (unsigned*)&ov;
        #pragma unroll
        for (int j = 0; j < 4; j++)
            w[j] = (unsigned)f2h(o[2 * j]) | ((unsigned)f2h(o[2 * j + 1]) << 16);
        *(uint4*)(out + (size_t)wave * 256 + f0) = ov;
    }
}

// ---------------- layer 3: GEMM [M,256](f16)@[256,16](f32) + fused scores ----------
__global__ __launch_bounds__(256) void k_gemm3(const unsigned short* __restrict__ A,
                                               const float* __restrict__ B,
                                               const float* __restrict__ a3s,
                                               const float* __restrict__ a3d,
                                               float* __restrict__ C,
                                               float* __restrict__ s_src,
                                               float* __restrict__ s_dst,
                                               int M, int K) {
    __shared__ float Bs[256 * 16];
    for (int i = threadIdx.x; i < K * 16; i += 256) Bs[i] = B[i];
    __syncthreads();
    int tx = threadIdx.x & 15;
    int ty = threadIdx.x >> 4;
    int row = blockIdx.x * 16 + ty;
    if (row >= M) return;
    const unsigned short* Ar = A + (size_t)row * K;
    float acc = 0.f;
    for (int kk = 0; kk < K; kk += 8) {
        uint4 va = *(const uint4*)(Ar + kk);
        const unsigned* u = (const unsigned*)&va;
        #pragma unroll
        for (int j = 0; j < 4; j++) {
            float lo = h2f((unsigned short)(u[j] & 0xffff));
            float hi = h2f((unsigned short)(u[j] >> 16));
            acc += lo * Bs[(kk + 2 * j) * 16 + tx] + hi * Bs[(kk + 2 * j + 1) * 16 + tx];
        }
    }
    C[(size_t)row * 16 + tx] = acc;
    float ps = acc * a3s[tx], pd = acc * a3d[tx];
    #pragma unroll
    for (int off = 1; off < 16; off <<= 1) {
        ps += __shfl_xor(ps, off);
        pd += __shfl_xor(pd, off);
    }
    if (tx == 0) { s_src[row] = ps; s_dst[row] = pd; }
}

// ---------------- layer 3 aggregation + inline scores + bias + log_softmax ----------
__global__ void k_agg3(const float* __restrict__ h3, const int* __restrict__ rowptr,
                       const unsigned* __restrict__ colp,
                       const float* __restrict__ s_src, const float* __restrict__ s_dst,
                       const float* __restrict__ b3,
                       float* __restrict__ outp, int n) {
    int wave = (blockIdx.x * blockDim.x + threadIdx.x) >> 6;
    int lane = threadIdx.x & 63;
    if (wave >= n) return;
    int g = lane >> 4, c = lane & 15;
    int rs = rowptr[wave], re = rowptr[wave + 1];
    float sdn = s_dst[wave];

    float z = 0.f, acc = 0.f;
    if (g == 0) {
        float p = __expf(fminf(lrelu(s_src[wave] + sdn), 80.f));
        z += p;
        acc += p * h3[(size_t)wave * 16 + c];
    }
    int i = rs + g;
    for (; i + 4 < re; i += 8) {
        int s0 = colp[i] & 0xffff, s1 = colp[i + 4] & 0xffff;
        float q0 = s_src[s0], q1 = s_src[s1];
        float v0 = h3[(size_t)s0 * 16 + c], v1 = h3[(size_t)s1 * 16 + c];
        float p0 = __expf(fminf(lrelu(q0 + sdn), 80.f));
        float p1 = __expf(fminf(lrelu(q1 + sdn), 80.f));
        z += p0 + p1;
        acc += p0 * v0 + p1 * v1;
    }
    for (; i < re; i += 4) {
        int s = colp[i] & 0xffff;
        float p = __expf(fminf(lrelu(s_src[s] + sdn), 80.f));
        z += p;
        acc += p * h3[(size_t)s * 16 + c];
    }
    z += __shfl_xor(z, 16);  z += __shfl_xor(z, 32);
    acc += __shfl_xor(acc, 16); acc += __shfl_xor(acc, 32);
    if (lane < 16) {
        float v = acc / z + b3[c];
        float mm = v;
        #pragma unroll
        for (int off = 1; off < 16; off <<= 1) mm = fmaxf(mm, __shfl_xor(mm, off));
        float se = __expf(v - mm);
        #pragma unroll
        for (int off = 1; off < 16; off <<= 1) se += __shfl_xor(se, off);
        outp[(size_t)wave * 16 + c] = v - mm - logf(se);
    }
}

extern "C" void kernel_launch(void* const* d_in, const int* in_sizes, int n_in,
                              void* d_out, int out_size, void* d_ws, size_t ws_size,
                              hipStream_t stream) {
    const float* x      = (const float*)d_in[0];
    const int*   ei     = (const int*)d_in[1];
    const float* W1     = (const float*)d_in[2];
    const float* a1_src = (const float*)d_in[3];
    const float* a1_dst = (const float*)d_in[4];
    const float* b1     = (const float*)d_in[5];
    const float* W2     = (const float*)d_in[6];
    const float* a2_src = (const float*)d_in[7];
    const float* a2_dst = (const float*)d_in[8];
    const float* b2     = (const float*)d_in[9];
    const float* W3     = (const float*)d_in[10];
    const float* a3_src = (const float*)d_in[11];
    const float* a3_dst = (const float*)d_in[12];
    const float* b3     = (const float*)d_in[13];
    float* outp = (float*)d_out;

    const int N = N_NODES, E = N_EDGES;
    const int* src = ei;
    const int* dst = ei + E;

    char* ws = (char*)d_ws;
    size_t off = 0;
    auto alloc = [&](size_t bytes) {
        void* p = ws + off;
        off = (off + bytes + 255) & ~(size_t)255;
        return p;
    };
    int*   rowptr = (int*)alloc((N + 1) * sizeof(int));
    int*   counts = (int*)alloc(N * sizeof(int));
    unsigned* colp = (unsigned*)alloc(E * sizeof(unsigned));
    unsigned short* rank = (unsigned short*)alloc(E * sizeof(short));
    int*   incl   = (int*)alloc(N * sizeof(int));
    int*   bsums  = (int*)alloc(64 * sizeof(int));
    int*   boffs  = (int*)alloc(64 * sizeof(int));
    float* s_src  = (float*)alloc((size_t)N * HEADS * sizeof(float));
    float* s_dst  = (float*)alloc((size_t)N * HEADS * sizeof(float));
    float4* pT4   = (float4*)alloc((size_t)E * sizeof(float4));
    unsigned short* W1t = (unsigned short*)alloc((size_t)256 * F_IN * sizeof(short));
    unsigned short* W2t = (unsigned short*)alloc((size_t)256 * 256 * sizeof(short));
    unsigned char* hA8  = (unsigned char*)alloc((size_t)N * 256);          // fp8 e4m3
    unsigned short* hB  = (unsigned short*)alloc((size_t)N * 256 * sizeof(short));
    float* h3     = (float*)alloc((size_t)N * 16 * sizeof(float));
    (void)ws_size;

    const int aggBlocks = (N + 3) / 4;
    const int gemmBlocks = ((N + 127) / 128) * 2;
    const int edgeBlocks = (E + 255) / 256;
    const int scatBlocks = ((E + 1) / 2 + 255) / 256;

    // ---- prep: W transposes + histogram/ranks (fused) ----
    hipMemsetAsync(counts, 0, N * sizeof(int), stream);
    k_prep<<<NB_WT1 + NB_WT2 + NB_HIST, 256, 0, stream>>>(W1, W1t, W2, W2t, dst, counts, rank);

    // ---- CSR scan ----
    const int nb = (N + 1023) / 1024;
    k_scan1<<<nb, 256, 0, stream>>>(counts, incl, bsums, N);
    k_scan2<<<1, 64, 0, stream>>>(bsums, boffs, nb, rowptr + N);
    k_scan3<<<(N + 255) / 256, 256, 0, stream>>>(incl, counts, boffs, rowptr, N);

    // ---- fused: layer-1 GEMM (f32 x -> fp8 hA) + atomic-free scatter ----
    k_b<<<gemmBlocks + scatBlocks, 256, 0, stream>>>(x, W1t, a1_src, a1_dst, hA8, s_src, s_dst,
                                                     N, F_IN, gemmBlocks,
                                                     src, dst, rowptr, rank, colp, E);
    // ---- layer 1 ----
    k_escore<<<edgeBlocks, 256, 0, stream>>>(colp, s_src, s_dst, pT4, E);
    k_aggregate<<<aggBlocks, 256, 0, stream>>>(hA8, rowptr, colp, (const float*)pT4,
                                               s_src, s_dst, b1, hB, N, E);
    // ---- layer 2 ----
    k_gemm_mfma<<<gemmBlocks, 256, 0, stream>>>(hB, W2t, a2_src, a2_dst, hA8, s_src, s_dst, N, 256);
    k_escore<<<edgeBlocks, 256, 0, stream>>>(colp, s_src, s_dst, pT4, E);
    k_aggregate<<<aggBlocks, 256, 0, stream>>>(hA8, rowptr, colp, (const float*)pT4,
                                               s_src, s_dst, b2, hB, N, E);
    // ---- layer 3 ----
    k_gemm3<<<(N + 15) / 16, 256, 0, stream>>>(hB, W3, a3_src, a3_dst, h3, s_src, s_dst, N, 256);
    k_agg3<<<aggBlocks, 256, 0, stream>>>(h3, rowptr, colp, s_src, s_dst, b3, outp, N);
}

// Round 12
// 241.045 us; speedup vs baseline: 2.6529x; 1.0388x over previous
//
#include <hip/hip_runtime.h>
#include <hip/hip_bf16.h>
#include <math.h>

#define N_NODES 50000
#define N_EDGES 800000
#define F_IN    128
#define HID     64
#define HEADS   4
#define NCLS    16
#define NEG_SLOPE 0.2f

typedef __attribute__((ext_vector_type(8))) _Float16 half8v;
typedef __attribute__((ext_vector_type(4))) float f32x4;
typedef __attribute__((ext_vector_type(2))) float f32x2;

static __device__ __forceinline__ float lrelu(float x) {
    return x >= 0.f ? x : NEG_SLOPE * x;
}
static __device__ __forceinline__ unsigned short f2h(float f) {
    _Float16 h = (_Float16)f;
    return __builtin_bit_cast(unsigned short, h);
}
static __device__ __forceinline__ float h2f(unsigned short u) {
    return (float)__builtin_bit_cast(_Float16, u);
}

// ---------------- fused prep: W1t, W2t, edge histogram + ranks ----------------
#define NB_WT1  128           // 128*256 / 256
#define NB_WT2  256           // 256*256 / 256
#define NB_HIST 3125          // E / 256
__global__ void k_prep(const float* __restrict__ W1, unsigned short* __restrict__ W1t,
                       const float* __restrict__ W2, unsigned short* __restrict__ W2t,
                       const int* __restrict__ dst, int* __restrict__ counts,
                       unsigned short* __restrict__ rank) {
    int bid = blockIdx.x, tid = threadIdx.x;
    if (bid < NB_WT1) {
        int i = bid * 256 + tid;
        int k = i >> 8, c = i & 255;
        W1t[c * F_IN + k] = f2h(W1[i]);
    } else if (bid < NB_WT1 + NB_WT2) {
        int i = (bid - NB_WT1) * 256 + tid;
        int k = i >> 8, c = i & 255;
        W2t[c * 256 + k] = f2h(W2[i]);
    } else {
        int i = (bid - NB_WT1 - NB_WT2) * 256 + tid;
        if (i < N_EDGES) rank[i] = (unsigned short)atomicAdd(&counts[dst[i]], 1);
    }
}

// ---------------- CSR scan ----------------
__global__ __launch_bounds__(256) void k_scan1(const int* __restrict__ counts, int* __restrict__ incl,
                                               int* __restrict__ bsums, int n) {
    __shared__ int wsum[4];
    int blk = blockIdx.x, tid = threadIdx.x;
    int lane = tid & 63, w = tid >> 6;
    int i0 = blk * 1024 + tid * 4;
    int v[4];
    #pragma unroll
    for (int j = 0; j < 4; j++) v[j] = (i0 + j < n) ? counts[i0 + j] : 0;
    int t = v[0] + v[1] + v[2] + v[3];
    int x = t;
    #pragma unroll
    for (int d = 1; d < 64; d <<= 1) { int y = __shfl_up(x, d); if (lane >= d) x += y; }
    if (lane == 63) wsum[w] = x;
    __syncthreads();
    int woff = 0;
    #pragma unroll
    for (int ww = 0; ww < 4; ww++) woff += (ww < w) ? wsum[ww] : 0;
    int p = woff + x - t;
    #pragma unroll
    for (int j = 0; j < 4; j++) { p += v[j]; if (i0 + j < n) incl[i0 + j] = p; }
    if (tid == 255) bsums[blk] = woff + x;
}

__global__ void k_scan2(const int* __restrict__ bsums, int* __restrict__ boffs, int nb, int* rowptr_end) {
    int lane = threadIdx.x;
    int v = (lane < nb) ? bsums[lane] : 0;
    int x = v;
    #pragma unroll
    for (int d = 1; d < 64; d <<= 1) { int y = __shfl_up(x, d); if (lane >= d) x += y; }
    if (lane < nb) boffs[lane] = x - v;
    if (lane == 63) *rowptr_end = x;
}

__global__ void k_scan3(const int* __restrict__ incl, const int* __restrict__ counts,
                        const int* __restrict__ boffs, int* __restrict__ rowptr, int n) {
    int i = blockIdx.x * blockDim.x + threadIdx.x;
    if (i < n) rowptr[i] = boffs[i >> 10] + incl[i] - counts[i];
}

// ---------------- GEMM body (f16 MFMA, N=256) + fused per-node scores ----------
// CONVA: A is f32, converted to f16 during LDS staging. C output is fp8 e4m3.
static __device__ __forceinline__ int swz(int r, int lc) {
    return r * 4 + (lc ^ (r & 3) ^ ((r >> 2) & 1));
}

template<int CONVA>
static __device__ __forceinline__ void gemm_body(
        int bid, const void* __restrict__ Av, const unsigned short* __restrict__ Bt,
        const float* __restrict__ asrc, const float* __restrict__ adst,
        unsigned char* __restrict__ C8, float* __restrict__ s_src, float* __restrict__ s_dst,
        int M, int K, unsigned short* Asm, unsigned short* Bsm) {
    int tid = threadIdx.x;
    int lane = tid & 63, wid = tid >> 6;
    int bx = bid & 1, by = bid >> 1;
    int row0 = by * 128, col0 = bx * 128;
    int wr = wid >> 1, wc = wid & 1;
    f32x4 acc[4][4] = {};

    for (int k0 = 0; k0 < K; k0 += 32) {
        __syncthreads();
        #pragma unroll
        for (int s = 0; s < 2; s++) {
            int c = tid + s * 256;
            int row = c >> 2, lc = c & 3;
            int gr = row0 + row; if (gr >= M) gr = 0;
            uint4 va;
            if (CONVA) {
                const float* Af = (const float*)Av + (size_t)gr * K + k0 + lc * 8;
                float4 fa = *(const float4*)Af;
                float4 fb = *(const float4*)(Af + 4);
                va.x = (unsigned)f2h(fa.x) | ((unsigned)f2h(fa.y) << 16);
                va.y = (unsigned)f2h(fa.z) | ((unsigned)f2h(fa.w) << 16);
                va.z = (unsigned)f2h(fb.x) | ((unsigned)f2h(fb.y) << 16);
                va.w = (unsigned)f2h(fb.z) | ((unsigned)f2h(fb.w) << 16);
            } else {
                va = *(const uint4*)((const unsigned short*)Av + (size_t)gr * K + k0 + lc * 8);
            }
            *(uint4*)(&Asm[swz(row, lc) * 8]) = va;
            uint4 vb = *(const uint4*)(Bt + (size_t)(col0 + row) * K + k0 + lc * 8);
            *(uint4*)(&Bsm[swz(row, lc) * 8]) = vb;
        }
        __syncthreads();
        half8v af[4], bg[4];
        int lq = lane >> 4;
        #pragma unroll
        for (int m = 0; m < 4; m++) {
            int r = wr * 64 + m * 16 + (lane & 15);
            af[m] = *(const half8v*)(&Asm[swz(r, lq) * 8]);
        }
        #pragma unroll
        for (int n = 0; n < 4; n++) {
            int r = wc * 64 + n * 16 + (lane & 15);
            bg[n] = *(const half8v*)(&Bsm[swz(r, lq) * 8]);
        }
        #pragma unroll
        for (int m = 0; m < 4; m++)
            #pragma unroll
            for (int n = 0; n < 4; n++)
                acc[m][n] = __builtin_amdgcn_mfma_f32_16x16x32_f16(af[m], bg[n], acc[m][n], 0, 0, 0);
    }

    // C write: fp8 e4m3, row stride 256 B
    #pragma unroll
    for (int m = 0; m < 4; m++) {
        #pragma unroll
        for (int r = 0; r < 4; r++) {
            int row = row0 + wr * 64 + m * 16 + (lane >> 4) * 4 + r;
            if (row < M) {
                int q01 = __builtin_amdgcn_cvt_pk_fp8_f32(acc[m][0][r], acc[m][1][r], 0, false);
                int q23 = __builtin_amdgcn_cvt_pk_fp8_f32(acc[m][2][r], acc[m][3][r], 0, false);
                size_t base = (size_t)row * 256 + col0 + wc * 64 + (lane & 15);
                C8[base]      = (unsigned char)(q01 & 0xff);
                C8[base + 16] = (unsigned char)((q01 >> 8) & 0xff);
                C8[base + 32] = (unsigned char)(q23 & 0xff);
                C8[base + 48] = (unsigned char)((q23 >> 8) & 0xff);
            }
        }
    }

    // fused attention scores: this wave's 64 cols = head (bx*2+wc)
    int c16 = lane & 15, lq = lane >> 4;
    int head = bx * 2 + wc;
    float avs[4], avd[4];
    #pragma unroll
    for (int nn = 0; nn < 4; nn++) {
        avs[nn] = asrc[head * 64 + nn * 16 + c16];
        avd[nn] = adst[head * 64 + nn * 16 + c16];
    }
    #pragma unroll
    for (int mm = 0; mm < 4; mm++) {
        #pragma unroll
        for (int r = 0; r < 4; r++) {
            float ps = 0.f, pd = 0.f;
            #pragma unroll
            for (int nn = 0; nn < 4; nn++) {
                ps += acc[mm][nn][r] * avs[nn];
                pd += acc[mm][nn][r] * avd[nn];
            }
            #pragma unroll
            for (int off = 1; off < 16; off <<= 1) {
                ps += __shfl_xor(ps, off);
                pd += __shfl_xor(pd, off);
            }
            if (c16 == 0) {
                int grow = row0 + wr * 64 + mm * 16 + lq * 4 + r;
                if (grow < M) {
                    s_src[grow * 4 + head] = ps;
                    s_dst[grow * 4 + head] = pd;
                }
            }
        }
    }
}

// standalone GEMM (layer 2, f16 A, fp8 C)
__global__ __launch_bounds__(256) void k_gemm_mfma(const unsigned short* __restrict__ A,
                                                   const unsigned short* __restrict__ Bt,
                                                   const float* __restrict__ asrc,
                                                   const float* __restrict__ adst,
                                                   unsigned char* __restrict__ C8,
                                                   float* __restrict__ s_src,
                                                   float* __restrict__ s_dst,
                                                   int M, int K) {
    __shared__ unsigned short Asm[128 * 32];
    __shared__ unsigned short Bsm[128 * 32];
    gemm_body<0>(blockIdx.x, A, Bt, asrc, adst, C8, s_src, s_dst, M, K, Asm, Bsm);
}

// fused: layer-1 GEMM (f32 A, fp8 C) + atomic-free CSR scatter
__global__ __launch_bounds__(256) void k_b(const float* __restrict__ A,
                                           const unsigned short* __restrict__ Bt,
                                           const float* __restrict__ asrc,
                                           const float* __restrict__ adst,
                                           unsigned char* __restrict__ C8,
                                           float* __restrict__ s_src,
                                           float* __restrict__ s_dst,
                                           int M, int K, int gemmBlocks,
                                           const int* __restrict__ src, const int* __restrict__ dst,
                                           const int* __restrict__ rowptr,
                                           const unsigned short* __restrict__ rank,
                                           unsigned* __restrict__ colp, int e) {
    __shared__ unsigned short Asm[128 * 32];
    __shared__ unsigned short Bsm[128 * 32];
    int bid = blockIdx.x;
    if (bid < gemmBlocks) {
        gemm_body<1>(bid, A, Bt, asrc, adst, C8, s_src, s_dst, M, K, Asm, Bsm);
    } else {
        int half = (e + 1) >> 1;
        int i = (bid - gemmBlocks) * 256 + (int)threadIdx.x;
        if (i < half) {
            int d = dst[i];
            colp[rowptr[d] + rank[i]] = (unsigned)src[i] | ((unsigned)d << 16);
        }
        int j = i + half;
        if (j < e) {
            int d = dst[j];
            colp[rowptr[d] + rank[j]] = (unsigned)src[j] | ((unsigned)d << 16);
        }
    }
}

// ---------------- per-edge p = exp(score), [edge][head] float4 layout ----------
__global__ void k_escore(const unsigned* __restrict__ colp,
                         const float* __restrict__ s_src, const float* __restrict__ s_dst,
                         float4* __restrict__ pT4, int e) {
    int i = blockIdx.x * blockDim.x + threadIdx.x;
    if (i >= e) return;
    unsigned v = colp[i];
    int s = v & 0xffff, d = v >> 16;
    float4 ss = *(const float4*)(s_src + (size_t)s * 4);
    float4 ds = *(const float4*)(s_dst + (size_t)d * 4);
    float4 o;
    o.x = __expf(fminf(lrelu(ss.x + ds.x), 80.f));
    o.y = __expf(fminf(lrelu(ss.y + ds.y), 80.f));
    o.z = __expf(fminf(lrelu(ss.z + ds.z), 80.f));
    o.w = __expf(fminf(lrelu(ss.w + ds.w), 80.f));
    pT4[i] = o;
}

// ---------------- single-pass aggregation, layers 1&2 (fp8 h, pk_fma) --------
__global__ void k_aggregate(const unsigned char* __restrict__ h8, const int* __restrict__ rowptr,
                            const unsigned* __restrict__ colp, const float* __restrict__ pT4,
                            const float* __restrict__ s_src, const float* __restrict__ s_dst,
                            const float* __restrict__ bias,
                            unsigned short* __restrict__ out, int n, int e) {
    int wave = (blockIdx.x * blockDim.x + threadIdx.x) >> 6;
    int lane = threadIdx.x & 63;
    if (wave >= n) return;
    int half = lane >> 5, l5 = lane & 31;
    int head = l5 >> 3;          // 8 lanes x 8 feats = 64 feats per head
    unsigned foff = (unsigned)(l5 * 8);    // byte offset of this lane's 8 fp8 feats
    const float* pp = pT4 + head;          // [edge][head]
    int rs = rowptr[wave], re = rowptr[wave + 1];

    float z = 0.f;
    f32x2 a01 = {0.f, 0.f}, a23 = {0.f, 0.f}, a45 = {0.f, 0.f}, a67 = {0.f, 0.f};
    #define ACC8(P, HV) { \
        f32x2 pbc = {(P), (P)}; \
        f32x2 v0 = __builtin_amdgcn_cvt_pk_f32_fp8((HV).x, false); \
        f32x2 v1 = __builtin_amdgcn_cvt_pk_f32_fp8((HV).x, true);  \
        f32x2 v2 = __builtin_amdgcn_cvt_pk_f32_fp8((HV).y, false); \
        f32x2 v3 = __builtin_amdgcn_cvt_pk_f32_fp8((HV).y, true);  \
        asm("v_pk_fma_f32 %0, %1, %2, %0" : "+v"(a01) : "v"(v0), "v"(pbc)); \
        asm("v_pk_fma_f32 %0, %1, %2, %0" : "+v"(a23) : "v"(v1), "v"(pbc)); \
        asm("v_pk_fma_f32 %0, %1, %2, %0" : "+v"(a45) : "v"(v2), "v"(pbc)); \
        asm("v_pk_fma_f32 %0, %1, %2, %0" : "+v"(a67) : "v"(v3), "v"(pbc)); \
        z += (P); }

    if (half == 0) {
        float pself = __expf(fminf(lrelu(s_src[wave * 4 + head] + s_dst[wave * 4 + head]), 80.f));
        uint2 own = *(const uint2*)(h8 + (((unsigned)wave << 8) + foff));
        ACC8(pself, own);
    }
    int i = rs + half;
    // 8 gathers in flight per half
    for (; i + 14 < re; i += 16) {
        unsigned cc[8]; float pv[8]; uint2 hv[8];
        #pragma unroll
        for (int j = 0; j < 8; j++) { cc[j] = colp[i + 2 * j]; pv[j] = pp[(i + 2 * j) * 4]; }
        #pragma unroll
        for (int j = 0; j < 8; j++)
            hv[j] = *(const uint2*)(h8 + (((cc[j] & 0xffffu) << 8) + foff));
        #pragma unroll
        for (int j = 0; j < 8; j++) { ACC8(pv[j], hv[j]); }
    }
    for (; i + 6 < re; i += 8) {
        unsigned cc[4]; float pv[4]; uint2 hv[4];
        #pragma unroll
        for (int j = 0; j < 4; j++) { cc[j] = colp[i + 2 * j]; pv[j] = pp[(i + 2 * j) * 4]; }
        #pragma unroll
        for (int j = 0; j < 4; j++)
            hv[j] = *(const uint2*)(h8 + (((cc[j] & 0xffffu) << 8) + foff));
        #pragma unroll
        for (int j = 0; j < 4; j++) { ACC8(pv[j], hv[j]); }
    }
    for (; i < re; i += 2) {
        unsigned c0 = colp[i];
        float p0 = pp[i * 4];
        uint2 h0 = *(const uint2*)(h8 + (((c0 & 0xffffu) << 8) + foff));
        ACC8(p0, h0);
    }
    #undef ACC8
    // merge halves
    z += __shfl_xor(z, 32);
    float a[8] = {a01.x, a01.y, a23.x, a23.y, a45.x, a45.y, a67.x, a67.y};
    #pragma unroll
    for (int j = 0; j < 8; j++) a[j] += __shfl_xor(a[j], 32);

    if (half == 0) {
        float inv = 1.f / z;
        int f0 = l5 * 8;
        float4 bv0 = *(const float4*)(bias + f0);
        float4 bv1 = *(const float4*)(bias + f0 + 4);
        float o[8];
        o[0] = a[0] * inv + bv0.x; o[1] = a[1] * inv + bv0.y;
        o[2] = a[2] * inv + bv0.z; o[3] = a[3] * inv + bv0.w;
        o[4] = a[4] * inv + bv1.x; o[5] = a[5] * inv + bv1.y;
        o[6] = a[6] * inv + bv1.z; o[7] = a[7] * inv + bv1.w;
        #pragma unroll
        for (int j = 0; j < 8; j++) o[j] = o[j] > 0.f ? o[j] : __expf(o[j]) - 1.f;
        uint4 ov;
        unsigned* w = (unsigned*)&ov;
        #pragma unroll
        for (int j = 0; j < 4; j++)
            w[j] = (unsigned)f2h(o[2 * j]) | ((unsigned)f2h(o[2 * j + 1]) << 16);
        *(uint4*)(out + (size_t)wave * 256 + f0) = ov;
    }
}

// ---------------- layer 3: GEMM [M,256](f16)@[256,16](f32) + fused scores ----------
__global__ __launch_bounds__(256) void k_gemm3(const unsigned short* __restrict__ A,
                                               const float* __restrict__ B,
                                               const float* __restrict__ a3s,
                                               const float* __restrict__ a3d,
                                               float* __restrict__ C,
                                               float* __restrict__ s_src,
                                               float* __restrict__ s_dst,
                                               int M, int K) {
    __shared__ float Bs[256 * 16];
    for (int i = threadIdx.x; i < K * 16; i += 256) Bs[i] = B[i];
    __syncthreads();
    int tx = threadIdx.x & 15;
    int ty = threadIdx.x >> 4;
    int row = blockIdx.x * 16 + ty;
    if (row >= M) return;
    const unsigned short* Ar = A + (size_t)row * K;
    float acc = 0.f;
    for (int kk = 0; kk < K; kk += 8) {
        uint4 va = *(const uint4*)(Ar + kk);
        const unsigned* u = (const unsigned*)&va;
        #pragma unroll
        for (int j = 0; j < 4; j++) {
            float lo = h2f((unsigned short)(u[j] & 0xffff));
            float hi = h2f((unsigned short)(u[j] >> 16));
            acc += lo * Bs[(kk + 2 * j) * 16 + tx] + hi * Bs[(kk + 2 * j + 1) * 16 + tx];
        }
    }
    C[(size_t)row * 16 + tx] = acc;
    float ps = acc * a3s[tx], pd = acc * a3d[tx];
    #pragma unroll
    for (int off = 1; off < 16; off <<= 1) {
        ps += __shfl_xor(ps, off);
        pd += __shfl_xor(pd, off);
    }
    if (tx == 0) { s_src[row] = ps; s_dst[row] = pd; }
}

// ---------------- layer 3 aggregation + inline scores + bias + log_softmax ----------
__global__ void k_agg3(const float* __restrict__ h3, const int* __restrict__ rowptr,
                       const unsigned* __restrict__ colp,
                       const float* __restrict__ s_src, const float* __restrict__ s_dst,
                       const float* __restrict__ b3,
                       float* __restrict__ outp, int n) {
    int wave = (blockIdx.x * blockDim.x + threadIdx.x) >> 6;
    int lane = threadIdx.x & 63;
    if (wave >= n) return;
    int g = lane >> 4, c = lane & 15;
    int rs = rowptr[wave], re = rowptr[wave + 1];
    float sdn = s_dst[wave];

    float z = 0.f, acc = 0.f;
    if (g == 0) {
        float p = __expf(fminf(lrelu(s_src[wave] + sdn), 80.f));
        z += p;
        acc += p * h3[(size_t)wave * 16 + c];
    }
    int i = rs + g;
    for (; i + 12 < re; i += 16) {
        int s0 = colp[i] & 0xffff,     s1 = colp[i + 4] & 0xffff;
        int s2 = colp[i + 8] & 0xffff, s3 = colp[i + 12] & 0xffff;
        float q0 = s_src[s0], q1 = s_src[s1], q2 = s_src[s2], q3 = s_src[s3];
        float v0 = h3[(size_t)s0 * 16 + c], v1 = h3[(size_t)s1 * 16 + c];
        float v2 = h3[(size_t)s2 * 16 + c], v3 = h3[(size_t)s3 * 16 + c];
        float p0 = __expf(fminf(lrelu(q0 + sdn), 80.f));
        float p1 = __expf(fminf(lrelu(q1 + sdn), 80.f));
        float p2 = __expf(fminf(lrelu(q2 + sdn), 80.f));
        float p3 = __expf(fminf(lrelu(q3 + sdn), 80.f));
        z += (p0 + p1) + (p2 + p3);
        acc += p0 * v0 + p1 * v1 + p2 * v2 + p3 * v3;
    }
    for (; i + 4 < re; i += 8) {
        int s0 = colp[i] & 0xffff, s1 = colp[i + 4] & 0xffff;
        float q0 = s_src[s0], q1 = s_src[s1];
        float v0 = h3[(size_t)s0 * 16 + c], v1 = h3[(size_t)s1 * 16 + c];
        float p0 = __expf(fminf(lrelu(q0 + sdn), 80.f));
        float p1 = __expf(fminf(lrelu(q1 + sdn), 80.f));
        z += p0 + p1;
        acc += p0 * v0 + p1 * v1;
    }
    for (; i < re; i += 4) {
        int s = colp[i] & 0xffff;
        float p = __expf(fminf(lrelu(s_src[s] + sdn), 80.f));
        z += p;
        acc += p * h3[(size_t)s * 16 + c];
    }
    z += __shfl_xor(z, 16);  z += __shfl_xor(z, 32);
    acc += __shfl_xor(acc, 16); acc += __shfl_xor(acc, 32);
    if (lane < 16) {
        float v = acc / z + b3[c];
        float mm = v;
        #pragma unroll
        for (int off = 1; off < 16; off <<= 1) mm = fmaxf(mm, __shfl_xor(mm, off));
        float se = __expf(v - mm);
        #pragma unroll
        for (int off = 1; off < 16; off <<= 1) se += __shfl_xor(se, off);
        outp[(size_t)wave * 16 + c] = v - mm - logf(se);
    }
}

extern "C" void kernel_launch(void* const* d_in, const int* in_sizes, int n_in,
                              void* d_out, int out_size, void* d_ws, size_t ws_size,
                              hipStream_t stream) {
    const float* x      = (const float*)d_in[0];
    const int*   ei     = (const int*)d_in[1];
    const float* W1     = (const float*)d_in[2];
    const float* a1_src = (const float*)d_in[3];
    const float* a1_dst = (const float*)d_in[4];
    const float* b1     = (const float*)d_in[5];
    const float* W2     = (const float*)d_in[6];
    const float* a2_src = (const float*)d_in[7];
    const float* a2_dst = (const float*)d_in[8];
    const float* b2     = (const float*)d_in[9];
    const float* W3     = (const float*)d_in[10];
    const float* a3_src = (const float*)d_in[11];
    const float* a3_dst = (const float*)d_in[12];
    const float* b3     = (const float*)d_in[13];
    float* outp = (float*)d_out;

    const int N = N_NODES, E = N_EDGES;
    const int* src = ei;
    const int* dst = ei + E;

    char* ws = (char*)d_ws;
    size_t off = 0;
    auto alloc = [&](size_t bytes) {
        void* p = ws + off;
        off = (off + bytes + 255) & ~(size_t)255;
        return p;
    };
    int*   rowptr = (int*)alloc((N + 1) * sizeof(int));
    int*   counts = (int*)alloc(N * sizeof(int));
    unsigned* colp = (unsigned*)alloc(E * sizeof(unsigned));
    unsigned short* rank = (unsigned short*)alloc(E * sizeof(short));
    int*   incl   = (int*)alloc(N * sizeof(int));
    int*   bsums  = (int*)alloc(64 * sizeof(int));
    int*   boffs  = (int*)alloc(64 * sizeof(int));
    float* s_src  = (float*)alloc((size_t)N * HEADS * sizeof(float));
    float* s_dst  = (float*)alloc((size_t)N * HEADS * sizeof(float));
    float4* pT4   = (float4*)alloc((size_t)E * sizeof(float4));
    unsigned short* W1t = (unsigned short*)alloc((size_t)256 * F_IN * sizeof(short));
    unsigned short* W2t = (unsigned short*)alloc((size_t)256 * 256 * sizeof(short));
    unsigned char* hA8  = (unsigned char*)alloc((size_t)N * 256);          // fp8 e4m3
    unsigned short* hB  = (unsigned short*)alloc((size_t)N * 256 * sizeof(short));
    float* h3     = (float*)alloc((size_t)N * 16 * sizeof(float));
    (void)ws_size;

    const int aggBlocks = (N + 3) / 4;
    const int gemmBlocks = ((N + 127) / 128) * 2;
    const int edgeBlocks = (E + 255) / 256;
    const int scatBlocks = ((E + 1) / 2 + 255) / 256;

    // ---- prep: W transposes + histogram/ranks (fused) ----
    hipMemsetAsync(counts, 0, N * sizeof(int), stream);
    k_prep<<<NB_WT1 + NB_WT2 + NB_HIST, 256, 0, stream>>>(W1, W1t, W2, W2t, dst, counts, rank);

    // ---- CSR scan ----
    const int nb = (N + 1023) / 1024;
    k_scan1<<<nb, 256, 0, stream>>>(counts, incl, bsums, N);
    k_scan2<<<1, 64, 0, stream>>>(bsums, boffs, nb, rowptr + N);
    k_scan3<<<(N + 255) / 256, 256, 0, stream>>>(incl, counts, boffs, rowptr, N);

    // ---- fused: layer-1 GEMM (f32 x -> fp8 hA) + atomic-free scatter ----
    k_b<<<gemmBlocks + scatBlocks, 256, 0, stream>>>(x, W1t, a1_src, a1_dst, hA8, s_src, s_dst,
                                                     N, F_IN, gemmBlocks,
                                                     src, dst, rowptr, rank, colp, E);
    // ---- layer 1 ----
    k_escore<<<edgeBlocks, 256, 0, stream>>>(colp, s_src, s_dst, pT4, E);
    k_aggregate<<<aggBlocks, 256, 0, stream>>>(hA8, rowptr, colp, (const float*)pT4,
                                               s_src, s_dst, b1, hB, N, E);
    // ---- layer 2 ----
    k_gemm_mfma<<<gemmBlocks, 256, 0, stream>>>(hB, W2t, a2_src, a2_dst, hA8, s_src, s_dst, N, 256);
    k_escore<<<edgeBlocks, 256, 0, stream>>>(colp, s_src, s_dst, pT4, E);
    k_aggregate<<<aggBlocks, 256, 0, stream>>>(hA8, rowptr, colp, (const float*)pT4,
                                               s_src, s_dst, b2, hB, N, E);
    // ---- layer 3 ----
    k_gemm3<<<(N + 15) / 16, 256, 0, stream>>>(hB, W3, a3_src, a3_dst, h3, s_src, s_dst, N, 256);
    k_agg3<<<aggBlocks, 256, 0, stream>>>(h3, rowptr, colp, s_src, s_dst, b3, outp, N);
}

// Round 13
// 231.044 us; speedup vs baseline: 2.7677x; 1.0433x over previous
//
#include <hip/hip_runtime.h>
#include <hip/hip_bf16.h>
#include <math.h>

#define N_NODES 50000
#define N_EDGES 800000
#define F_IN    128
#define HID     64
#define HEADS   4
#define NCLS    16
#define NEG_SLOPE 0.2f

typedef __attribute__((ext_vector_type(8))) _Float16 half8v;
typedef __attribute__((ext_vector_type(4))) float f32x4;
typedef __attribute__((ext_vector_type(2))) float f32x2;

static __device__ __forceinline__ float lrelu(float x) {
    return x >= 0.f ? x : NEG_SLOPE * x;
}
static __device__ __forceinline__ unsigned short f2h(float f) {
    _Float16 h = (_Float16)f;
    return __builtin_bit_cast(unsigned short, h);
}
static __device__ __forceinline__ float h2f(unsigned short u) {
    return (float)__builtin_bit_cast(_Float16, u);
}

// ---------------- zero counts (replaces 41us fillBufferAligned) ----------------
__global__ void k_zero(int4* __restrict__ p, int n4) {
    int i = blockIdx.x * blockDim.x + threadIdx.x;
    if (i < n4) p[i] = int4{0, 0, 0, 0};
}

// ---------------- fused prep: W1t, W2t, edge histogram + ranks ----------------
#define NB_WT1  128           // 128*256 / 256
#define NB_WT2  256           // 256*256 / 256
#define NB_HIST 3125          // E / 256
__global__ void k_prep(const float* __restrict__ W1, unsigned short* __restrict__ W1t,
                       const float* __restrict__ W2, unsigned short* __restrict__ W2t,
                       const int* __restrict__ dst, int* __restrict__ counts,
                       unsigned short* __restrict__ rank) {
    int bid = blockIdx.x, tid = threadIdx.x;
    if (bid < NB_WT1) {
        int i = bid * 256 + tid;
        int k = i >> 8, c = i & 255;
        W1t[c * F_IN + k] = f2h(W1[i]);
    } else if (bid < NB_WT1 + NB_WT2) {
        int i = (bid - NB_WT1) * 256 + tid;
        int k = i >> 8, c = i & 255;
        W2t[c * 256 + k] = f2h(W2[i]);
    } else {
        int i = (bid - NB_WT1 - NB_WT2) * 256 + tid;
        if (i < N_EDGES) rank[i] = (unsigned short)atomicAdd(&counts[dst[i]], 1);
    }
}

// ---------------- CSR scan ----------------
__global__ __launch_bounds__(256) void k_scan1(const int* __restrict__ counts, int* __restrict__ incl,
                                               int* __restrict__ bsums, int n) {
    __shared__ int wsum[4];
    int blk = blockIdx.x, tid = threadIdx.x;
    int lane = tid & 63, w = tid >> 6;
    int i0 = blk * 1024 + tid * 4;
    int v[4];
    #pragma unroll
    for (int j = 0; j < 4; j++) v[j] = (i0 + j < n) ? counts[i0 + j] : 0;
    int t = v[0] + v[1] + v[2] + v[3];
    int x = t;
    #pragma unroll
    for (int d = 1; d < 64; d <<= 1) { int y = __shfl_up(x, d); if (lane >= d) x += y; }
    if (lane == 63) wsum[w] = x;
    __syncthreads();
    int woff = 0;
    #pragma unroll
    for (int ww = 0; ww < 4; ww++) woff += (ww < w) ? wsum[ww] : 0;
    int p = woff + x - t;
    #pragma unroll
    for (int j = 0; j < 4; j++) { p += v[j]; if (i0 + j < n) incl[i0 + j] = p; }
    if (tid == 255) bsums[blk] = woff + x;
}

__global__ void k_scan2(const int* __restrict__ bsums, int* __restrict__ boffs, int nb, int* rowptr_end) {
    int lane = threadIdx.x;
    int v = (lane < nb) ? bsums[lane] : 0;
    int x = v;
    #pragma unroll
    for (int d = 1; d < 64; d <<= 1) { int y = __shfl_up(x, d); if (lane >= d) x += y; }
    if (lane < nb) boffs[lane] = x - v;
    if (lane == 63) *rowptr_end = x;
}

__global__ void k_scan3(const int* __restrict__ incl, const int* __restrict__ counts,
                        const int* __restrict__ boffs, int* __restrict__ rowptr, int n) {
    int i = blockIdx.x * blockDim.x + threadIdx.x;
    if (i < n) rowptr[i] = boffs[i >> 10] + incl[i] - counts[i];
}

// ---------------- GEMM body (f16 MFMA, N=256) + fused per-node scores ----------
// CONVA: A is f32, converted to f16 during LDS staging. C output is fp8 e4m3.
static __device__ __forceinline__ int swz(int r, int lc) {
    return r * 4 + (lc ^ (r & 3) ^ ((r >> 2) & 1));
}

template<int CONVA>
static __device__ __forceinline__ void gemm_body(
        int bid, const void* __restrict__ Av, const unsigned short* __restrict__ Bt,
        const float* __restrict__ asrc, const float* __restrict__ adst,
        unsigned char* __restrict__ C8, float* __restrict__ s_src, float* __restrict__ s_dst,
        int M, int K, unsigned short* Asm, unsigned short* Bsm) {
    int tid = threadIdx.x;
    int lane = tid & 63, wid = tid >> 6;
    int bx = bid & 1, by = bid >> 1;
    int row0 = by * 128, col0 = bx * 128;
    int wr = wid >> 1, wc = wid & 1;
    f32x4 acc[4][4] = {};

    for (int k0 = 0; k0 < K; k0 += 32) {
        __syncthreads();
        #pragma unroll
        for (int s = 0; s < 2; s++) {
            int c = tid + s * 256;
            int row = c >> 2, lc = c & 3;
            int gr = row0 + row; if (gr >= M) gr = 0;
            uint4 va;
            if (CONVA) {
                const float* Af = (const float*)Av + (size_t)gr * K + k0 + lc * 8;
                float4 fa = *(const float4*)Af;
                float4 fb = *(const float4*)(Af + 4);
                va.x = (unsigned)f2h(fa.x) | ((unsigned)f2h(fa.y) << 16);
                va.y = (unsigned)f2h(fa.z) | ((unsigned)f2h(fa.w) << 16);
                va.z = (unsigned)f2h(fb.x) | ((unsigned)f2h(fb.y) << 16);
                va.w = (unsigned)f2h(fb.z) | ((unsigned)f2h(fb.w) << 16);
            } else {
                va = *(const uint4*)((const unsigned short*)Av + (size_t)gr * K + k0 + lc * 8);
            }
            *(uint4*)(&Asm[swz(row, lc) * 8]) = va;
            uint4 vb = *(const uint4*)(Bt + (size_t)(col0 + row) * K + k0 + lc * 8);
            *(uint4*)(&Bsm[swz(row, lc) * 8]) = vb;
        }
        __syncthreads();
        half8v af[4], bg[4];
        int lq = lane >> 4;
        #pragma unroll
        for (int m = 0; m < 4; m++) {
            int r = wr * 64 + m * 16 + (lane & 15);
            af[m] = *(const half8v*)(&Asm[swz(r, lq) * 8]);
        }
        #pragma unroll
        for (int n = 0; n < 4; n++) {
            int r = wc * 64 + n * 16 + (lane & 15);
            bg[n] = *(const half8v*)(&Bsm[swz(r, lq) * 8]);
        }
        #pragma unroll
        for (int m = 0; m < 4; m++)
            #pragma unroll
            for (int n = 0; n < 4; n++)
                acc[m][n] = __builtin_amdgcn_mfma_f32_16x16x32_f16(af[m], bg[n], acc[m][n], 0, 0, 0);
    }

    // C write: fp8 e4m3, row stride 256 B
    #pragma unroll
    for (int m = 0; m < 4; m++) {
        #pragma unroll
        for (int r = 0; r < 4; r++) {
            int row = row0 + wr * 64 + m * 16 + (lane >> 4) * 4 + r;
            if (row < M) {
                int q01 = __builtin_amdgcn_cvt_pk_fp8_f32(acc[m][0][r], acc[m][1][r], 0, false);
                int q23 = __builtin_amdgcn_cvt_pk_fp8_f32(acc[m][2][r], acc[m][3][r], 0, false);
                size_t base = (size_t)row * 256 + col0 + wc * 64 + (lane & 15);
                C8[base]      = (unsigned char)(q01 & 0xff);
                C8[base + 16] = (unsigned char)((q01 >> 8) & 0xff);
                C8[base + 32] = (unsigned char)(q23 & 0xff);
                C8[base + 48] = (unsigned char)((q23 >> 8) & 0xff);
            }
        }
    }

    // fused attention scores: this wave's 64 cols = head (bx*2+wc)
    int c16 = lane & 15, lq = lane >> 4;
    int head = bx * 2 + wc;
    float avs[4], avd[4];
    #pragma unroll
    for (int nn = 0; nn < 4; nn++) {
        avs[nn] = asrc[head * 64 + nn * 16 + c16];
        avd[nn] = adst[head * 64 + nn * 16 + c16];
    }
    #pragma unroll
    for (int mm = 0; mm < 4; mm++) {
        #pragma unroll
        for (int r = 0; r < 4; r++) {
            float ps = 0.f, pd = 0.f;
            #pragma unroll
            for (int nn = 0; nn < 4; nn++) {
                ps += acc[mm][nn][r] * avs[nn];
                pd += acc[mm][nn][r] * avd[nn];
            }
            #pragma unroll
            for (int off = 1; off < 16; off <<= 1) {
                ps += __shfl_xor(ps, off);
                pd += __shfl_xor(pd, off);
            }
            if (c16 == 0) {
                int grow = row0 + wr * 64 + mm * 16 + lq * 4 + r;
                if (grow < M) {
                    s_src[grow * 4 + head] = ps;
                    s_dst[grow * 4 + head] = pd;
                }
            }
        }
    }
}

// standalone GEMM (layer 2, f16 A, fp8 C)
__global__ __launch_bounds__(256) void k_gemm_mfma(const unsigned short* __restrict__ A,
                                                   const unsigned short* __restrict__ Bt,
                                                   const float* __restrict__ asrc,
                                                   const float* __restrict__ adst,
                                                   unsigned char* __restrict__ C8,
                                                   float* __restrict__ s_src,
                                                   float* __restrict__ s_dst,
                                                   int M, int K) {
    __shared__ unsigned short Asm[128 * 32];
    __shared__ unsigned short Bsm[128 * 32];
    gemm_body<0>(blockIdx.x, A, Bt, asrc, adst, C8, s_src, s_dst, M, K, Asm, Bsm);
}

// fused: layer-1 GEMM (f32 A, fp8 C) + atomic-free CSR scatter
__global__ __launch_bounds__(256) void k_b(const float* __restrict__ A,
                                           const unsigned short* __restrict__ Bt,
                                           const float* __restrict__ asrc,
                                           const float* __restrict__ adst,
                                           unsigned char* __restrict__ C8,
                                           float* __restrict__ s_src,
                                           float* __restrict__ s_dst,
                                           int M, int K, int gemmBlocks,
                                           const int* __restrict__ src, const int* __restrict__ dst,
                                           const int* __restrict__ rowptr,
                                           const unsigned short* __restrict__ rank,
                                           unsigned* __restrict__ colp, int e) {
    __shared__ unsigned short Asm[128 * 32];
    __shared__ unsigned short Bsm[128 * 32];
    int bid = blockIdx.x;
    if (bid < gemmBlocks) {
        gemm_body<1>(bid, A, Bt, asrc, adst, C8, s_src, s_dst, M, K, Asm, Bsm);
    } else {
        int half = (e + 1) >> 1;
        int i = (bid - gemmBlocks) * 256 + (int)threadIdx.x;
        if (i < half) {
            int d = dst[i];
            colp[rowptr[d] + rank[i]] = (unsigned)src[i] | ((unsigned)d << 16);
        }
        int j = i + half;
        if (j < e) {
            int d = dst[j];
            colp[rowptr[d] + rank[j]] = (unsigned)src[j] | ((unsigned)d << 16);
        }
    }
}

// ---------------- single-pass aggregation, layers 1&2 (fp8 h, inline scores) --------
__global__ void k_aggregate(const unsigned char* __restrict__ h8, const int* __restrict__ rowptr,
                            const unsigned* __restrict__ colp,
                            const float* __restrict__ s_src, const float* __restrict__ s_dst,
                            const float* __restrict__ bias,
                            unsigned short* __restrict__ out, int n, int e) {
    int wave = (blockIdx.x * blockDim.x + threadIdx.x) >> 6;
    int lane = threadIdx.x & 63;
    if (wave >= n) return;
    int half = lane >> 5, l5 = lane & 31;
    int head = l5 >> 3;          // 8 lanes x 8 feats = 64 feats per head
    unsigned foff = (unsigned)(l5 * 8);    // byte offset of this lane's 8 fp8 feats
    int rs = rowptr[wave], re = rowptr[wave + 1];
    float sd = s_dst[wave * 4 + head];

    float z = 0.f;
    f32x2 a01 = {0.f, 0.f}, a23 = {0.f, 0.f}, a45 = {0.f, 0.f}, a67 = {0.f, 0.f};
    #define PEDGE(SV) __expf(fminf(lrelu((SV) + sd), 80.f))
    #define ACC8(P, HV) { \
        f32x2 pbc = {(P), (P)}; \
        f32x2 v0 = __builtin_amdgcn_cvt_pk_f32_fp8((HV).x, false); \
        f32x2 v1 = __builtin_amdgcn_cvt_pk_f32_fp8((HV).x, true);  \
        f32x2 v2 = __builtin_amdgcn_cvt_pk_f32_fp8((HV).y, false); \
        f32x2 v3 = __builtin_amdgcn_cvt_pk_f32_fp8((HV).y, true);  \
        asm("v_pk_fma_f32 %0, %1, %2, %0" : "+v"(a01) : "v"(v0), "v"(pbc)); \
        asm("v_pk_fma_f32 %0, %1, %2, %0" : "+v"(a23) : "v"(v1), "v"(pbc)); \
        asm("v_pk_fma_f32 %0, %1, %2, %0" : "+v"(a45) : "v"(v2), "v"(pbc)); \
        asm("v_pk_fma_f32 %0, %1, %2, %0" : "+v"(a67) : "v"(v3), "v"(pbc)); \
        z += (P); }

    if (half == 0) {
        float pself = PEDGE(s_src[wave * 4 + head]);
        uint2 own = *(const uint2*)(h8 + (((unsigned)wave << 8) + foff));
        ACC8(pself, own);
    }
    int i = rs + half;
    // 8 gathers in flight per half; s_src is L2-resident (800 KB)
    for (; i + 14 < re; i += 16) {
        unsigned cc[8]; float sv[8]; uint2 hv[8];
        #pragma unroll
        for (int j = 0; j < 8; j++) cc[j] = colp[i + 2 * j];
        #pragma unroll
        for (int j = 0; j < 8; j++) sv[j] = s_src[(cc[j] & 0xffffu) * 4 + head];
        #pragma unroll
        for (int j = 0; j < 8; j++)
            hv[j] = *(const uint2*)(h8 + (((cc[j] & 0xffffu) << 8) + foff));
        #pragma unroll
        for (int j = 0; j < 8; j++) {
            float p = PEDGE(sv[j]);
            ACC8(p, hv[j]);
        }
    }
    for (; i + 6 < re; i += 8) {
        unsigned cc[4]; float sv[4]; uint2 hv[4];
        #pragma unroll
        for (int j = 0; j < 4; j++) cc[j] = colp[i + 2 * j];
        #pragma unroll
        for (int j = 0; j < 4; j++) sv[j] = s_src[(cc[j] & 0xffffu) * 4 + head];
        #pragma unroll
        for (int j = 0; j < 4; j++)
            hv[j] = *(const uint2*)(h8 + (((cc[j] & 0xffffu) << 8) + foff));
        #pragma unroll
        for (int j = 0; j < 4; j++) {
            float p = PEDGE(sv[j]);
            ACC8(p, hv[j]);
        }
    }
    for (; i < re; i += 2) {
        unsigned c0 = colp[i];
        float s0 = s_src[(c0 & 0xffffu) * 4 + head];
        uint2 h0 = *(const uint2*)(h8 + (((c0 & 0xffffu) << 8) + foff));
        float p0 = PEDGE(s0);
        ACC8(p0, h0);
    }
    #undef ACC8
    #undef PEDGE
    // merge halves
    z += __shfl_xor(z, 32);
    float a[8] = {a01.x, a01.y, a23.x, a23.y, a45.x, a45.y, a67.x, a67.y};
    #pragma unroll
    for (int j = 0; j < 8; j++) a[j] += __shfl_xor(a[j], 32);

    if (half == 0) {
        float inv = 1.f / z;
        int f0 = l5 * 8;
        float4 bv0 = *(const float4*)(bias + f0);
        float4 bv1 = *(const float4*)(bias + f0 + 4);
        float o[8];
        o[0] = a[0] * inv + bv0.x; o[1] = a[1] * inv + bv0.y;
        o[2] = a[2] * inv + bv0.z; o[3] = a[3] * inv + bv0.w;
        o[4] = a[4] * inv + bv1.x; o[5] = a[5] * inv + bv1.y;
        o[6] = a[6] * inv + bv1.z; o[7] = a[7] * inv + bv1.w;
        #pragma unroll
        for (int j = 0; j < 8; j++) o[j] = o[j] > 0.f ? o[j] : __expf(o[j]) - 1.f;
        uint4 ov;
        unsigned* w = (unsigned*)&ov;
        #pragma unroll
        for (int j = 0; j < 4; j++)
            w[j] = (unsigned)f2h(o[2 * j]) | ((unsigned)f2h(o[2 * j + 1]) << 16);
        *(uint4*)(out + (size_t)wave * 256 + f0) = ov;
    }
}

// ---------------- layer 3: GEMM [M,256](f16)@[256,16](f32) + fused scores ----------
__global__ __launch_bounds__(256) void k_gemm3(const unsigned short* __restrict__ A,
                                               const float* __restrict__ B,
                                               const float* __restrict__ a3s,
                                               const float* __restrict__ a3d,
                                               float* __restrict__ C,
                                               float* __restrict__ s_src,
                                               float* __restrict__ s_dst,
                                               int M, int K) {
    __shared__ float Bs[256 * 16];
    for (int i = threadIdx.x; i < K * 16; i += 256) Bs[i] = B[i];
    __syncthreads();
    int tx = threadIdx.x & 15;
    int ty = threadIdx.x >> 4;
    int row = blockIdx.x * 16 + ty;
    if (row >= M) return;
    const unsigned short* Ar = A + (size_t)row * K;
    float acc = 0.f;
    for (int kk = 0; kk < K; kk += 8) {
        uint4 va = *(const uint4*)(Ar + kk);
        const unsigned* u = (const unsigned*)&va;
        #pragma unroll
        for (int j = 0; j < 4; j++) {
            float lo = h2f((unsigned short)(u[j] & 0xffff));
            float hi = h2f((unsigned short)(u[j] >> 16));
            acc += lo * Bs[(kk + 2 * j) * 16 + tx] + hi * Bs[(kk + 2 * j + 1) * 16 + tx];
        }
    }
    C[(size_t)row * 16 + tx] = acc;
    float ps = acc * a3s[tx], pd = acc * a3d[tx];
    #pragma unroll
    for (int off = 1; off < 16; off <<= 1) {
        ps += __shfl_xor(ps, off);
        pd += __shfl_xor(pd, off);
    }
    if (tx == 0) { s_src[row] = ps; s_dst[row] = pd; }
}

// ---------------- layer 3 aggregation + inline scores + bias + log_softmax ----------
__global__ void k_agg3(const float* __restrict__ h3, const int* __restrict__ rowptr,
                       const unsigned* __restrict__ colp,
                       const float* __restrict__ s_src, const float* __restrict__ s_dst,
                       const float* __restrict__ b3,
                       float* __restrict__ outp, int n) {
    int wave = (blockIdx.x * blockDim.x + threadIdx.x) >> 6;
    int lane = threadIdx.x & 63;
    if (wave >= n) return;
    int g = lane >> 4, c = lane & 15;
    int rs = rowptr[wave], re = rowptr[wave + 1];
    float sdn = s_dst[wave];

    float z = 0.f, acc = 0.f;
    if (g == 0) {
        float p = __expf(fminf(lrelu(s_src[wave] + sdn), 80.f));
        z += p;
        acc += p * h3[(size_t)wave * 16 + c];
    }
    int i = rs + g;
    for (; i + 12 < re; i += 16) {
        int s0 = colp[i] & 0xffff,     s1 = colp[i + 4] & 0xffff;
        int s2 = colp[i + 8] & 0xffff, s3 = colp[i + 12] & 0xffff;
        float q0 = s_src[s0], q1 = s_src[s1], q2 = s_src[s2], q3 = s_src[s3];
        float v0 = h3[(size_t)s0 * 16 + c], v1 = h3[(size_t)s1 * 16 + c];
        float v2 = h3[(size_t)s2 * 16 + c], v3 = h3[(size_t)s3 * 16 + c];
        float p0 = __expf(fminf(lrelu(q0 + sdn), 80.f));
        float p1 = __expf(fminf(lrelu(q1 + sdn), 80.f));
        float p2 = __expf(fminf(lrelu(q2 + sdn), 80.f));
        float p3 = __expf(fminf(lrelu(q3 + sdn), 80.f));
        z += (p0 + p1) + (p2 + p3);
        acc += p0 * v0 + p1 * v1 + p2 * v2 + p3 * v3;
    }
    for (; i + 4 < re; i += 8) {
        int s0 = colp[i] & 0xffff, s1 = colp[i + 4] & 0xffff;
        float q0 = s_src[s0], q1 = s_src[s1];
        float v0 = h3[(size_t)s0 * 16 + c], v1 = h3[(size_t)s1 * 16 + c];
        float p0 = __expf(fminf(lrelu(q0 + sdn), 80.f));
        float p1 = __expf(fminf(lrelu(q1 + sdn), 80.f));
        z += p0 + p1;
        acc += p0 * v0 + p1 * v1;
    }
    for (; i < re; i += 4) {
        int s = colp[i] & 0xffff;
        float p = __expf(fminf(lrelu(s_src[s] + sdn), 80.f));
        z += p;
        acc += p * h3[(size_t)s * 16 + c];
    }
    z += __shfl_xor(z, 16);  z += __shfl_xor(z, 32);
    acc += __shfl_xor(acc, 16); acc += __shfl_xor(acc, 32);
    if (lane < 16) {
        float v = acc / z + b3[c];
        float mm = v;
        #pragma unroll
        for (int off = 1; off < 16; off <<= 1) mm = fmaxf(mm, __shfl_xor(mm, off));
        float se = __expf(v - mm);
        #pragma unroll
        for (int off = 1; off < 16; off <<= 1) se += __shfl_xor(se, off);
        outp[(size_t)wave * 16 + c] = v - mm - logf(se);
    }
}

extern "C" void kernel_launch(void* const* d_in, const int* in_sizes, int n_in,
                              void* d_out, int out_size, void* d_ws, size_t ws_size,
                              hipStream_t stream) {
    const float* x      = (const float*)d_in[0];
    const int*   ei     = (const int*)d_in[1];
    const float* W1     = (const float*)d_in[2];
    const float* a1_src = (const float*)d_in[3];
    const float* a1_dst = (const float*)d_in[4];
    const float* b1     = (const float*)d_in[5];
    const float* W2     = (const float*)d_in[6];
    const float* a2_src = (const float*)d_in[7];
    const float* a2_dst = (const float*)d_in[8];
    const float* b2     = (const float*)d_in[9];
    const float* W3     = (const float*)d_in[10];
    const float* a3_src = (const float*)d_in[11];
    const float* a3_dst = (const float*)d_in[12];
    const float* b3     = (const float*)d_in[13];
    float* outp = (float*)d_out;

    const int N = N_NODES, E = N_EDGES;
    const int* src = ei;
    const int* dst = ei + E;

    char* ws = (char*)d_ws;
    size_t off = 0;
    auto alloc = [&](size_t bytes) {
        void* p = ws + off;
        off = (off + bytes + 255) & ~(size_t)255;
        return p;
    };
    int*   rowptr = (int*)alloc((N + 1) * sizeof(int));
    int*   counts = (int*)alloc(N * sizeof(int));
    unsigned* colp = (unsigned*)alloc(E * sizeof(unsigned));
    unsigned short* rank = (unsigned short*)alloc(E * sizeof(short));
    int*   incl   = (int*)alloc(N * sizeof(int));
    int*   bsums  = (int*)alloc(64 * sizeof(int));
    int*   boffs  = (int*)alloc(64 * sizeof(int));
    float* s_src  = (float*)alloc((size_t)N * HEADS * sizeof(float));
    float* s_dst  = (float*)alloc((size_t)N * HEADS * sizeof(float));
    unsigned short* W1t = (unsigned short*)alloc((size_t)256 * F_IN * sizeof(short));
    unsigned short* W2t = (unsigned short*)alloc((size_t)256 * 256 * sizeof(short));
    unsigned char* hA8  = (unsigned char*)alloc((size_t)N * 256);          // fp8 e4m3
    unsigned short* hB  = (unsigned short*)alloc((size_t)N * 256 * sizeof(short));
    float* h3     = (float*)alloc((size_t)N * 16 * sizeof(float));
    (void)ws_size;

    const int aggBlocks = (N + 3) / 4;
    const int gemmBlocks = ((N + 127) / 128) * 2;
    const int scatBlocks = ((E + 1) / 2 + 255) / 256;

    // ---- prep: zero counts (custom, not 41us fillBuffer), W transposes + hist/ranks ----
    k_zero<<<(N / 4 + 255) / 256, 256, 0, stream>>>((int4*)counts, N / 4);
    k_prep<<<NB_WT1 + NB_WT2 + NB_HIST, 256, 0, stream>>>(W1, W1t, W2, W2t, dst, counts, rank);

    // ---- CSR scan ----
    const int nb = (N + 1023) / 1024;
    k_scan1<<<nb, 256, 0, stream>>>(counts, incl, bsums, N);
    k_scan2<<<1, 64, 0, stream>>>(bsums, boffs, nb, rowptr + N);
    k_scan3<<<(N + 255) / 256, 256, 0, stream>>>(incl, counts, boffs, rowptr, N);

    // ---- fused: layer-1 GEMM (f32 x -> fp8 hA) + atomic-free scatter ----
    k_b<<<gemmBlocks + scatBlocks, 256, 0, stream>>>(x, W1t, a1_src, a1_dst, hA8, s_src, s_dst,
                                                     N, F_IN, gemmBlocks,
                                                     src, dst, rowptr, rank, colp, E);
    // ---- layer 1 (scores inline) ----
    k_aggregate<<<aggBlocks, 256, 0, stream>>>(hA8, rowptr, colp, s_src, s_dst, b1, hB, N, E);
    // ---- layer 2 ----
    k_gemm_mfma<<<gemmBlocks, 256, 0, stream>>>(hB, W2t, a2_src, a2_dst, hA8, s_src, s_dst, N, 256);
    k_aggregate<<<aggBlocks, 256, 0, stream>>>(hA8, rowptr, colp, s_src, s_dst, b2, hB, N, E);
    // ---- layer 3 ----
    k_gemm3<<<(N + 15) / 16, 256, 0, stream>>>(hB, W3, a3_src, a3_dst, h3, s_src, s_dst, N, 256);
    k_agg3<<<aggBlocks, 256, 0, stream>>>(h3, rowptr, colp, s_src, s_dst, b3, outp, N);
}

// Round 14
// 229.821 us; speedup vs baseline: 2.7825x; 1.0053x over previous
//
#include <hip/hip_runtime.h>
#include <hip/hip_bf16.h>
#include <math.h>

#define N_NODES 50000
#define N_EDGES 800000
#define F_IN    128
#define HID     64
#define HEADS   4
#define NCLS    16
#define NEG_SLOPE 0.2f

typedef __attribute__((ext_vector_type(8))) _Float16 half8v;
typedef __attribute__((ext_vector_type(4))) float f32x4;
typedef __attribute__((ext_vector_type(2))) float f32x2;

static __device__ __forceinline__ float lrelu(float x) {
    return x >= 0.f ? x : NEG_SLOPE * x;
}
static __device__ __forceinline__ unsigned short f2h(float f) {
    _Float16 h = (_Float16)f;
    return __builtin_bit_cast(unsigned short, h);
}
static __device__ __forceinline__ float h2f(unsigned short u) {
    return (float)__builtin_bit_cast(_Float16, u);
}

// ---------------- zero counts ----------------
__global__ void k_zero(int4* __restrict__ p, int n4) {
    int i = blockIdx.x * blockDim.x + threadIdx.x;
    if (i < n4) p[i] = int4{0, 0, 0, 0};
}

// ---------------- fused prep: W1t, W2t, edge histogram + ranks ----------------
#define NB_WT1  128           // 128*256 / 256
#define NB_WT2  256           // 256*256 / 256
#define NB_HIST 3125          // E / 256
__global__ void k_prep(const float* __restrict__ W1, unsigned short* __restrict__ W1t,
                       const float* __restrict__ W2, unsigned short* __restrict__ W2t,
                       const int* __restrict__ dst, int* __restrict__ counts,
                       unsigned short* __restrict__ rank) {
    int bid = blockIdx.x, tid = threadIdx.x;
    if (bid < NB_WT1) {
        int i = bid * 256 + tid;
        int k = i >> 8, c = i & 255;
        W1t[c * F_IN + k] = f2h(W1[i]);
    } else if (bid < NB_WT1 + NB_WT2) {
        int i = (bid - NB_WT1) * 256 + tid;
        int k = i >> 8, c = i & 255;
        W2t[c * 256 + k] = f2h(W2[i]);
    } else {
        int i = (bid - NB_WT1 - NB_WT2) * 256 + tid;
        if (i < N_EDGES) rank[i] = (unsigned short)atomicAdd(&counts[dst[i]], 1);
    }
}

// ---------------- CSR scan ----------------
__global__ __launch_bounds__(256) void k_scan1(const int* __restrict__ counts, int* __restrict__ incl,
                                               int* __restrict__ bsums, int n) {
    __shared__ int wsum[4];
    int blk = blockIdx.x, tid = threadIdx.x;
    int lane = tid & 63, w = tid >> 6;
    int i0 = blk * 1024 + tid * 4;
    int v[4];
    #pragma unroll
    for (int j = 0; j < 4; j++) v[j] = (i0 + j < n) ? counts[i0 + j] : 0;
    int t = v[0] + v[1] + v[2] + v[3];
    int x = t;
    #pragma unroll
    for (int d = 1; d < 64; d <<= 1) { int y = __shfl_up(x, d); if (lane >= d) x += y; }
    if (lane == 63) wsum[w] = x;
    __syncthreads();
    int woff = 0;
    #pragma unroll
    for (int ww = 0; ww < 4; ww++) woff += (ww < w) ? wsum[ww] : 0;
    int p = woff + x - t;
    #pragma unroll
    for (int j = 0; j < 4; j++) { p += v[j]; if (i0 + j < n) incl[i0 + j] = p; }
    if (tid == 255) bsums[blk] = woff + x;
}

__global__ void k_scan2(const int* __restrict__ bsums, int* __restrict__ boffs, int nb, int* rowptr_end) {
    int lane = threadIdx.x;
    int v = (lane < nb) ? bsums[lane] : 0;
    int x = v;
    #pragma unroll
    for (int d = 1; d < 64; d <<= 1) { int y = __shfl_up(x, d); if (lane >= d) x += y; }
    if (lane < nb) boffs[lane] = x - v;
    if (lane == 63) *rowptr_end = x;
}

__global__ void k_scan3(const int* __restrict__ incl, const int* __restrict__ counts,
                        const int* __restrict__ boffs, int* __restrict__ rowptr, int n) {
    int i = blockIdx.x * blockDim.x + threadIdx.x;
    if (i < n) rowptr[i] = boffs[i >> 10] + incl[i] - counts[i];
}

// ---------------- GEMM body (f16 MFMA, N=256) + fused per-node scores ----------
// CONVA: A is f32, converted to f16 during LDS staging. C output is fp8 e4m3.
static __device__ __forceinline__ int swz(int r, int lc) {
    return r * 4 + (lc ^ (r & 3) ^ ((r >> 2) & 1));
}

template<int CONVA>
static __device__ __forceinline__ void gemm_body(
        int bid, const void* __restrict__ Av, const unsigned short* __restrict__ Bt,
        const float* __restrict__ asrc, const float* __restrict__ adst,
        unsigned char* __restrict__ C8, float* __restrict__ s_src, float* __restrict__ s_dst,
        int M, int K, unsigned short* Asm, unsigned short* Bsm) {
    int tid = threadIdx.x;
    int lane = tid & 63, wid = tid >> 6;
    int bx = bid & 1, by = bid >> 1;
    int row0 = by * 128, col0 = bx * 128;
    int wr = wid >> 1, wc = wid & 1;
    f32x4 acc[4][4] = {};

    for (int k0 = 0; k0 < K; k0 += 32) {
        __syncthreads();
        #pragma unroll
        for (int s = 0; s < 2; s++) {
            int c = tid + s * 256;
            int row = c >> 2, lc = c & 3;
            int gr = row0 + row; if (gr >= M) gr = 0;
            uint4 va;
            if (CONVA) {
                const float* Af = (const float*)Av + (size_t)gr * K + k0 + lc * 8;
                float4 fa = *(const float4*)Af;
                float4 fb = *(const float4*)(Af + 4);
                va.x = (unsigned)f2h(fa.x) | ((unsigned)f2h(fa.y) << 16);
                va.y = (unsigned)f2h(fa.z) | ((unsigned)f2h(fa.w) << 16);
                va.z = (unsigned)f2h(fb.x) | ((unsigned)f2h(fb.y) << 16);
                va.w = (unsigned)f2h(fb.z) | ((unsigned)f2h(fb.w) << 16);
            } else {
                va = *(const uint4*)((const unsigned short*)Av + (size_t)gr * K + k0 + lc * 8);
            }
            *(uint4*)(&Asm[swz(row, lc) * 8]) = va;
            uint4 vb = *(const uint4*)(Bt + (size_t)(col0 + row) * K + k0 + lc * 8);
            *(uint4*)(&Bsm[swz(row, lc) * 8]) = vb;
        }
        __syncthreads();
        half8v af[4], bg[4];
        int lq = lane >> 4;
        #pragma unroll
        for (int m = 0; m < 4; m++) {
            int r = wr * 64 + m * 16 + (lane & 15);
            af[m] = *(const half8v*)(&Asm[swz(r, lq) * 8]);
        }
        #pragma unroll
        for (int n = 0; n < 4; n++) {
            int r = wc * 64 + n * 16 + (lane & 15);
            bg[n] = *(const half8v*)(&Bsm[swz(r, lq) * 8]);
        }
        #pragma unroll
        for (int m = 0; m < 4; m++)
            #pragma unroll
            for (int n = 0; n < 4; n++)
                acc[m][n] = __builtin_amdgcn_mfma_f32_16x16x32_f16(af[m], bg[n], acc[m][n], 0, 0, 0);
    }

    // C write: fp8 e4m3, row stride 256 B
    #pragma unroll
    for (int m = 0; m < 4; m++) {
        #pragma unroll
        for (int r = 0; r < 4; r++) {
            int row = row0 + wr * 64 + m * 16 + (lane >> 4) * 4 + r;
            if (row < M) {
                int q01 = __builtin_amdgcn_cvt_pk_fp8_f32(acc[m][0][r], acc[m][1][r], 0, false);
                int q23 = __builtin_amdgcn_cvt_pk_fp8_f32(acc[m][2][r], acc[m][3][r], 0, false);
                size_t base = (size_t)row * 256 + col0 + wc * 64 + (lane & 15);
                C8[base]      = (unsigned char)(q01 & 0xff);
                C8[base + 16] = (unsigned char)((q01 >> 8) & 0xff);
                C8[base + 32] = (unsigned char)(q23 & 0xff);
                C8[base + 48] = (unsigned char)((q23 >> 8) & 0xff);
            }
        }
    }

    // fused attention scores: this wave's 64 cols = head (bx*2+wc)
    int c16 = lane & 15, lq = lane >> 4;
    int head = bx * 2 + wc;
    float avs[4], avd[4];
    #pragma unroll
    for (int nn = 0; nn < 4; nn++) {
        avs[nn] = asrc[head * 64 + nn * 16 + c16];
        avd[nn] = adst[head * 64 + nn * 16 + c16];
    }
    #pragma unroll
    for (int mm = 0; mm < 4; mm++) {
        #pragma unroll
        for (int r = 0; r < 4; r++) {
            float ps = 0.f, pd = 0.f;
            #pragma unroll
            for (int nn = 0; nn < 4; nn++) {
                ps += acc[mm][nn][r] * avs[nn];
                pd += acc[mm][nn][r] * avd[nn];
            }
            #pragma unroll
            for (int off = 1; off < 16; off <<= 1) {
                ps += __shfl_xor(ps, off);
                pd += __shfl_xor(pd, off);
            }
            if (c16 == 0) {
                int grow = row0 + wr * 64 + mm * 16 + lq * 4 + r;
                if (grow < M) {
                    s_src[grow * 4 + head] = ps;
                    s_dst[grow * 4 + head] = pd;
                }
            }
        }
    }
}

// standalone GEMM (layer 2, f16 A, fp8 C)
__global__ __launch_bounds__(256) void k_gemm_mfma(const unsigned short* __restrict__ A,
                                                   const unsigned short* __restrict__ Bt,
                                                   const float* __restrict__ asrc,
                                                   const float* __restrict__ adst,
                                                   unsigned char* __restrict__ C8,
                                                   float* __restrict__ s_src,
                                                   float* __restrict__ s_dst,
                                                   int M, int K) {
    __shared__ unsigned short Asm[128 * 32];
    __shared__ unsigned short Bsm[128 * 32];
    gemm_body<0>(blockIdx.x, A, Bt, asrc, adst, C8, s_src, s_dst, M, K, Asm, Bsm);
}

// fused: layer-1 GEMM (f32 A, fp8 C) + atomic-free CSR scatter
__global__ __launch_bounds__(256) void k_b(const float* __restrict__ A,
                                           const unsigned short* __restrict__ Bt,
                                           const float* __restrict__ asrc,
                                           const float* __restrict__ adst,
                                           unsigned char* __restrict__ C8,
                                           float* __restrict__ s_src,
                                           float* __restrict__ s_dst,
                                           int M, int K, int gemmBlocks,
                                           const int* __restrict__ src, const int* __restrict__ dst,
                                           const int* __restrict__ rowptr,
                                           const unsigned short* __restrict__ rank,
                                           unsigned* __restrict__ colp, int e) {
    __shared__ unsigned short Asm[128 * 32];
    __shared__ unsigned short Bsm[128 * 32];
    int bid = blockIdx.x;
    if (bid < gemmBlocks) {
        gemm_body<1>(bid, A, Bt, asrc, adst, C8, s_src, s_dst, M, K, Asm, Bsm);
    } else {
        int half = (e + 1) >> 1;
        int i = (bid - gemmBlocks) * 256 + (int)threadIdx.x;
        if (i < half) {
            int d = dst[i];
            colp[rowptr[d] + rank[i]] = (unsigned)src[i] | ((unsigned)d << 16);
        }
        int j = i + half;
        if (j < e) {
            int d = dst[j];
            colp[rowptr[d] + rank[j]] = (unsigned)src[j] | ((unsigned)d << 16);
        }
    }
}

// ---------------- single-pass aggregation, layers 1&2 (fp8 h, lane-vectorized p) ------
__global__ void k_aggregate(const unsigned char* __restrict__ h8, const int* __restrict__ rowptr,
                            const unsigned* __restrict__ colp,
                            const float* __restrict__ s_src, const float* __restrict__ s_dst,
                            const float* __restrict__ bias,
                            unsigned short* __restrict__ out, int n, int e) {
    int wave = (blockIdx.x * blockDim.x + threadIdx.x) >> 6;
    int lane = threadIdx.x & 63;
    if (wave >= n) return;
    int half = lane >> 5, l5 = lane & 31;
    int head = l5 >> 3;          // 8 lanes x 8 feats = 64 feats per head
    int j8 = l5 & 7;             // index within head group (edge assignment for p)
    int base8 = lane & ~7;       // shfl source base of this head group
    unsigned foff = (unsigned)(l5 * 8);    // byte offset of this lane's 8 fp8 feats
    int rs = rowptr[wave], re = rowptr[wave + 1];
    float sd = s_dst[wave * 4 + head];

    float z = 0.f;
    f32x2 a01 = {0.f, 0.f}, a23 = {0.f, 0.f}, a45 = {0.f, 0.f}, a67 = {0.f, 0.f};
    #define PEDGE(SV) __expf(fminf(lrelu((SV) + sd), 80.f))
    #define ACC8(P, HV) { \
        f32x2 pbc = {(P), (P)}; \
        f32x2 v0 = __builtin_amdgcn_cvt_pk_f32_fp8((HV).x, false); \
        f32x2 v1 = __builtin_amdgcn_cvt_pk_f32_fp8((HV).x, true);  \
        f32x2 v2 = __builtin_amdgcn_cvt_pk_f32_fp8((HV).y, false); \
        f32x2 v3 = __builtin_amdgcn_cvt_pk_f32_fp8((HV).y, true);  \
        asm("v_pk_fma_f32 %0, %1, %2, %0" : "+v"(a01) : "v"(v0), "v"(pbc)); \
        asm("v_pk_fma_f32 %0, %1, %2, %0" : "+v"(a23) : "v"(v1), "v"(pbc)); \
        asm("v_pk_fma_f32 %0, %1, %2, %0" : "+v"(a45) : "v"(v2), "v"(pbc)); \
        asm("v_pk_fma_f32 %0, %1, %2, %0" : "+v"(a67) : "v"(v3), "v"(pbc)); \
        z += (P); }

    if (half == 0) {
        float pself = PEDGE(s_src[wave * 4 + head]);
        uint2 own = *(const uint2*)(h8 + (((unsigned)wave << 8) + foff));
        ACC8(pself, own);
    }
    int i = rs + half;
    // 8 edges per iteration per half; lane j8 computes p for edge j8, shfl-broadcast.
    for (; i + 14 < re; i += 16) {
        unsigned cc[8];
        #pragma unroll
        for (int j = 0; j < 8; j++) cc[j] = colp[i + 2 * j];
        float s_own = s_src[(cc[j8] & 0xffffu) * 4 + head];
        uint2 hv[8];
        #pragma unroll
        for (int j = 0; j < 8; j++)
            hv[j] = *(const uint2*)(h8 + (((cc[j] & 0xffffu) << 8) + foff));
        float p_own = PEDGE(s_own);
        float pv[8];
        #pragma unroll
        for (int j = 0; j < 8; j++) pv[j] = __shfl(p_own, base8 + j);
        #pragma unroll
        for (int j = 0; j < 8; j++) { ACC8(pv[j], hv[j]); }
    }
    for (; i + 6 < re; i += 8) {
        unsigned cc[4];
        #pragma unroll
        for (int j = 0; j < 4; j++) cc[j] = colp[i + 2 * j];
        float s_own = s_src[(cc[j8 & 3] & 0xffffu) * 4 + head];
        uint2 hv[4];
        #pragma unroll
        for (int j = 0; j < 4; j++)
            hv[j] = *(const uint2*)(h8 + (((cc[j] & 0xffffu) << 8) + foff));
        float p_own = PEDGE(s_own);
        float pv[4];
        #pragma unroll
        for (int j = 0; j < 4; j++) pv[j] = __shfl(p_own, base8 + j);
        #pragma unroll
        for (int j = 0; j < 4; j++) { ACC8(pv[j], hv[j]); }
    }
    for (; i < re; i += 2) {
        unsigned c0 = colp[i];
        float s0 = s_src[(c0 & 0xffffu) * 4 + head];
        uint2 h0 = *(const uint2*)(h8 + (((c0 & 0xffffu) << 8) + foff));
        float p0 = PEDGE(s0);
        ACC8(p0, h0);
    }
    #undef ACC8
    #undef PEDGE
    // merge halves
    z += __shfl_xor(z, 32);
    float a[8] = {a01.x, a01.y, a23.x, a23.y, a45.x, a45.y, a67.x, a67.y};
    #pragma unroll
    for (int j = 0; j < 8; j++) a[j] += __shfl_xor(a[j], 32);

    if (half == 0) {
        float inv = 1.f / z;
        int f0 = l5 * 8;
        float4 bv0 = *(const float4*)(bias + f0);
        float4 bv1 = *(const float4*)(bias + f0 + 4);
        float o[8];
        o[0] = a[0] * inv + bv0.x; o[1] = a[1] * inv + bv0.y;
        o[2] = a[2] * inv + bv0.z; o[3] = a[3] * inv + bv0.w;
        o[4] = a[4] * inv + bv1.x; o[5] = a[5] * inv + bv1.y;
        o[6] = a[6] * inv + bv1.z; o[7] = a[7] * inv + bv1.w;
        #pragma unroll
        for (int j = 0; j < 8; j++) o[j] = o[j] > 0.f ? o[j] : __expf(o[j]) - 1.f;
        uint4 ov;
        unsigned* w = (unsigned*)&ov;
        #pragma unroll
        for (int j = 0; j < 4; j++)
            w[j] = (unsigned)f2h(o[2 * j]) | ((unsigned)f2h(o[2 * j + 1]) << 16);
        *(uint4*)(out + (size_t)wave * 256 + f0) = ov;
    }
}

// ---------------- layer 3: GEMM [M,256](f16)@[256,16](f32) -> f16 + fused scores ----
__global__ __launch_bounds__(256) void k_gemm3(const unsigned short* __restrict__ A,
                                               const float* __restrict__ B,
                                               const float* __restrict__ a3s,
                                               const float* __restrict__ a3d,
                                               unsigned short* __restrict__ C,
                                               float* __restrict__ s_src,
                                               float* __restrict__ s_dst,
                                               int M, int K) {
    __shared__ float Bs[256 * 16];
    for (int i = threadIdx.x; i < K * 16; i += 256) Bs[i] = B[i];
    __syncthreads();
    int tx = threadIdx.x & 15;
    int ty = threadIdx.x >> 4;
    int row = blockIdx.x * 16 + ty;
    if (row >= M) return;
    const unsigned short* Ar = A + (size_t)row * K;
    float acc = 0.f;
    for (int kk = 0; kk < K; kk += 8) {
        uint4 va = *(const uint4*)(Ar + kk);
        const unsigned* u = (const unsigned*)&va;
        #pragma unroll
        for (int j = 0; j < 4; j++) {
            float lo = h2f((unsigned short)(u[j] & 0xffff));
            float hi = h2f((unsigned short)(u[j] >> 16));
            acc += lo * Bs[(kk + 2 * j) * 16 + tx] + hi * Bs[(kk + 2 * j + 1) * 16 + tx];
        }
    }
    C[(size_t)row * 16 + tx] = f2h(acc);
    float ps = acc * a3s[tx], pd = acc * a3d[tx];
    #pragma unroll
    for (int off = 1; off < 16; off <<= 1) {
        ps += __shfl_xor(ps, off);
        pd += __shfl_xor(pd, off);
    }
    if (tx == 0) { s_src[row] = ps; s_dst[row] = pd; }
}

// ---------------- layer 3 aggregation + inline scores + bias + log_softmax ----------
__global__ void k_agg3(const unsigned short* __restrict__ h3, const int* __restrict__ rowptr,
                       const unsigned* __restrict__ colp,
                       const float* __restrict__ s_src, const float* __restrict__ s_dst,
                       const float* __restrict__ b3,
                       float* __restrict__ outp, int n) {
    int wave = (blockIdx.x * blockDim.x + threadIdx.x) >> 6;
    int lane = threadIdx.x & 63;
    if (wave >= n) return;
    int g = lane >> 4, c = lane & 15;
    int rs = rowptr[wave], re = rowptr[wave + 1];
    float sdn = s_dst[wave];

    float z = 0.f, acc = 0.f;
    if (g == 0) {
        float p = __expf(fminf(lrelu(s_src[wave] + sdn), 80.f));
        z += p;
        acc += p * h2f(h3[(size_t)wave * 16 + c]);
    }
    int i = rs + g;
    for (; i + 12 < re; i += 16) {
        int s0 = colp[i] & 0xffff,     s1 = colp[i + 4] & 0xffff;
        int s2 = colp[i + 8] & 0xffff, s3 = colp[i + 12] & 0xffff;
        float q0 = s_src[s0], q1 = s_src[s1], q2 = s_src[s2], q3 = s_src[s3];
        float v0 = h2f(h3[(size_t)s0 * 16 + c]), v1 = h2f(h3[(size_t)s1 * 16 + c]);
        float v2 = h2f(h3[(size_t)s2 * 16 + c]), v3 = h2f(h3[(size_t)s3 * 16 + c]);
        float p0 = __expf(fminf(lrelu(q0 + sdn), 80.f));
        float p1 = __expf(fminf(lrelu(q1 + sdn), 80.f));
        float p2 = __expf(fminf(lrelu(q2 + sdn), 80.f));
        float p3 = __expf(fminf(lrelu(q3 + sdn), 80.f));
        z += (p0 + p1) + (p2 + p3);
        acc += p0 * v0 + p1 * v1 + p2 * v2 + p3 * v3;
    }
    for (; i + 4 < re; i += 8) {
        int s0 = colp[i] & 0xffff, s1 = colp[i + 4] & 0xffff;
        float q0 = s_src[s0], q1 = s_src[s1];
        float v0 = h2f(h3[(size_t)s0 * 16 + c]), v1 = h2f(h3[(size_t)s1 * 16 + c]);
        float p0 = __expf(fminf(lrelu(q0 + sdn), 80.f));
        float p1 = __expf(fminf(lrelu(q1 + sdn), 80.f));
        z += p0 + p1;
        acc += p0 * v0 + p1 * v1;
    }
    for (; i < re; i += 4) {
        int s = colp[i] & 0xffff;
        float p = __expf(fminf(lrelu(s_src[s] + sdn), 80.f));
        z += p;
        acc += p * h2f(h3[(size_t)s * 16 + c]);
    }
    z += __shfl_xor(z, 16);  z += __shfl_xor(z, 32);
    acc += __shfl_xor(acc, 16); acc += __shfl_xor(acc, 32);
    if (lane < 16) {
        float v = acc / z + b3[c];
        float mm = v;
        #pragma unroll
        for (int off = 1; off < 16; off <<= 1) mm = fmaxf(mm, __shfl_xor(mm, off));
        float se = __expf(v - mm);
        #pragma unroll
        for (int off = 1; off < 16; off <<= 1) se += __shfl_xor(se, off);
        outp[(size_t)wave * 16 + c] = v - mm - logf(se);
    }
}

extern "C" void kernel_launch(void* const* d_in, const int* in_sizes, int n_in,
                              void* d_out, int out_size, void* d_ws, size_t ws_size,
                              hipStream_t stream) {
    const float* x      = (const float*)d_in[0];
    const int*   ei     = (const int*)d_in[1];
    const float* W1     = (const float*)d_in[2];
    const float* a1_src = (const float*)d_in[3];
    const float* a1_dst = (const float*)d_in[4];
    const float* b1     = (const float*)d_in[5];
    const float* W2     = (const float*)d_in[6];
    const float* a2_src = (const float*)d_in[7];
    const float* a2_dst = (const float*)d_in[8];
    const float* b2     = (const float*)d_in[9];
    const float* W3     = (const float*)d_in[10];
    const float* a3_src = (const float*)d_in[11];
    const float* a3_dst = (const float*)d_in[12];
    const float* b3     = (const float*)d_in[13];
    float* outp = (float*)d_out;

    const int N = N_NODES, E = N_EDGES;
    const int* src = ei;
    const int* dst = ei + E;

    char* ws = (char*)d_ws;
    size_t off = 0;
    auto alloc = [&](size_t bytes) {
        void* p = ws + off;
        off = (off + bytes + 255) & ~(size_t)255;
        return p;
    };
    int*   rowptr = (int*)alloc((N + 1) * sizeof(int));
    int*   counts = (int*)alloc(N * sizeof(int));
    unsigned* colp = (unsigned*)alloc(E * sizeof(unsigned));
    unsigned short* rank = (unsigned short*)alloc(E * sizeof(short));
    int*   incl   = (int*)alloc(N * sizeof(int));
    int*   bsums  = (int*)alloc(64 * sizeof(int));
    int*   boffs  = (int*)alloc(64 * sizeof(int));
    float* s_src  = (float*)alloc((size_t)N * HEADS * sizeof(float));
    float* s_dst  = (float*)alloc((size_t)N * HEADS * sizeof(float));
    unsigned short* W1t = (unsigned short*)alloc((size_t)256 * F_IN * sizeof(short));
    unsigned short* W2t = (unsigned short*)alloc((size_t)256 * 256 * sizeof(short));
    unsigned char* hA8  = (unsigned char*)alloc((size_t)N * 256);          // fp8 e4m3
    unsigned short* hB  = (unsigned short*)alloc((size_t)N * 256 * sizeof(short));
    unsigned short* h3  = (unsigned short*)alloc((size_t)N * 16 * sizeof(short));
    (void)ws_size;

    const int aggBlocks = (N + 3) / 4;
    const int gemmBlocks = ((N + 127) / 128) * 2;
    const int scatBlocks = ((E + 1) / 2 + 255) / 256;

    // ---- prep: zero counts, W transposes + hist/ranks ----
    k_zero<<<(N / 4 + 255) / 256, 256, 0, stream>>>((int4*)counts, N / 4);
    k_prep<<<NB_WT1 + NB_WT2 + NB_HIST, 256, 0, stream>>>(W1, W1t, W2, W2t, dst, counts, rank);

    // ---- CSR scan ----
    const int nb = (N + 1023) / 1024;
    k_scan1<<<nb, 256, 0, stream>>>(counts, incl, bsums, N);
    k_scan2<<<1, 64, 0, stream>>>(bsums, boffs, nb, rowptr + N);
    k_scan3<<<(N + 255) / 256, 256, 0, stream>>>(incl, counts, boffs, rowptr, N);

    // ---- fused: layer-1 GEMM (f32 x -> fp8 hA) + atomic-free scatter ----
    k_b<<<gemmBlocks + scatBlocks, 256, 0, stream>>>(x, W1t, a1_src, a1_dst, hA8, s_src, s_dst,
                                                     N, F_IN, gemmBlocks,
                                                     src, dst, rowptr, rank, colp, E);
    // ---- layer 1 (scores inline) ----
    k_aggregate<<<aggBlocks, 256, 0, stream>>>(hA8, rowptr, colp, s_src, s_dst, b1, hB, N, E);
    // ---- layer 2 ----
    k_gemm_mfma<<<gemmBlocks, 256, 0, stream>>>(hB, W2t, a2_src, a2_dst, hA8, s_src, s_dst, N, 256);
    k_aggregate<<<aggBlocks, 256, 0, stream>>>(hA8, rowptr, colp, s_src, s_dst, b2, hB, N, E);
    // ---- layer 3 ----
    k_gemm3<<<(N + 15) / 16, 256, 0, stream>>>(hB, W3, a3_src, a3_dst, h3, s_src, s_dst, N, 256);
    k_agg3<<<aggBlocks, 256, 0, stream>>>(h3, rowptr, colp, s_src, s_dst, b3, outp, N);
}

// Round 15
// 222.097 us; speedup vs baseline: 2.8792x; 1.0348x over previous
//
#include <hip/hip_runtime.h>
#include <hip/hip_bf16.h>
#include <math.h>

#define N_NODES 50000
#define N_EDGES 800000
#define F_IN    128
#define HID     64
#define HEADS   4
#define NCLS    16
#define NEG_SLOPE 0.2f

typedef __attribute__((ext_vector_type(8))) _Float16 half8v;
typedef __attribute__((ext_vector_type(4))) float f32x4;
typedef __attribute__((ext_vector_type(2))) float f32x2;

static __device__ __forceinline__ float lrelu(float x) {
    return x >= 0.f ? x : NEG_SLOPE * x;
}
static __device__ __forceinline__ unsigned short f2h(float f) {
    _Float16 h = (_Float16)f;
    return __builtin_bit_cast(unsigned short, h);
}
static __device__ __forceinline__ float h2f(unsigned short u) {
    return (float)__builtin_bit_cast(_Float16, u);
}

// ---------------- zero counts ----------------
__global__ void k_zero(int4* __restrict__ p, int n4) {
    int i = blockIdx.x * blockDim.x + threadIdx.x;
    if (i < n4) p[i] = int4{0, 0, 0, 0};
}

// ---------------- fused prep: W1t, W2t, edge histogram + ranks ----------------
#define NB_WT1  128           // 128*256 / 256
#define NB_WT2  256           // 256*256 / 256
#define NB_HIST 3125          // E / 256
__global__ void k_prep(const float* __restrict__ W1, unsigned short* __restrict__ W1t,
                       const float* __restrict__ W2, unsigned short* __restrict__ W2t,
                       const int* __restrict__ dst, int* __restrict__ counts,
                       unsigned short* __restrict__ rank) {
    int bid = blockIdx.x, tid = threadIdx.x;
    if (bid < NB_WT1) {
        int i = bid * 256 + tid;
        int k = i >> 8, c = i & 255;
        W1t[c * F_IN + k] = f2h(W1[i]);
    } else if (bid < NB_WT1 + NB_WT2) {
        int i = (bid - NB_WT1) * 256 + tid;
        int k = i >> 8, c = i & 255;
        W2t[c * 256 + k] = f2h(W2[i]);
    } else {
        int i = (bid - NB_WT1 - NB_WT2) * 256 + tid;
        if (i < N_EDGES) rank[i] = (unsigned short)atomicAdd(&counts[dst[i]], 1);
    }
}

// ---------------- CSR scan ----------------
__global__ __launch_bounds__(256) void k_scan1(const int* __restrict__ counts, int* __restrict__ incl,
                                               int* __restrict__ bsums, int n) {
    __shared__ int wsum[4];
    int blk = blockIdx.x, tid = threadIdx.x;
    int lane = tid & 63, w = tid >> 6;
    int i0 = blk * 1024 + tid * 4;
    int v[4];
    #pragma unroll
    for (int j = 0; j < 4; j++) v[j] = (i0 + j < n) ? counts[i0 + j] : 0;
    int t = v[0] + v[1] + v[2] + v[3];
    int x = t;
    #pragma unroll
    for (int d = 1; d < 64; d <<= 1) { int y = __shfl_up(x, d); if (lane >= d) x += y; }
    if (lane == 63) wsum[w] = x;
    __syncthreads();
    int woff = 0;
    #pragma unroll
    for (int ww = 0; ww < 4; ww++) woff += (ww < w) ? wsum[ww] : 0;
    int p = woff + x - t;
    #pragma unroll
    for (int j = 0; j < 4; j++) { p += v[j]; if (i0 + j < n) incl[i0 + j] = p; }
    if (tid == 255) bsums[blk] = woff + x;
}

__global__ void k_scan2(const int* __restrict__ bsums, int* __restrict__ boffs, int nb, int* rowptr_end) {
    int lane = threadIdx.x;
    int v = (lane < nb) ? bsums[lane] : 0;
    int x = v;
    #pragma unroll
    for (int d = 1; d < 64; d <<= 1) { int y = __shfl_up(x, d); if (lane >= d) x += y; }
    if (lane < nb) boffs[lane] = x - v;
    if (lane == 63) *rowptr_end = x;
}

__global__ void k_scan3(const int* __restrict__ incl, const int* __restrict__ counts,
                        const int* __restrict__ boffs, int* __restrict__ rowptr, int n) {
    int i = blockIdx.x * blockDim.x + threadIdx.x;
    if (i < n) rowptr[i] = boffs[i >> 10] + incl[i] - counts[i];
}

// ---------------- GEMM body (f16 MFMA, N=256) + fused per-node scores ----------
// CONVA: A is f32, converted to f16 during LDS staging. C output is fp8 e4m3.
static __device__ __forceinline__ int swz(int r, int lc) {
    return r * 4 + (lc ^ (r & 3) ^ ((r >> 2) & 1));
}

template<int CONVA>
static __device__ __forceinline__ void gemm_body(
        int bid, const void* __restrict__ Av, const unsigned short* __restrict__ Bt,
        const float* __restrict__ asrc, const float* __restrict__ adst,
        unsigned char* __restrict__ C8, float* __restrict__ s_src, float* __restrict__ s_dst,
        int M, int K, unsigned short* Asm, unsigned short* Bsm) {
    int tid = threadIdx.x;
    int lane = tid & 63, wid = tid >> 6;
    int bx = bid & 1, by = bid >> 1;
    int row0 = by * 128, col0 = bx * 128;
    int wr = wid >> 1, wc = wid & 1;
    f32x4 acc[4][4] = {};

    for (int k0 = 0; k0 < K; k0 += 32) {
        __syncthreads();
        #pragma unroll
        for (int s = 0; s < 2; s++) {
            int c = tid + s * 256;
            int row = c >> 2, lc = c & 3;
            int gr = row0 + row; if (gr >= M) gr = 0;
            uint4 va;
            if (CONVA) {
                const float* Af = (const float*)Av + (size_t)gr * K + k0 + lc * 8;
                float4 fa = *(const float4*)Af;
                float4 fb = *(const float4*)(Af + 4);
                va.x = (unsigned)f2h(fa.x) | ((unsigned)f2h(fa.y) << 16);
                va.y = (unsigned)f2h(fa.z) | ((unsigned)f2h(fa.w) << 16);
                va.z = (unsigned)f2h(fb.x) | ((unsigned)f2h(fb.y) << 16);
                va.w = (unsigned)f2h(fb.z) | ((unsigned)f2h(fb.w) << 16);
            } else {
                va = *(const uint4*)((const unsigned short*)Av + (size_t)gr * K + k0 + lc * 8);
            }
            *(uint4*)(&Asm[swz(row, lc) * 8]) = va;
            uint4 vb = *(const uint4*)(Bt + (size_t)(col0 + row) * K + k0 + lc * 8);
            *(uint4*)(&Bsm[swz(row, lc) * 8]) = vb;
        }
        __syncthreads();
        half8v af[4], bg[4];
        int lq = lane >> 4;
        #pragma unroll
        for (int m = 0; m < 4; m++) {
            int r = wr * 64 + m * 16 + (lane & 15);
            af[m] = *(const half8v*)(&Asm[swz(r, lq) * 8]);
        }
        #pragma unroll
        for (int n = 0; n < 4; n++) {
            int r = wc * 64 + n * 16 + (lane & 15);
            bg[n] = *(const half8v*)(&Bsm[swz(r, lq) * 8]);
        }
        #pragma unroll
        for (int m = 0; m < 4; m++)
            #pragma unroll
            for (int n = 0; n < 4; n++)
                acc[m][n] = __builtin_amdgcn_mfma_f32_16x16x32_f16(af[m], bg[n], acc[m][n], 0, 0, 0);
    }

    // C write: fp8 e4m3, row stride 256 B
    #pragma unroll
    for (int m = 0; m < 4; m++) {
        #pragma unroll
        for (int r = 0; r < 4; r++) {
            int row = row0 + wr * 64 + m * 16 + (lane >> 4) * 4 + r;
            if (row < M) {
                int q01 = __builtin_amdgcn_cvt_pk_fp8_f32(acc[m][0][r], acc[m][1][r], 0, false);
                int q23 = __builtin_amdgcn_cvt_pk_fp8_f32(acc[m][2][r], acc[m][3][r], 0, false);
                size_t base = (size_t)row * 256 + col0 + wc * 64 + (lane & 15);
                C8[base]      = (unsigned char)(q01 & 0xff);
                C8[base + 16] = (unsigned char)((q01 >> 8) & 0xff);
                C8[base + 32] = (unsigned char)(q23 & 0xff);
                C8[base + 48] = (unsigned char)((q23 >> 8) & 0xff);
            }
        }
    }

    // fused attention scores: this wave's 64 cols = head (bx*2+wc)
    int c16 = lane & 15, lq = lane >> 4;
    int head = bx * 2 + wc;
    float avs[4], avd[4];
    #pragma unroll
    for (int nn = 0; nn < 4; nn++) {
        avs[nn] = asrc[head * 64 + nn * 16 + c16];
        avd[nn] = adst[head * 64 + nn * 16 + c16];
    }
    #pragma unroll
    for (int mm = 0; mm < 4; mm++) {
        #pragma unroll
        for (int r = 0; r < 4; r++) {
            float ps = 0.f, pd = 0.f;
            #pragma unroll
            for (int nn = 0; nn < 4; nn++) {
                ps += acc[mm][nn][r] * avs[nn];
                pd += acc[mm][nn][r] * avd[nn];
            }
            #pragma unroll
            for (int off = 1; off < 16; off <<= 1) {
                ps += __shfl_xor(ps, off);
                pd += __shfl_xor(pd, off);
            }
            if (c16 == 0) {
                int grow = row0 + wr * 64 + mm * 16 + lq * 4 + r;
                if (grow < M) {
                    s_src[grow * 4 + head] = ps;
                    s_dst[grow * 4 + head] = pd;
                }
            }
        }
    }
}

// standalone GEMM (layer 2, f16 A, fp8 C)
__global__ __launch_bounds__(256) void k_gemm_mfma(const unsigned short* __restrict__ A,
                                                   const unsigned short* __restrict__ Bt,
                                                   const float* __restrict__ asrc,
                                                   const float* __restrict__ adst,
                                                   unsigned char* __restrict__ C8,
                                                   float* __restrict__ s_src,
                                                   float* __restrict__ s_dst,
                                                   int M, int K) {
    __shared__ unsigned short Asm[128 * 32];
    __shared__ unsigned short Bsm[128 * 32];
    gemm_body<0>(blockIdx.x, A, Bt, asrc, adst, C8, s_src, s_dst, M, K, Asm, Bsm);
}

// fused: layer-1 GEMM (f32 A, fp8 C) + atomic-free CSR scatter (ushort col)
__global__ __launch_bounds__(256) void k_b(const float* __restrict__ A,
                                           const unsigned short* __restrict__ Bt,
                                           const float* __restrict__ asrc,
                                           const float* __restrict__ adst,
                                           unsigned char* __restrict__ C8,
                                           float* __restrict__ s_src,
                                           float* __restrict__ s_dst,
                                           int M, int K, int gemmBlocks,
                                           const int* __restrict__ src, const int* __restrict__ dst,
                                           const int* __restrict__ rowptr,
                                           const unsigned short* __restrict__ rank,
                                           unsigned short* __restrict__ col, int e) {
    __shared__ unsigned short Asm[128 * 32];
    __shared__ unsigned short Bsm[128 * 32];
    int bid = blockIdx.x;
    if (bid < gemmBlocks) {
        gemm_body<1>(bid, A, Bt, asrc, adst, C8, s_src, s_dst, M, K, Asm, Bsm);
    } else {
        int half = (e + 1) >> 1;
        int i = (bid - gemmBlocks) * 256 + (int)threadIdx.x;
        if (i < half) {
            int d = dst[i];
            col[rowptr[d] + rank[i]] = (unsigned short)src[i];
        }
        int j = i + half;
        if (j < e) {
            int d = dst[j];
            col[rowptr[d] + rank[j]] = (unsigned short)src[j];
        }
    }
}

// ---------------- single-pass aggregation, layers 1&2 (fp8 h, 2 nodes/wave) ----------
// One node per 32-lane half. 4 head groups x 8 lanes, 8 fp8 feats/lane.
__global__ void k_aggregate(const unsigned char* __restrict__ h8, const int* __restrict__ rowptr,
                            const unsigned short* __restrict__ col,
                            const float* __restrict__ s_src, const float* __restrict__ s_dst,
                            const float* __restrict__ bias,
                            unsigned short* __restrict__ out, int n) {
    int wave = (blockIdx.x * blockDim.x + threadIdx.x) >> 6;
    int lane = threadIdx.x & 63;
    int half = lane >> 5, l5 = lane & 31;
    int node = wave * 2 + half;
    if (node >= n) return;
    int head = l5 >> 3;          // 4 head groups of 8 lanes per half
    int j8 = l5 & 7;
    int base8 = lane & ~7;       // shfl base of this 8-lane group
    unsigned foff = (unsigned)(l5 * 8);    // byte offset of this lane's 8 fp8 feats
    int rs = rowptr[node], re = rowptr[node + 1];
    float sd = s_dst[node * 4 + head];

    float z = 0.f;
    f32x2 a01 = {0.f, 0.f}, a23 = {0.f, 0.f}, a45 = {0.f, 0.f}, a67 = {0.f, 0.f};
    #define PEDGE(SV) __expf(fminf(lrelu((SV) + sd), 80.f))
    #define ACC8(P, HV) { \
        f32x2 pbc = {(P), (P)}; \
        f32x2 v0 = __builtin_amdgcn_cvt_pk_f32_fp8((HV).x, false); \
        f32x2 v1 = __builtin_amdgcn_cvt_pk_f32_fp8((HV).x, true);  \
        f32x2 v2 = __builtin_amdgcn_cvt_pk_f32_fp8((HV).y, false); \
        f32x2 v3 = __builtin_amdgcn_cvt_pk_f32_fp8((HV).y, true);  \
        asm("v_pk_fma_f32 %0, %1, %2, %0" : "+v"(a01) : "v"(v0), "v"(pbc)); \
        asm("v_pk_fma_f32 %0, %1, %2, %0" : "+v"(a23) : "v"(v1), "v"(pbc)); \
        asm("v_pk_fma_f32 %0, %1, %2, %0" : "+v"(a45) : "v"(v2), "v"(pbc)); \
        asm("v_pk_fma_f32 %0, %1, %2, %0" : "+v"(a67) : "v"(v3), "v"(pbc)); \
        z += (P); }

    {
        float pself = PEDGE(s_src[node * 4 + head]);
        uint2 own = *(const uint2*)(h8 + (((unsigned)node << 8) + foff));
        ACC8(pself, own);
    }
    int i = rs;
    // 8 edges per iteration; lane j8 computes p for edge j8, shfl-broadcast within group.
    for (; i + 7 < re; i += 8) {
        unsigned cc[8];
        #pragma unroll
        for (int j = 0; j < 8; j++) cc[j] = col[i + j];
        float s_own = s_src[cc[j8] * 4 + head];
        uint2 hv[8];
        #pragma unroll
        for (int j = 0; j < 8; j++)
            hv[j] = *(const uint2*)(h8 + ((cc[j] << 8) + foff));
        float p_own = PEDGE(s_own);
        float pv[8];
        #pragma unroll
        for (int j = 0; j < 8; j++) pv[j] = __shfl(p_own, base8 + j);
        #pragma unroll
        for (int j = 0; j < 8; j++) { ACC8(pv[j], hv[j]); }
    }
    for (; i + 3 < re; i += 4) {
        unsigned cc[4];
        #pragma unroll
        for (int j = 0; j < 4; j++) cc[j] = col[i + j];
        float s_own = s_src[cc[j8 & 3] * 4 + head];
        uint2 hv[4];
        #pragma unroll
        for (int j = 0; j < 4; j++)
            hv[j] = *(const uint2*)(h8 + ((cc[j] << 8) + foff));
        float p_own = PEDGE(s_own);
        float pv[4];
        #pragma unroll
        for (int j = 0; j < 4; j++) pv[j] = __shfl(p_own, base8 + j);
        #pragma unroll
        for (int j = 0; j < 4; j++) { ACC8(pv[j], hv[j]); }
    }
    for (; i < re; i++) {
        unsigned c0 = col[i];
        float s0 = s_src[c0 * 4 + head];
        uint2 h0 = *(const uint2*)(h8 + ((c0 << 8) + foff));
        float p0 = PEDGE(s0);
        ACC8(p0, h0);
    }
    #undef ACC8
    #undef PEDGE

    float inv = 1.f / z;
    int f0 = l5 * 8;
    float4 bv0 = *(const float4*)(bias + f0);
    float4 bv1 = *(const float4*)(bias + f0 + 4);
    float o[8];
    o[0] = a01.x * inv + bv0.x; o[1] = a01.y * inv + bv0.y;
    o[2] = a23.x * inv + bv0.z; o[3] = a23.y * inv + bv0.w;
    o[4] = a45.x * inv + bv1.x; o[5] = a45.y * inv + bv1.y;
    o[6] = a67.x * inv + bv1.z; o[7] = a67.y * inv + bv1.w;
    #pragma unroll
    for (int j = 0; j < 8; j++) o[j] = o[j] > 0.f ? o[j] : __expf(o[j]) - 1.f;
    uint4 ov;
    unsigned* w = (unsigned*)&ov;
    #pragma unroll
    for (int j = 0; j < 4; j++)
        w[j] = (unsigned)f2h(o[2 * j]) | ((unsigned)f2h(o[2 * j + 1]) << 16);
    *(uint4*)(out + (size_t)node * 256 + f0) = ov;
}

// ---------------- layer 3: GEMM [M,256](f16)@[256,16](f32) -> f16 + fused scores ----
__global__ __launch_bounds__(256) void k_gemm3(const unsigned short* __restrict__ A,
                                               const float* __restrict__ B,
                                               const float* __restrict__ a3s,
                                               const float* __restrict__ a3d,
                                               unsigned short* __restrict__ C,
                                               float* __restrict__ s_src,
                                               float* __restrict__ s_dst,
                                               int M, int K) {
    __shared__ float Bs[256 * 16];
    for (int i = threadIdx.x; i < K * 16; i += 256) Bs[i] = B[i];
    __syncthreads();
    int tx = threadIdx.x & 15;
    int ty = threadIdx.x >> 4;
    int row = blockIdx.x * 16 + ty;
    if (row >= M) return;
    const unsigned short* Ar = A + (size_t)row * K;
    float acc = 0.f;
    for (int kk = 0; kk < K; kk += 8) {
        uint4 va = *(const uint4*)(Ar + kk);
        const unsigned* u = (const unsigned*)&va;
        #pragma unroll
        for (int j = 0; j < 4; j++) {
            float lo = h2f((unsigned short)(u[j] & 0xffff));
            float hi = h2f((unsigned short)(u[j] >> 16));
            acc += lo * Bs[(kk + 2 * j) * 16 + tx] + hi * Bs[(kk + 2 * j + 1) * 16 + tx];
        }
    }
    C[(size_t)row * 16 + tx] = f2h(acc);
    float ps = acc * a3s[tx], pd = acc * a3d[tx];
    #pragma unroll
    for (int off = 1; off < 16; off <<= 1) {
        ps += __shfl_xor(ps, off);
        pd += __shfl_xor(pd, off);
    }
    if (tx == 0) { s_src[row] = ps; s_dst[row] = pd; }
}

// ---------------- layer 3 aggregation + inline scores + bias + log_softmax ----------
__global__ void k_agg3(const unsigned short* __restrict__ h3, const int* __restrict__ rowptr,
                       const unsigned short* __restrict__ col,
                       const float* __restrict__ s_src, const float* __restrict__ s_dst,
                       const float* __restrict__ b3,
                       float* __restrict__ outp, int n) {
    int wave = (blockIdx.x * blockDim.x + threadIdx.x) >> 6;
    int lane = threadIdx.x & 63;
    if (wave >= n) return;
    int g = lane >> 4, c = lane & 15;
    int gbase = lane & ~15;
    int rs = rowptr[wave], re = rowptr[wave + 1];
    float sdn = s_dst[wave];

    float z = 0.f, acc = 0.f;
    if (g == 0) {
        float p = __expf(fminf(lrelu(s_src[wave] + sdn), 80.f));
        z += p;
        acc += p * h2f(h3[(size_t)wave * 16 + c]);
    }
    int i = rs + g;
    // 4 edges per group-iteration; lane (c&3) computes p for its edge, shfl-broadcast.
    for (; i + 12 < re; i += 16) {
        int ss[4];
        #pragma unroll
        for (int j = 0; j < 4; j++) ss[j] = col[i + 4 * j];
        float q_own = s_src[ss[c & 3]];
        float v0 = h2f(h3[(size_t)ss[0] * 16 + c]), v1 = h2f(h3[(size_t)ss[1] * 16 + c]);
        float v2 = h2f(h3[(size_t)ss[2] * 16 + c]), v3 = h2f(h3[(size_t)ss[3] * 16 + c]);
        float p_own = __expf(fminf(lrelu(q_own + sdn), 80.f));
        float p0 = __shfl(p_own, gbase + 0);
        float p1 = __shfl(p_own, gbase + 1);
        float p2 = __shfl(p_own, gbase + 2);
        float p3 = __shfl(p_own, gbase + 3);
        z += (p0 + p1) + (p2 + p3);
        acc += p0 * v0 + p1 * v1 + p2 * v2 + p3 * v3;
    }
    for (; i < re; i += 4) {
        int s = col[i];
        float p = __expf(fminf(lrelu(s_src[s] + sdn), 80.f));
        z += p;
        acc += p * h2f(h3[(size_t)s * 16 + c]);
    }
    z += __shfl_xor(z, 16);  z += __shfl_xor(z, 32);
    acc += __shfl_xor(acc, 16); acc += __shfl_xor(acc, 32);
    if (lane < 16) {
        float v = acc / z + b3[c];
        float mm = v;
        #pragma unroll
        for (int off = 1; off < 16; off <<= 1) mm = fmaxf(mm, __shfl_xor(mm, off));
        float se = __expf(v - mm);
        #pragma unroll
        for (int off = 1; off < 16; off <<= 1) se += __shfl_xor(se, off);
        outp[(size_t)wave * 16 + c] = v - mm - logf(se);
    }
}

extern "C" void kernel_launch(void* const* d_in, const int* in_sizes, int n_in,
                              void* d_out, int out_size, void* d_ws, size_t ws_size,
                              hipStream_t stream) {
    const float* x      = (const float*)d_in[0];
    const int*   ei     = (const int*)d_in[1];
    const float* W1     = (const float*)d_in[2];
    const float* a1_src = (const float*)d_in[3];
    const float* a1_dst = (const float*)d_in[4];
    const float* b1     = (const float*)d_in[5];
    const float* W2     = (const float*)d_in[6];
    const float* a2_src = (const float*)d_in[7];
    const float* a2_dst = (const float*)d_in[8];
    const float* b2     = (const float*)d_in[9];
    const float* W3     = (const float*)d_in[10];
    const float* a3_src = (const float*)d_in[11];
    const float* a3_dst = (const float*)d_in[12];
    const float* b3     = (const float*)d_in[13];
    float* outp = (float*)d_out;

    const int N = N_NODES, E = N_EDGES;
    const int* src = ei;
    const int* dst = ei + E;

    char* ws = (char*)d_ws;
    size_t off = 0;
    auto alloc = [&](size_t bytes) {
        void* p = ws + off;
        off = (off + bytes + 255) & ~(size_t)255;
        return p;
    };
    int*   rowptr = (int*)alloc((N + 1) * sizeof(int));
    int*   counts = (int*)alloc(N * sizeof(int));
    unsigned short* col = (unsigned short*)alloc(E * sizeof(short));
    unsigned short* rank = (unsigned short*)alloc(E * sizeof(short));
    int*   incl   = (int*)alloc(N * sizeof(int));
    int*   bsums  = (int*)alloc(64 * sizeof(int));
    int*   boffs  = (int*)alloc(64 * sizeof(int));
    float* s_src  = (float*)alloc((size_t)N * HEADS * sizeof(float));
    float* s_dst  = (float*)alloc((size_t)N * HEADS * sizeof(float));
    unsigned short* W1t = (unsigned short*)alloc((size_t)256 * F_IN * sizeof(short));
    unsigned short* W2t = (unsigned short*)alloc((size_t)256 * 256 * sizeof(short));
    unsigned char* hA8  = (unsigned char*)alloc((size_t)N * 256);          // fp8 e4m3
    unsigned short* hB  = (unsigned short*)alloc((size_t)N * 256 * sizeof(short));
    unsigned short* h3  = (unsigned short*)alloc((size_t)N * 16 * sizeof(short));
    (void)ws_size;

    const int aggBlocks  = (N + 3) / 4;        // k_agg3: 1 node/wave
    const int aggBlocks2 = (N + 7) / 8;        // k_aggregate: 2 nodes/wave
    const int gemmBlocks = ((N + 127) / 128) * 2;
    const int scatBlocks = ((E + 1) / 2 + 255) / 256;

    // ---- prep: zero counts, W transposes + hist/ranks ----
    k_zero<<<(N / 4 + 255) / 256, 256, 0, stream>>>((int4*)counts, N / 4);
    k_prep<<<NB_WT1 + NB_WT2 + NB_HIST, 256, 0, stream>>>(W1, W1t, W2, W2t, dst, counts, rank);

    // ---- CSR scan ----
    const int nb = (N + 1023) / 1024;
    k_scan1<<<nb, 256, 0, stream>>>(counts, incl, bsums, N);
    k_scan2<<<1, 64, 0, stream>>>(bsums, boffs, nb, rowptr + N);
    k_scan3<<<(N + 255) / 256, 256, 0, stream>>>(incl, counts, boffs, rowptr, N);

    // ---- fused: layer-1 GEMM (f32 x -> fp8 hA) + atomic-free scatter ----
    k_b<<<gemmBlocks + scatBlocks, 256, 0, stream>>>(x, W1t, a1_src, a1_dst, hA8, s_src, s_dst,
                                                     N, F_IN, gemmBlocks,
                                                     src, dst, rowptr, rank, col, E);
    // ---- layer 1 (scores inline) ----
    k_aggregate<<<aggBlocks2, 256, 0, stream>>>(hA8, rowptr, col, s_src, s_dst, b1, hB, N);
    // ---- layer 2 ----
    k_gemm_mfma<<<gemmBlocks, 256, 0, stream>>>(hB, W2t, a2_src, a2_dst, hA8, s_src, s_dst, N, 256);
    k_aggregate<<<aggBlocks2, 256, 0, stream>>>(hA8, rowptr, col, s_src, s_dst, b2, hB, N);
    // ---- layer 3 ----
    k_gemm3<<<(N + 15) / 16, 256, 0, stream>>>(hB, W3, a3_src, a3_dst, h3, s_src, s_dst, N, 256);
    k_agg3<<<aggBlocks, 256, 0, stream>>>(h3, rowptr, col, s_src, s_dst, b3, outp, N);
}